// Round 2
// baseline (879.186 us; speedup 1.0000x reference)
//
#include <hip/hip_runtime.h>
#include <hip/hip_bf16.h>
#include <stdint.h>

// ParaGraph: 2 node types (net/cell, N=100000), 3 relations (E=600000 each), D=128.
// I/O FP32. LDS-free barrier-free bf16 MFMA GEMMs (W pre-converted to bf16, L1-resident;
// A has no intra-block reuse -> direct global->VGPR fragments). Bias folded via c=W2@bias.
// Block-local LDS radix partition -> per-bucket counting sort -> node-CSR; wave-per-node agg.
#define NN 100000
#define NE 600000
#define NB 782        // ceil(NN/128) dst buckets of 128 nodes
#define BCAP 1600     // LDS rec capacity per bucket (mean 767, sd ~28)
#define CHUNK 4096    // edges per partition block
#define NCH ((NE + CHUNK - 1) / CHUNK)   // 147

typedef unsigned short u16;
typedef unsigned int u32;
typedef __attribute__((ext_vector_type(8))) short short8;
typedef __attribute__((ext_vector_type(8))) __bf16 bf16x8;
typedef __attribute__((ext_vector_type(4))) float floatx4;

__device__ __forceinline__ float b2f(u16 u) {
  union { float f; u32 i; } c; c.i = ((u32)u) << 16; return c.f;
}
__device__ __forceinline__ u16 f2b(float f) {
  union { float f; u32 i; } c; c.f = f;
  u32 r = c.i + 0x7FFFu + ((c.i >> 16) & 1u);  // RNE
  return (u16)(r >> 16);
}

// ---------- weight pre-conversion to bf16 (once): Wl [128][256], Wg0/1/2 [128][128]
__global__ __launch_bounds__(256) void conv_k(const float* __restrict__ Wl,
                                              const float* __restrict__ Wg0,
                                              const float* __restrict__ Wg1,
                                              const float* __restrict__ Wg2,
                                              u16* __restrict__ Wl_bf, u16* __restrict__ Wg_bf) {
  int y = blockIdx.y;
  const float* src = (y == 0) ? Wl : (y == 1) ? Wg0 : (y == 2) ? Wg1 : Wg2;
  u16* dst = (y == 0) ? Wl_bf : Wg_bf + (size_t)(y - 1) * 16384;
  int n = (y == 0) ? 32768 : 16384;
  int i = (blockIdx.x * 256 + threadIdx.x) * 4;
  if (i >= n) return;
  float4 v = *(const float4*)(src + i);
  ushort4 p; p.x = f2b(v.x); p.y = f2b(v.y); p.z = f2b(v.z); p.w = f2b(v.w);
  *(ushort4*)(dst + i) = p;
}

// ---------- feature projection: feat = x @ Wp.T, [N,16]x[16,128] -> bf16 [N,128]
__global__ __launch_bounds__(256) void proj_k(const float* __restrict__ x_net, const float* __restrict__ x_cell,
                                              const float* __restrict__ Wp_net, const float* __restrict__ Wp_cell,
                                              u16* __restrict__ feat_net, u16* __restrict__ feat_cell) {
  const float* x  = blockIdx.y ? x_cell : x_net;
  const float* Wp = blockIdx.y ? Wp_cell : Wp_net;
  u16* feat       = blockIdx.y ? feat_cell : feat_net;
  __shared__ float Ws[128 * 17];
  __shared__ float xs[16][17];
  int tid = threadIdx.x;
#pragma unroll
  for (int it = 0; it < 8; ++it) {
    int idx = it * 256 + tid;
    int j = idx >> 4, k = idx & 15;
    Ws[j * 17 + k] = Wp[idx];
  }
  int n0 = blockIdx.x * 16;
  { int nn = tid >> 4, k = tid & 15;
    xs[nn][k] = x[(size_t)(n0 + nn) * 16 + k]; }
  __syncthreads();
  int j = tid & 127, g = tid >> 7;
  float acc[8];
#pragma unroll
  for (int r = 0; r < 8; ++r) acc[r] = 0.f;
#pragma unroll
  for (int k = 0; k < 16; ++k) {
    float w = Ws[j * 17 + k];
#pragma unroll
    for (int r = 0; r < 8; ++r) acc[r] += xs[g * 8 + r][k] * w;
  }
#pragma unroll
  for (int r = 0; r < 8; ++r)
    feat[(size_t)(n0 + g * 8 + r) * 128 + j] = f2b(acc[r]);
}

// ---------- vectors: a<6: vecs[a][k] = sum_j Wg[j,k]*(al|ar)[j];  a==6: c[j] = sum_k W2[j,k]*bias[k]
__global__ __launch_bounds__(128) void vec_k(const float* Wg0, const float* al0, const float* ar0,
                                             const float* Wg1, const float* al1, const float* ar1,
                                             const float* Wg2, const float* al2, const float* ar2,
                                             const float* Wl, const float* bias,
                                             float* __restrict__ vecs) {
  int a = blockIdx.x;
  int j = threadIdx.x;
  float s = 0.f;
  if (a < 6) {
    const float* W = (a < 2) ? Wg0 : (a < 4) ? Wg1 : Wg2;
    const float* v = (a == 0) ? al0 : (a == 1) ? ar0 : (a == 2) ? al1 : (a == 3) ? ar1 : (a == 4) ? al2 : ar2;
    for (int i = 0; i < 128; ++i) s += W[i * 128 + j] * v[i];
  } else {
    for (int i = 0; i < 128; ++i) s += Wl[(size_t)j * 256 + 128 + i] * bias[i];
  }
  vecs[a * 128 + j] = s;
}

// ---------- per-node logits, single pass per ntype
// y=0 (net): a=1 er0, a=2 el1, a=4 el2, a=5 er2;  y=1 (cell): a=0 el0, a=3 er1
__global__ __launch_bounds__(256) void logits_k(const u16* __restrict__ feat_net, const u16* __restrict__ feat_cell,
                                                const float* __restrict__ vecs, float* __restrict__ outs) {
  __shared__ float vs[6 * 128];
  int tid = threadIdx.x;
#pragma unroll
  for (int it = 0; it < 3; ++it) vs[it * 256 + tid] = vecs[it * 256 + tid];
  __syncthreads();
  int y = blockIdx.y;
  const u16* f = y ? feat_cell : feat_net;
  int n = blockIdx.x * 256 + tid;
  if (n >= NN) return;
  const u16* row = f + (size_t)n * 128;
  if (y == 0) {
    float s1 = 0.f, s2 = 0.f, s4 = 0.f, s5 = 0.f;
#pragma unroll
    for (int k = 0; k < 128; k += 8) {
      short8 u = *(const short8*)(row + k);
#pragma unroll
      for (int t = 0; t < 8; ++t) {
        float fv = b2f((u16)u[t]);
        s1 += fv * vs[1 * 128 + k + t]; s2 += fv * vs[2 * 128 + k + t];
        s4 += fv * vs[4 * 128 + k + t]; s5 += fv * vs[5 * 128 + k + t];
      }
    }
    outs[(size_t)1 * NN + n] = s1; outs[(size_t)2 * NN + n] = s2;
    outs[(size_t)4 * NN + n] = s4; outs[(size_t)5 * NN + n] = s5;
  } else {
    float s0 = 0.f, s3 = 0.f;
#pragma unroll
    for (int k = 0; k < 128; k += 8) {
      short8 u = *(const short8*)(row + k);
#pragma unroll
      for (int t = 0; t < 8; ++t) {
        float fv = b2f((u16)u[t]);
        s0 += fv * vs[0 * 128 + k + t]; s3 += fv * vs[3 * 128 + k + t];
      }
    }
    outs[(size_t)0 * NN + n] = s0; outs[(size_t)3 * NN + n] = s3;
  }
}

// ---------- histogram over dst buckets, LDS-aggregated
__global__ __launch_bounds__(256) void bhist_k(const int* __restrict__ dst0, const int* __restrict__ dst1,
                                               const int* __restrict__ dst2, int* __restrict__ bcnt) {
  int r = blockIdx.y;
  const int* dst = (r == 0) ? dst0 : (r == 1) ? dst1 : dst2;
  __shared__ int h[NB];
  int tid = threadIdx.x;
  for (int i = tid; i < NB; i += 256) h[i] = 0;
  __syncthreads();
  int e0 = blockIdx.x * CHUNK;
  int cnt = NE - e0; if (cnt > CHUNK) cnt = CHUNK;
  for (int i = tid; i < cnt; i += 256) atomicAdd(&h[((u32)dst[e0 + i]) >> 7], 1);
  __syncthreads();
  for (int b = tid; b < NB; b += 256) {
    int c = h[b];
    if (c) atomicAdd(&bcnt[(size_t)r * NB + b], c);
  }
}

// ---------- exclusive scan of NB counters per relation (one 1024-block each)
__global__ __launch_bounds__(1024) void bscan_k(const int* __restrict__ bcnt, int* __restrict__ bptr,
                                                int* __restrict__ bcur) {
  int r = blockIdx.x, t = threadIdx.x;
  const int* c = bcnt + (size_t)r * NB;
  int* p = bptr + (size_t)r * (NB + 1);
  int* cur = bcur + (size_t)r * NB;
  int v = (t < NB) ? c[t] : 0;
  __shared__ int ss[1024];
  ss[t] = v; __syncthreads();
  for (int off = 1; off < 1024; off <<= 1) {
    int u = (t >= off) ? ss[t - off] : 0;
    __syncthreads();
    ss[t] += u;
    __syncthreads();
  }
  if (t < NB) { int e = ss[t] - v; p[t] = e; cur[t] = e; }
  if (t == 1023) p[NB] = ss[1023];
}

// ---------- block-local radix partition: LDS-bin a 4096-edge chunk by dst bucket,
// reserve contiguous global space per (block,bucket), stream out coalesced runs.
__global__ __launch_bounds__(256) void bscatter_k(const int* __restrict__ src0, const int* __restrict__ dst0,
                                                  const int* __restrict__ src1, const int* __restrict__ dst1,
                                                  const int* __restrict__ src2, const int* __restrict__ dst2,
                                                  int* __restrict__ bcur, u32* __restrict__ recs) {
  int r = blockIdx.y;
  const int* src = (r == 0) ? src0 : (r == 1) ? src1 : src2;
  const int* dst = (r == 0) ? dst0 : (r == 1) ? dst1 : dst2;
  __shared__ int hist[NB];
  __shared__ int lstart[NB];
  __shared__ int lcur[NB];
  __shared__ int badj[NB];
  __shared__ u32 rbuf[CHUNK];
  __shared__ u16 kbuf[CHUNK];
  __shared__ int ss[256];
  int tid = threadIdx.x;
  int e0 = blockIdx.x * CHUNK;
  int cnt = NE - e0; if (cnt > CHUNK) cnt = CHUNK;

  for (int i = tid; i < NB; i += 256) hist[i] = 0;
  __syncthreads();
  // phase 1: local histogram
  for (int i = tid; i < cnt; i += 256) atomicAdd(&hist[((u32)dst[e0 + i]) >> 7], 1);
  __syncthreads();
  // phase 2: local exclusive scan (256 threads x 4 bins) + global reservation
  int loc[4]; int s = 0;
  int base4 = tid * 4;
#pragma unroll
  for (int j = 0; j < 4; ++j) {
    int idx = base4 + j;
    int v = (idx < NB) ? hist[idx] : 0;
    loc[j] = s; s += v;
  }
  ss[tid] = s; __syncthreads();
  for (int off = 1; off < 256; off <<= 1) {
    int u = (tid >= off) ? ss[tid - off] : 0;
    __syncthreads();
    ss[tid] += u;
    __syncthreads();
  }
  int ex = ss[tid] - s;
#pragma unroll
  for (int j = 0; j < 4; ++j) {
    int idx = base4 + j;
    if (idx < NB) { int e = ex + loc[j]; lstart[idx] = e; lcur[idx] = e; }
  }
  __syncthreads();
  for (int b = tid; b < NB; b += 256) {
    int c = hist[b];
    int g = 0;
    if (c) g = atomicAdd(&bcur[(size_t)r * NB + b], c);
    badj[b] = g - lstart[b];
  }
  __syncthreads();
  // phase 3: reorder records into LDS, sorted by bucket
  for (int i = tid; i < cnt; i += 256) {
    int dN = dst[e0 + i], sN = src[e0 + i];
    int b = ((u32)dN) >> 7;
    int pos = atomicAdd(&lcur[b], 1);
    rbuf[pos] = ((u32)(dN & 127) << 17) | (u32)sN;
    kbuf[pos] = (u16)b;
  }
  __syncthreads();
  // phase 4: coalesced run-writes (consecutive slots in a bucket -> consecutive addrs)
  u32* out = recs + (size_t)r * NE;
  for (int i = tid; i < cnt; i += 256) {
    int b = kbuf[i];
    out[badj[b] + i] = rbuf[i];
  }
}

// ---------- per-bucket LDS counting sort (in place) + node rowptr
__global__ __launch_bounds__(256) void sort_k(u32* __restrict__ recs, const int* __restrict__ bptr,
                                              int* __restrict__ rowptr) {
  int r = blockIdx.y, b = blockIdx.x, tid = threadIdx.x;
  const int* p = bptr + (size_t)r * (NB + 1);
  u32* rec = recs + (size_t)r * NE;
  int* rp = rowptr + (size_t)r * (NN + 1);
  int base = p[b], end = p[b + 1];
  int cnt = end - base; if (cnt > BCAP) cnt = BCAP;   // statistically impossible to exceed
  __shared__ u32 rs[BCAP];
  __shared__ int hist[128], excl[128], cur[128];
  for (int i = tid; i < cnt; i += 256) rs[i] = rec[base + i];
  if (tid < 128) hist[tid] = 0;
  __syncthreads();
  for (int i = tid; i < cnt; i += 256) atomicAdd(&hist[rs[i] >> 17], 1);
  __syncthreads();
  if (tid < 128) cur[tid] = hist[tid];
  __syncthreads();
  for (int off = 1; off < 128; off <<= 1) {
    int v = 0;
    if (tid < 128 && tid >= off) v = cur[tid - off];
    __syncthreads();
    if (tid < 128) cur[tid] += v;
    __syncthreads();
  }
  if (tid < 128) {
    int e = cur[tid] - hist[tid];      // exclusive
    excl[tid] = e;
    int node = b * 128 + tid;
    if (node < NN) rp[node] = base + e;
  }
  if (b == NB - 1 && tid == 0) rp[NN] = p[NB];
  if (tid < 128) cur[tid] = excl[tid];
  __syncthreads();
  for (int i = tid; i < cnt; i += 256) {
    u32 v = rs[i];
    int pos = atomicAdd(&cur[v >> 17], 1);
    rec[base + pos] = v & 0x1FFFFu;    // store src only, node-sorted
  }
}

// ---------- aggregation: one wave per dst node, register accumulation
// out[n] (+)= (sum_e x_e h[src_e]) / (sum_e x_e);  x = exp(leaky(el[src]+er[n]))
template<int RMW>
__global__ __launch_bounds__(256) void agg_k(const u16* __restrict__ h, const u32* __restrict__ srecs,
                                             const int* __restrict__ rp,
                                             const float* __restrict__ el, const float* __restrict__ er,
                                             float* __restrict__ out) {
  int n = blockIdx.x * 4 + (threadIdx.x >> 6);
  if (n >= NN) return;
  int lane = threadIdx.x & 63;
  int start = rp[n], end = rp[n + 1];
  float2* o = (float2*)(out + (size_t)n * 128) + lane;
  if (start == end) { if (!RMW) *o = make_float2(0.f, 0.f); return; }
  float ern = er[n];
  float2 acc = make_float2(0.f, 0.f);
  float s = 0.f;
  for (int e = start; e < end; ++e) {
    int src = (int)srecs[e];
    float l = el[src] + ern;
    l = (l >= 0.f) ? l : 0.2f * l;
    float x = __expf(l);
    s += x;
    u32 hv = *(const u32*)(h + (size_t)src * 128 + 2 * lane);
    acc.x += x * b2f((u16)(hv & 0xffff));
    acc.y += x * b2f((u16)(hv >> 16));
  }
  float inv = 1.f / s;
  float2 prev = RMW ? *o : make_float2(0.f, 0.f);
  prev.x += acc.x * inv; prev.y += acc.y * inv;
  *o = prev;
}

// ---------- LDS-free bf16 GEMM (up to 3 jobs): C[n][j] = sum_k A[n][k] * W[j*ldw+k], bf16 out
// A: bf16 [N,128], no intra-block reuse -> direct global fragment loads.
// W: bf16 (pre-converted), 32KB tile -> L1-resident across blocks.
struct BJob { const u16* A; const u16* W; int ldw; u16* C; };
struct BJobs3 { BJob j[3]; };
__global__ __launch_bounds__(256) void gemm_bf_k(BJobs3 jobs) {
  BJob jb = jobs.j[blockIdx.y];
  const int tid = threadIdx.x;
  const int row0 = blockIdx.x * 64;
  const int lane = tid & 63, wv = tid >> 6;
  const int m16 = lane & 15, quad = lane >> 4;
  int ar = row0 + wv * 16 + m16;
  if (ar >= NN) ar = NN - 1;             // clamp: stores are guarded below
  const u16* Ab = jb.A + (size_t)ar * 128 + quad * 8;
  bf16x8 a[4];
#pragma unroll
  for (int kk = 0; kk < 4; ++kk) a[kk] = *(const bf16x8*)(Ab + kk * 32);
  const u16* Wb = jb.W + (size_t)m16 * jb.ldw + quad * 8;
  floatx4 acc[8];
#pragma unroll
  for (int c = 0; c < 8; ++c) acc[c] = floatx4{0.f, 0.f, 0.f, 0.f};
#pragma unroll
  for (int c = 0; c < 8; ++c) {
    const u16* wr = Wb + (size_t)(c * 16) * jb.ldw;
#pragma unroll
    for (int kk = 0; kk < 4; ++kk) {
      bf16x8 b = *(const bf16x8*)(wr + kk * 32);
      acc[c] = __builtin_amdgcn_mfma_f32_16x16x32_bf16(a[kk], b, acc[c], 0, 0, 0);
    }
  }
#pragma unroll
  for (int c = 0; c < 8; ++c) {
    int col = c * 16 + m16;
#pragma unroll
    for (int r = 0; r < 4; ++r) {
      int grow = row0 + wv * 16 + quad * 4 + r;
      if (grow < NN) jb.C[(size_t)grow * 128 + col] = f2b(acc[c][r]);
    }
  }
}

// ---------- LDS-free fused concat-linear-relu (up to 2 jobs):
// C = relu(P + A @ W2cols128.T + c), c = W2@bias precomputed (bias fold), fp32 in/out.
struct FJob { const float* A; const u16* P; float* C; };
struct FJobs2 { FJob j[2]; const u16* W; const float* cvec; };
__global__ __launch_bounds__(256) void fused_k(FJobs2 jobs) {
  FJob jb = jobs.j[blockIdx.y];
  const int tid = threadIdx.x;
  const int row0 = blockIdx.x * 64;
  const int lane = tid & 63, wv = tid >> 6;
  const int m16 = lane & 15, quad = lane >> 4;
  int ar = row0 + wv * 16 + m16;
  if (ar >= NN) ar = NN - 1;             // clamp: stores are guarded below
  const float* Ab = jb.A + (size_t)ar * 128 + quad * 8;
  bf16x8 a[4];
#pragma unroll
  for (int kk = 0; kk < 4; ++kk) {
    float4 v0 = *(const float4*)(Ab + kk * 32);
    float4 v1 = *(const float4*)(Ab + kk * 32 + 4);
    short8 s;
    s[0] = (short)f2b(v0.x); s[1] = (short)f2b(v0.y);
    s[2] = (short)f2b(v0.z); s[3] = (short)f2b(v0.w);
    s[4] = (short)f2b(v1.x); s[5] = (short)f2b(v1.y);
    s[6] = (short)f2b(v1.z); s[7] = (short)f2b(v1.w);
    a[kk] = __builtin_bit_cast(bf16x8, s);
  }
  const u16* Wb = jobs.W + (size_t)m16 * 256 + quad * 8;   // W2 cols 128..255, ldw=256
  floatx4 acc[8];
#pragma unroll
  for (int c = 0; c < 8; ++c) acc[c] = floatx4{0.f, 0.f, 0.f, 0.f};
#pragma unroll
  for (int c = 0; c < 8; ++c) {
    const u16* wr = Wb + (size_t)(c * 16) * 256;
#pragma unroll
    for (int kk = 0; kk < 4; ++kk) {
      bf16x8 b = *(const bf16x8*)(wr + kk * 32);
      acc[c] = __builtin_amdgcn_mfma_f32_16x16x32_bf16(a[kk], b, acc[c], 0, 0, 0);
    }
  }
#pragma unroll
  for (int c = 0; c < 8; ++c) {
    int col = c * 16 + m16;
    float cv = jobs.cvec[col];
#pragma unroll
    for (int r = 0; r < 4; ++r) {
      int grow = row0 + wv * 16 + quad * 4 + r;
      if (grow < NN) {
        float v = acc[c][r] + b2f(jb.P[(size_t)grow * 128 + col]) + cv;
        jb.C[(size_t)grow * 128 + col] = fmaxf(v, 0.f);
      }
    }
  }
}

// ---------- r0 cell shortcut: buf_cell = relu(P_cell + W2@bias)   (agg input was all zeros)
__global__ __launch_bounds__(256) void elem_k(const u16* __restrict__ P, const float* __restrict__ vecs,
                                              float* __restrict__ out) {
  __shared__ float cs[128];
  if (threadIdx.x < 128) cs[threadIdx.x] = vecs[6 * 128 + threadIdx.x];
  __syncthreads();
  size_t idx = ((size_t)blockIdx.x * 256 + threadIdx.x) * 8;
  if (idx >= (size_t)NN * 128) return;
  int col = (int)(idx & 127);
  short8 u = *(const short8*)(P + idx);
  float4 o0, o1;
  o0.x = fmaxf(b2f((u16)u[0]) + cs[col + 0], 0.f);
  o0.y = fmaxf(b2f((u16)u[1]) + cs[col + 1], 0.f);
  o0.z = fmaxf(b2f((u16)u[2]) + cs[col + 2], 0.f);
  o0.w = fmaxf(b2f((u16)u[3]) + cs[col + 3], 0.f);
  o1.x = fmaxf(b2f((u16)u[4]) + cs[col + 4], 0.f);
  o1.y = fmaxf(b2f((u16)u[5]) + cs[col + 5], 0.f);
  o1.z = fmaxf(b2f((u16)u[6]) + cs[col + 6], 0.f);
  o1.w = fmaxf(b2f((u16)u[7]) + cs[col + 7], 0.f);
  *(float4*)(out + idx) = o0;
  *(float4*)(out + idx + 4) = o1;
}

extern "C" void kernel_launch(void* const* d_in, const int* in_sizes, int n_in,
                              void* d_out, int out_size, void* d_ws, size_t ws_size,
                              hipStream_t stream) {
  const float* x_net   = (const float*)d_in[0];
  const float* x_cell  = (const float*)d_in[1];
  const float* Wp_net  = (const float*)d_in[2];
  const float* Wp_cell = (const float*)d_in[3];
  const float* Wg[3] = {(const float*)d_in[4], (const float*)d_in[7], (const float*)d_in[10]};
  const float* al[3] = {(const float*)d_in[5], (const float*)d_in[8], (const float*)d_in[11]};
  const float* ar[3] = {(const float*)d_in[6], (const float*)d_in[9], (const float*)d_in[12]};
  const float* Wl    = (const float*)d_in[13];
  const float* bias  = (const float*)d_in[14];
  const int* src[3] = {(const int*)d_in[15], (const int*)d_in[17], (const int*)d_in[19]};
  const int* dst[3] = {(const int*)d_in[16], (const int*)d_in[18], (const int*)d_in[20]};

  char* ws = (char*)d_ws;
  size_t off = 0;
  auto alloc = [&](size_t b) { void* p = ws + off; off = (off + b + 255) & ~(size_t)255; return p; };
  u16*  feat_net  = (u16*)alloc((size_t)NN * 128 * 2);
  u16*  feat_cell = (u16*)alloc((size_t)NN * 128 * 2);
  u16*  hbuf      = (u16*)alloc((size_t)NN * 128 * 2);
  u16*  P_net     = (u16*)alloc((size_t)NN * 128 * 2);
  u16*  P_cell    = (u16*)alloc((size_t)NN * 128 * 2);
  float* buf_net  = (float*)alloc((size_t)NN * 128 * 4);
  float* buf_cell = (float*)alloc((size_t)NN * 128 * 4);
  float* vecs     = (float*)alloc(7 * 128 * 4);
  float* logit    = (float*)alloc((size_t)6 * NN * 4);
  u16*   Wl_bf    = (u16*)alloc((size_t)128 * 256 * 2);
  u16*   Wg_bf    = (u16*)alloc((size_t)3 * 128 * 128 * 2);
  int*   bcnt     = (int*)alloc((size_t)3 * NB * 4);
  int*   bcur     = (int*)alloc((size_t)3 * NB * 4);
  int*   bptr     = (int*)alloc((size_t)3 * (NB + 1) * 4);
  int*   rowptr   = (int*)alloc((size_t)3 * (NN + 1) * 4);
  u32*   recs     = (u32*)alloc((size_t)3 * NE * 4);
  // ~245 MB total

  hipMemsetAsync(bcnt, 0, (size_t)3 * NB * 4, stream);

  conv_k<<<dim3(32, 4), 256, 0, stream>>>(Wl, Wg[0], Wg[1], Wg[2], Wl_bf, Wg_bf);
  proj_k<<<dim3(NN / 16, 2), 256, 0, stream>>>(x_net, x_cell, Wp_net, Wp_cell, feat_net, feat_cell);
  vec_k<<<7, 128, 0, stream>>>(Wg[0], al[0], ar[0], Wg[1], al[1], ar[1], Wg[2], al[2], ar[2], Wl, bias, vecs);
  logits_k<<<dim3((NN + 255) / 256, 2), 256, 0, stream>>>(feat_net, feat_cell, vecs, logit);

  bhist_k<<<dim3(NCH, 3), 256, 0, stream>>>(dst[0], dst[1], dst[2], bcnt);
  bscan_k<<<3, 1024, 0, stream>>>(bcnt, bptr, bcur);
  bscatter_k<<<dim3(NCH, 3), 256, 0, stream>>>(src[0], dst[0], src[1], dst[1], src[2], dst[2],
                                               bcur, recs);
  sort_k<<<dim3(NB, 3), 256, 0, stream>>>(recs, bptr, rowptr);

  const int gb = (NN + 63) / 64;  // 1563
  {
    BJobs3 jobs;
    jobs.j[0] = {feat_net,  Wl_bf, 256, P_net};
    jobs.j[1] = {feat_cell, Wl_bf, 256, P_cell};
    jobs.j[2] = {feat_cell, Wg_bf, 128, hbuf};   // h0 = feat_cell @ Wg0.T
    gemm_bf_k<<<dim3(gb, 3), 256, 0, stream>>>(jobs);
  }

  float* out_f = (float*)d_out;  // [2,N,D] fp32: net then cell
  const int ab = (NN + 3) / 4;   // 25000

  // ---- r = 0 : cell -> net
  agg_k<0><<<ab, 256, 0, stream>>>(hbuf, recs, rowptr, logit, logit + (size_t)NN, buf_net);
  {
    FJobs2 jobs; jobs.W = Wl_bf + 128; jobs.cvec = vecs + 6 * 128;
    jobs.j[0] = {buf_net, P_net, buf_net}; jobs.j[1] = jobs.j[0];
    fused_k<<<dim3(gb, 1), 256, 0, stream>>>(jobs);
  }
  elem_k<<<(NN * 128 / 8 + 255) / 256, 256, 0, stream>>>(P_cell, vecs, buf_cell);

  // ---- r = 1 : net -> cell
  {
    BJobs3 jobs;
    jobs.j[0] = {feat_net, Wg_bf + 16384, 128, hbuf};
    jobs.j[1] = jobs.j[0]; jobs.j[2] = jobs.j[0];
    gemm_bf_k<<<dim3(gb, 1), 256, 0, stream>>>(jobs);
  }
  agg_k<1><<<ab, 256, 0, stream>>>(hbuf, recs + (size_t)NE, rowptr + (NN + 1),
                                   logit + (size_t)2 * NN, logit + (size_t)3 * NN, buf_cell);
  {
    FJobs2 jobs; jobs.W = Wl_bf + 128; jobs.cvec = vecs + 6 * 128;
    jobs.j[0] = {buf_net, P_net, buf_net};
    jobs.j[1] = {buf_cell, P_cell, buf_cell};
    fused_k<<<dim3(gb, 2), 256, 0, stream>>>(jobs);
  }

  // ---- r = 2 : net -> net
  {
    BJobs3 jobs;
    jobs.j[0] = {feat_net, Wg_bf + 32768, 128, hbuf};
    jobs.j[1] = jobs.j[0]; jobs.j[2] = jobs.j[0];
    gemm_bf_k<<<dim3(gb, 1), 256, 0, stream>>>(jobs);
  }
  agg_k<1><<<ab, 256, 0, stream>>>(hbuf, recs + (size_t)2 * NE, rowptr + 2 * (NN + 1),
                                   logit + (size_t)4 * NN, logit + (size_t)5 * NN, buf_net);
  {
    FJobs2 jobs; jobs.W = Wl_bf + 128; jobs.cvec = vecs + 6 * 128;
    jobs.j[0] = {buf_net, P_net, out_f};
    jobs.j[1] = {buf_cell, P_cell, out_f + (size_t)NN * 128};
    fused_k<<<dim3(gb, 2), 256, 0, stream>>>(jobs);
  }
}

// Round 3
// 686.069 us; speedup vs baseline: 1.2815x; 1.2815x over previous
//
#include <hip/hip_runtime.h>
#include <hip/hip_bf16.h>
#include <stdint.h>

// ParaGraph: 2 node types (net/cell, N=100000), 3 relations (E=600000 each), D=128.
// I/O FP32. GEMMs: W pre-converted to bf16, cooperatively staged to LDS (plain 16B
// copies, no per-block f2b), A read direct global->VGPR fragments (no intra-block
// reuse). Bias folded via c=W2@bias. Block-local LDS radix partition -> per-bucket
// counting sort -> node-CSR; wave-per-node register softmax aggregation.
#define NN 100000
#define NE 600000
#define SP 136        // GEMM LDS row stride (ushorts): 128 + 8 pad
#define NB 782        // ceil(NN/128) dst buckets of 128 nodes
#define BCAP 1600     // LDS rec capacity per bucket (mean 767, sd ~28)
#define CHUNK 4096    // edges per partition block
#define NCH ((NE + CHUNK - 1) / CHUNK)   // 147

typedef unsigned short u16;
typedef unsigned int u32;
typedef __attribute__((ext_vector_type(8))) short short8;
typedef __attribute__((ext_vector_type(8))) __bf16 bf16x8;
typedef __attribute__((ext_vector_type(4))) float floatx4;

__device__ __forceinline__ float b2f(u16 u) {
  union { float f; u32 i; } c; c.i = ((u32)u) << 16; return c.f;
}
__device__ __forceinline__ u16 f2b(float f) {
  union { float f; u32 i; } c; c.f = f;
  u32 r = c.i + 0x7FFFu + ((c.i >> 16) & 1u);  // RNE
  return (u16)(r >> 16);
}

// ---------- weight pre-conversion to bf16 (once): Wl [128][256], Wg0/1/2 [128][128]
__global__ __launch_bounds__(256) void conv_k(const float* __restrict__ Wl,
                                              const float* __restrict__ Wg0,
                                              const float* __restrict__ Wg1,
                                              const float* __restrict__ Wg2,
                                              u16* __restrict__ Wl_bf, u16* __restrict__ Wg_bf) {
  int y = blockIdx.y;
  const float* src = (y == 0) ? Wl : (y == 1) ? Wg0 : (y == 2) ? Wg1 : Wg2;
  u16* dst = (y == 0) ? Wl_bf : Wg_bf + (size_t)(y - 1) * 16384;
  int n = (y == 0) ? 32768 : 16384;
  int i = (blockIdx.x * 256 + threadIdx.x) * 4;
  if (i >= n) return;
  float4 v = *(const float4*)(src + i);
  ushort4 p; p.x = f2b(v.x); p.y = f2b(v.y); p.z = f2b(v.z); p.w = f2b(v.w);
  *(ushort4*)(dst + i) = p;
}

// ---------- feature projection: feat = x @ Wp.T, [N,16]x[16,128] -> bf16 [N,128]
__global__ __launch_bounds__(256) void proj_k(const float* __restrict__ x_net, const float* __restrict__ x_cell,
                                              const float* __restrict__ Wp_net, const float* __restrict__ Wp_cell,
                                              u16* __restrict__ feat_net, u16* __restrict__ feat_cell) {
  const float* x  = blockIdx.y ? x_cell : x_net;
  const float* Wp = blockIdx.y ? Wp_cell : Wp_net;
  u16* feat       = blockIdx.y ? feat_cell : feat_net;
  __shared__ float Ws[128 * 17];
  __shared__ float xs[16][17];
  int tid = threadIdx.x;
#pragma unroll
  for (int it = 0; it < 8; ++it) {
    int idx = it * 256 + tid;
    int j = idx >> 4, k = idx & 15;
    Ws[j * 17 + k] = Wp[idx];
  }
  int n0 = blockIdx.x * 16;
  { int nn = tid >> 4, k = tid & 15;
    xs[nn][k] = x[(size_t)(n0 + nn) * 16 + k]; }
  __syncthreads();
  int j = tid & 127, g = tid >> 7;
  float acc[8];
#pragma unroll
  for (int r = 0; r < 8; ++r) acc[r] = 0.f;
#pragma unroll
  for (int k = 0; k < 16; ++k) {
    float w = Ws[j * 17 + k];
#pragma unroll
    for (int r = 0; r < 8; ++r) acc[r] += xs[g * 8 + r][k] * w;
  }
#pragma unroll
  for (int r = 0; r < 8; ++r)
    feat[(size_t)(n0 + g * 8 + r) * 128 + j] = f2b(acc[r]);
}

// ---------- vectors: a<6: vecs[a][k] = sum_j Wg[j,k]*(al|ar)[j];  a==6: c[j] = sum_k W2[j,k]*bias[k]
__global__ __launch_bounds__(128) void vec_k(const float* Wg0, const float* al0, const float* ar0,
                                             const float* Wg1, const float* al1, const float* ar1,
                                             const float* Wg2, const float* al2, const float* ar2,
                                             const float* Wl, const float* bias,
                                             float* __restrict__ vecs) {
  int a = blockIdx.x;
  int j = threadIdx.x;
  float s = 0.f;
  if (a < 6) {
    const float* W = (a < 2) ? Wg0 : (a < 4) ? Wg1 : Wg2;
    const float* v = (a == 0) ? al0 : (a == 1) ? ar0 : (a == 2) ? al1 : (a == 3) ? ar1 : (a == 4) ? al2 : ar2;
    for (int i = 0; i < 128; ++i) s += W[i * 128 + j] * v[i];
  } else {
    for (int i = 0; i < 128; ++i) s += Wl[(size_t)j * 256 + 128 + i] * bias[i];
  }
  vecs[a * 128 + j] = s;
}

// ---------- per-node logits, single pass per ntype
// y=0 (net): a=1 er0, a=2 el1, a=4 el2, a=5 er2;  y=1 (cell): a=0 el0, a=3 er1
__global__ __launch_bounds__(256) void logits_k(const u16* __restrict__ feat_net, const u16* __restrict__ feat_cell,
                                                const float* __restrict__ vecs, float* __restrict__ outs) {
  __shared__ float vs[6 * 128];
  int tid = threadIdx.x;
#pragma unroll
  for (int it = 0; it < 3; ++it) vs[it * 256 + tid] = vecs[it * 256 + tid];
  __syncthreads();
  int y = blockIdx.y;
  const u16* f = y ? feat_cell : feat_net;
  int n = blockIdx.x * 256 + tid;
  if (n >= NN) return;
  const u16* row = f + (size_t)n * 128;
  if (y == 0) {
    float s1 = 0.f, s2 = 0.f, s4 = 0.f, s5 = 0.f;
#pragma unroll
    for (int k = 0; k < 128; k += 8) {
      short8 u = *(const short8*)(row + k);
#pragma unroll
      for (int t = 0; t < 8; ++t) {
        float fv = b2f((u16)u[t]);
        s1 += fv * vs[1 * 128 + k + t]; s2 += fv * vs[2 * 128 + k + t];
        s4 += fv * vs[4 * 128 + k + t]; s5 += fv * vs[5 * 128 + k + t];
      }
    }
    outs[(size_t)1 * NN + n] = s1; outs[(size_t)2 * NN + n] = s2;
    outs[(size_t)4 * NN + n] = s4; outs[(size_t)5 * NN + n] = s5;
  } else {
    float s0 = 0.f, s3 = 0.f;
#pragma unroll
    for (int k = 0; k < 128; k += 8) {
      short8 u = *(const short8*)(row + k);
#pragma unroll
      for (int t = 0; t < 8; ++t) {
        float fv = b2f((u16)u[t]);
        s0 += fv * vs[0 * 128 + k + t]; s3 += fv * vs[3 * 128 + k + t];
      }
    }
    outs[(size_t)0 * NN + n] = s0; outs[(size_t)3 * NN + n] = s3;
  }
}

// ---------- histogram over dst buckets, LDS-aggregated
__global__ __launch_bounds__(256) void bhist_k(const int* __restrict__ dst0, const int* __restrict__ dst1,
                                               const int* __restrict__ dst2, int* __restrict__ bcnt) {
  int r = blockIdx.y;
  const int* dst = (r == 0) ? dst0 : (r == 1) ? dst1 : dst2;
  __shared__ int h[NB];
  int tid = threadIdx.x;
  for (int i = tid; i < NB; i += 256) h[i] = 0;
  __syncthreads();
  int e0 = blockIdx.x * CHUNK;
  int cnt = NE - e0; if (cnt > CHUNK) cnt = CHUNK;
  for (int i = tid; i < cnt; i += 256) atomicAdd(&h[((u32)dst[e0 + i]) >> 7], 1);
  __syncthreads();
  for (int b = tid; b < NB; b += 256) {
    int c = h[b];
    if (c) atomicAdd(&bcnt[(size_t)r * NB + b], c);
  }
}

// ---------- exclusive scan of NB counters per relation (one 1024-block each)
__global__ __launch_bounds__(1024) void bscan_k(const int* __restrict__ bcnt, int* __restrict__ bptr,
                                                int* __restrict__ bcur) {
  int r = blockIdx.x, t = threadIdx.x;
  const int* c = bcnt + (size_t)r * NB;
  int* p = bptr + (size_t)r * (NB + 1);
  int* cur = bcur + (size_t)r * NB;
  int v = (t < NB) ? c[t] : 0;
  __shared__ int ss[1024];
  ss[t] = v; __syncthreads();
  for (int off = 1; off < 1024; off <<= 1) {
    int u = (t >= off) ? ss[t - off] : 0;
    __syncthreads();
    ss[t] += u;
    __syncthreads();
  }
  if (t < NB) { int e = ss[t] - v; p[t] = e; cur[t] = e; }
  if (t == 1023) p[NB] = ss[1023];
}

// ---------- block-local radix partition: LDS-bin a 4096-edge chunk by dst bucket,
// reserve contiguous global space per (block,bucket), stream out coalesced runs.
__global__ __launch_bounds__(256) void bscatter_k(const int* __restrict__ src0, const int* __restrict__ dst0,
                                                  const int* __restrict__ src1, const int* __restrict__ dst1,
                                                  const int* __restrict__ src2, const int* __restrict__ dst2,
                                                  int* __restrict__ bcur, u32* __restrict__ recs) {
  int r = blockIdx.y;
  const int* src = (r == 0) ? src0 : (r == 1) ? src1 : src2;
  const int* dst = (r == 0) ? dst0 : (r == 1) ? dst1 : dst2;
  __shared__ int hist[NB];
  __shared__ int lstart[NB];
  __shared__ int lcur[NB];
  __shared__ int badj[NB];
  __shared__ u32 rbuf[CHUNK];
  __shared__ u16 kbuf[CHUNK];
  __shared__ int ss[256];
  int tid = threadIdx.x;
  int e0 = blockIdx.x * CHUNK;
  int cnt = NE - e0; if (cnt > CHUNK) cnt = CHUNK;

  for (int i = tid; i < NB; i += 256) hist[i] = 0;
  __syncthreads();
  // phase 1: local histogram
  for (int i = tid; i < cnt; i += 256) atomicAdd(&hist[((u32)dst[e0 + i]) >> 7], 1);
  __syncthreads();
  // phase 2: local exclusive scan (256 threads x 4 bins) + global reservation
  int loc[4]; int s = 0;
  int base4 = tid * 4;
#pragma unroll
  for (int j = 0; j < 4; ++j) {
    int idx = base4 + j;
    int v = (idx < NB) ? hist[idx] : 0;
    loc[j] = s; s += v;
  }
  ss[tid] = s; __syncthreads();
  for (int off = 1; off < 256; off <<= 1) {
    int u = (tid >= off) ? ss[tid - off] : 0;
    __syncthreads();
    ss[tid] += u;
    __syncthreads();
  }
  int ex = ss[tid] - s;
#pragma unroll
  for (int j = 0; j < 4; ++j) {
    int idx = base4 + j;
    if (idx < NB) { int e = ex + loc[j]; lstart[idx] = e; lcur[idx] = e; }
  }
  __syncthreads();
  for (int b = tid; b < NB; b += 256) {
    int c = hist[b];
    int g = 0;
    if (c) g = atomicAdd(&bcur[(size_t)r * NB + b], c);
    badj[b] = g - lstart[b];
  }
  __syncthreads();
  // phase 3: reorder records into LDS, sorted by bucket
  for (int i = tid; i < cnt; i += 256) {
    int dN = dst[e0 + i], sN = src[e0 + i];
    int b = ((u32)dN) >> 7;
    int pos = atomicAdd(&lcur[b], 1);
    rbuf[pos] = ((u32)(dN & 127) << 17) | (u32)sN;
    kbuf[pos] = (u16)b;
  }
  __syncthreads();
  // phase 4: coalesced run-writes (consecutive slots in a bucket -> consecutive addrs)
  u32* out = recs + (size_t)r * NE;
  for (int i = tid; i < cnt; i += 256) {
    int b = kbuf[i];
    out[badj[b] + i] = rbuf[i];
  }
}

// ---------- per-bucket LDS counting sort (in place) + node rowptr
__global__ __launch_bounds__(256) void sort_k(u32* __restrict__ recs, const int* __restrict__ bptr,
                                              int* __restrict__ rowptr) {
  int r = blockIdx.y, b = blockIdx.x, tid = threadIdx.x;
  const int* p = bptr + (size_t)r * (NB + 1);
  u32* rec = recs + (size_t)r * NE;
  int* rp = rowptr + (size_t)r * (NN + 1);
  int base = p[b], end = p[b + 1];
  int cnt = end - base; if (cnt > BCAP) cnt = BCAP;   // statistically impossible to exceed
  __shared__ u32 rs[BCAP];
  __shared__ int hist[128], excl[128], cur[128];
  for (int i = tid; i < cnt; i += 256) rs[i] = rec[base + i];
  if (tid < 128) hist[tid] = 0;
  __syncthreads();
  for (int i = tid; i < cnt; i += 256) atomicAdd(&hist[rs[i] >> 17], 1);
  __syncthreads();
  if (tid < 128) cur[tid] = hist[tid];
  __syncthreads();
  for (int off = 1; off < 128; off <<= 1) {
    int v = 0;
    if (tid < 128 && tid >= off) v = cur[tid - off];
    __syncthreads();
    if (tid < 128) cur[tid] += v;
    __syncthreads();
  }
  if (tid < 128) {
    int e = cur[tid] - hist[tid];      // exclusive
    excl[tid] = e;
    int node = b * 128 + tid;
    if (node < NN) rp[node] = base + e;
  }
  if (b == NB - 1 && tid == 0) rp[NN] = p[NB];
  if (tid < 128) cur[tid] = excl[tid];
  __syncthreads();
  for (int i = tid; i < cnt; i += 256) {
    u32 v = rs[i];
    int pos = atomicAdd(&cur[v >> 17], 1);
    rec[base + pos] = v & 0x1FFFFu;    // store src only, node-sorted
  }
}

// ---------- aggregation: one wave per dst node, register accumulation
// out[n] (+)= (sum_e x_e h[src_e]) / (sum_e x_e);  x = exp(leaky(el[src]+er[n]))
template<int RMW>
__global__ __launch_bounds__(256) void agg_k(const u16* __restrict__ h, const u32* __restrict__ srecs,
                                             const int* __restrict__ rp,
                                             const float* __restrict__ el, const float* __restrict__ er,
                                             float* __restrict__ out) {
  int n = blockIdx.x * 4 + (threadIdx.x >> 6);
  if (n >= NN) return;
  int lane = threadIdx.x & 63;
  int start = rp[n], end = rp[n + 1];
  float2* o = (float2*)(out + (size_t)n * 128) + lane;
  if (start == end) { if (!RMW) *o = make_float2(0.f, 0.f); return; }
  float ern = er[n];
  float2 acc = make_float2(0.f, 0.f);
  float s = 0.f;
  for (int e = start; e < end; ++e) {
    int src = (int)srecs[e];
    float l = el[src] + ern;
    l = (l >= 0.f) ? l : 0.2f * l;
    float x = __expf(l);
    s += x;
    u32 hv = *(const u32*)(h + (size_t)src * 128 + 2 * lane);
    acc.x += x * b2f((u16)(hv & 0xffff));
    acc.y += x * b2f((u16)(hv >> 16));
  }
  float inv = 1.f / s;
  float2 prev = RMW ? *o : make_float2(0.f, 0.f);
  prev.x += acc.x * inv; prev.y += acc.y * inv;
  *o = prev;
}

// ---------- bf16 GEMM (up to 3 jobs): C[n][j] = sum_k A[n][k] * W[j*ldw+woff+k], bf16 out
// W: pre-converted bf16, staged to LDS via plain 16B copies (no f2b). A: direct global frags.
struct BJob { const u16* A; const u16* W; int ldw; int woff; u16* C; };
struct BJobs3 { BJob j[3]; };
__global__ __launch_bounds__(256) void gemm_bf_k(BJobs3 jobs) {
  BJob jb = jobs.j[blockIdx.y];
  __shared__ u16 Wlds[128 * SP];
  const int tid = threadIdx.x;
  const int row0 = blockIdx.x * 64;
#pragma unroll
  for (int it = 0; it < 8; ++it) {
    int idx = it * 256 + tid;
    int r = idx >> 4, c = (idx & 15) << 3;
    *(short8*)(&Wlds[r * SP + c]) = *(const short8*)(jb.W + (size_t)r * jb.ldw + jb.woff + c);
  }
  const int lane = tid & 63, wv = tid >> 6;
  const int m16 = lane & 15, quad = lane >> 4;
  int arow = row0 + wv * 16 + m16;
  if (arow >= NN) arow = NN - 1;          // clamp: stores guarded below
  const u16* Ab = jb.A + (size_t)arow * 128 + quad * 8;
  bf16x8 a[4];
#pragma unroll
  for (int kk = 0; kk < 4; ++kk) a[kk] = *(const bf16x8*)(Ab + kk * 32);
  __syncthreads();
  const u16* brow = &Wlds[m16 * SP + quad * 8];
  floatx4 acc[8];
#pragma unroll
  for (int c = 0; c < 8; ++c) acc[c] = floatx4{0.f, 0.f, 0.f, 0.f};
#pragma unroll
  for (int kk = 0; kk < 4; ++kk) {
#pragma unroll
    for (int c = 0; c < 8; ++c) {
      bf16x8 bfr = *(const bf16x8*)(brow + c * 16 * SP + kk * 32);
      acc[c] = __builtin_amdgcn_mfma_f32_16x16x32_bf16(a[kk], bfr, acc[c], 0, 0, 0);
    }
  }
#pragma unroll
  for (int c = 0; c < 8; ++c) {
    int col = c * 16 + m16;
#pragma unroll
    for (int r = 0; r < 4; ++r) {
      int grow = row0 + wv * 16 + quad * 4 + r;
      if (grow < NN) jb.C[(size_t)grow * 128 + col] = f2b(acc[c][r]);
    }
  }
}

// ---------- fused concat-linear-relu (up to 2 jobs):
// C = relu(P + A @ W2cols128.T + c), c = W2@bias precomputed (bias fold), fp32 in/out.
struct FJob { const float* A; const u16* P; float* C; };
struct FJobs2 { FJob j[2]; const u16* W; const float* cvec; };  // W = Wl_bf + 128, ldw 256
__global__ __launch_bounds__(256) void fused_k(FJobs2 jobs) {
  FJob jb = jobs.j[blockIdx.y];
  __shared__ u16 Wlds[128 * SP];
  const int tid = threadIdx.x;
  const int row0 = blockIdx.x * 64;
#pragma unroll
  for (int it = 0; it < 8; ++it) {
    int idx = it * 256 + tid;
    int r = idx >> 4, c = (idx & 15) << 3;
    *(short8*)(&Wlds[r * SP + c]) = *(const short8*)(jobs.W + (size_t)r * 256 + c);
  }
  const int lane = tid & 63, wv = tid >> 6;
  const int m16 = lane & 15, quad = lane >> 4;
  int arow = row0 + wv * 16 + m16;
  if (arow >= NN) arow = NN - 1;          // clamp: stores guarded below
  const float* Ab = jb.A + (size_t)arow * 128 + quad * 8;
  bf16x8 a[4];
#pragma unroll
  for (int kk = 0; kk < 4; ++kk) {
    float4 v0 = *(const float4*)(Ab + kk * 32);
    float4 v1 = *(const float4*)(Ab + kk * 32 + 4);
    short8 s;
    s[0] = (short)f2b(v0.x); s[1] = (short)f2b(v0.y);
    s[2] = (short)f2b(v0.z); s[3] = (short)f2b(v0.w);
    s[4] = (short)f2b(v1.x); s[5] = (short)f2b(v1.y);
    s[6] = (short)f2b(v1.z); s[7] = (short)f2b(v1.w);
    a[kk] = __builtin_bit_cast(bf16x8, s);
  }
  __syncthreads();
  const u16* brow = &Wlds[m16 * SP + quad * 8];
  floatx4 acc[8];
#pragma unroll
  for (int c = 0; c < 8; ++c) acc[c] = floatx4{0.f, 0.f, 0.f, 0.f};
#pragma unroll
  for (int kk = 0; kk < 4; ++kk) {
#pragma unroll
    for (int c = 0; c < 8; ++c) {
      bf16x8 bfr = *(const bf16x8*)(brow + c * 16 * SP + kk * 32);
      acc[c] = __builtin_amdgcn_mfma_f32_16x16x32_bf16(a[kk], bfr, acc[c], 0, 0, 0);
    }
  }
#pragma unroll
  for (int c = 0; c < 8; ++c) {
    int col = c * 16 + m16;
    float cv = jobs.cvec[col];
#pragma unroll
    for (int r = 0; r < 4; ++r) {
      int grow = row0 + wv * 16 + quad * 4 + r;
      if (grow < NN) {
        float v = acc[c][r] + b2f(jb.P[(size_t)grow * 128 + col]) + cv;
        jb.C[(size_t)grow * 128 + col] = fmaxf(v, 0.f);
      }
    }
  }
}

// ---------- r0 cell shortcut: buf_cell = relu(P_cell + W2@bias)   (agg input was all zeros)
__global__ __launch_bounds__(256) void elem_k(const u16* __restrict__ P, const float* __restrict__ vecs,
                                              float* __restrict__ out) {
  __shared__ float cs[128];
  if (threadIdx.x < 128) cs[threadIdx.x] = vecs[6 * 128 + threadIdx.x];
  __syncthreads();
  size_t idx = ((size_t)blockIdx.x * 256 + threadIdx.x) * 8;
  if (idx >= (size_t)NN * 128) return;
  int col = (int)(idx & 127);
  short8 u = *(const short8*)(P + idx);
  float4 o0, o1;
  o0.x = fmaxf(b2f((u16)u[0]) + cs[col + 0], 0.f);
  o0.y = fmaxf(b2f((u16)u[1]) + cs[col + 1], 0.f);
  o0.z = fmaxf(b2f((u16)u[2]) + cs[col + 2], 0.f);
  o0.w = fmaxf(b2f((u16)u[3]) + cs[col + 3], 0.f);
  o1.x = fmaxf(b2f((u16)u[4]) + cs[col + 4], 0.f);
  o1.y = fmaxf(b2f((u16)u[5]) + cs[col + 5], 0.f);
  o1.z = fmaxf(b2f((u16)u[6]) + cs[col + 6], 0.f);
  o1.w = fmaxf(b2f((u16)u[7]) + cs[col + 7], 0.f);
  *(float4*)(out + idx) = o0;
  *(float4*)(out + idx + 4) = o1;
}

extern "C" void kernel_launch(void* const* d_in, const int* in_sizes, int n_in,
                              void* d_out, int out_size, void* d_ws, size_t ws_size,
                              hipStream_t stream) {
  const float* x_net   = (const float*)d_in[0];
  const float* x_cell  = (const float*)d_in[1];
  const float* Wp_net  = (const float*)d_in[2];
  const float* Wp_cell = (const float*)d_in[3];
  const float* Wg[3] = {(const float*)d_in[4], (const float*)d_in[7], (const float*)d_in[10]};
  const float* al[3] = {(const float*)d_in[5], (const float*)d_in[8], (const float*)d_in[11]};
  const float* ar[3] = {(const float*)d_in[6], (const float*)d_in[9], (const float*)d_in[12]};
  const float* Wl    = (const float*)d_in[13];
  const float* bias  = (const float*)d_in[14];
  const int* src[3] = {(const int*)d_in[15], (const int*)d_in[17], (const int*)d_in[19]};
  const int* dst[3] = {(const int*)d_in[16], (const int*)d_in[18], (const int*)d_in[20]};

  char* ws = (char*)d_ws;
  size_t off = 0;
  auto alloc = [&](size_t b) { void* p = ws + off; off = (off + b + 255) & ~(size_t)255; return p; };
  u16*  feat_net  = (u16*)alloc((size_t)NN * 128 * 2);
  u16*  feat_cell = (u16*)alloc((size_t)NN * 128 * 2);
  u16*  hbuf      = (u16*)alloc((size_t)NN * 128 * 2);
  u16*  P_net     = (u16*)alloc((size_t)NN * 128 * 2);
  u16*  P_cell    = (u16*)alloc((size_t)NN * 128 * 2);
  float* buf_net  = (float*)alloc((size_t)NN * 128 * 4);
  float* buf_cell = (float*)alloc((size_t)NN * 128 * 4);
  float* vecs     = (float*)alloc(7 * 128 * 4);
  float* logit    = (float*)alloc((size_t)6 * NN * 4);
  u16*   Wl_bf    = (u16*)alloc((size_t)128 * 256 * 2);
  u16*   Wg_bf    = (u16*)alloc((size_t)3 * 128 * 128 * 2);
  int*   bcnt     = (int*)alloc((size_t)3 * NB * 4);
  int*   bcur     = (int*)alloc((size_t)3 * NB * 4);
  int*   bptr     = (int*)alloc((size_t)3 * (NB + 1) * 4);
  int*   rowptr   = (int*)alloc((size_t)3 * (NN + 1) * 4);
  u32*   recs     = (u32*)alloc((size_t)3 * NE * 4);
  // ~245 MB total

  hipMemsetAsync(bcnt, 0, (size_t)3 * NB * 4, stream);

  conv_k<<<dim3(32, 4), 256, 0, stream>>>(Wl, Wg[0], Wg[1], Wg[2], Wl_bf, Wg_bf);
  proj_k<<<dim3(NN / 16, 2), 256, 0, stream>>>(x_net, x_cell, Wp_net, Wp_cell, feat_net, feat_cell);
  vec_k<<<7, 128, 0, stream>>>(Wg[0], al[0], ar[0], Wg[1], al[1], ar[1], Wg[2], al[2], ar[2], Wl, bias, vecs);
  logits_k<<<dim3((NN + 255) / 256, 2), 256, 0, stream>>>(feat_net, feat_cell, vecs, logit);

  bhist_k<<<dim3(NCH, 3), 256, 0, stream>>>(dst[0], dst[1], dst[2], bcnt);
  bscan_k<<<3, 1024, 0, stream>>>(bcnt, bptr, bcur);
  bscatter_k<<<dim3(NCH, 3), 256, 0, stream>>>(src[0], dst[0], src[1], dst[1], src[2], dst[2],
                                               bcur, recs);
  sort_k<<<dim3(NB, 3), 256, 0, stream>>>(recs, bptr, rowptr);

  const int gb = (NN + 63) / 64;  // 1563
  {
    BJobs3 jobs;
    jobs.j[0] = {feat_net,  Wl_bf, 256, 0, P_net};
    jobs.j[1] = {feat_cell, Wl_bf, 256, 0, P_cell};
    jobs.j[2] = {feat_cell, Wg_bf, 128, 0, hbuf};   // h0 = feat_cell @ Wg0.T
    gemm_bf_k<<<dim3(gb, 3), 256, 0, stream>>>(jobs);
  }

  float* out_f = (float*)d_out;  // [2,N,D] fp32: net then cell
  const int ab = (NN + 3) / 4;   // 25000

  // ---- r = 0 : cell -> net
  agg_k<0><<<ab, 256, 0, stream>>>(hbuf, recs, rowptr, logit, logit + (size_t)NN, buf_net);
  {
    FJobs2 jobs; jobs.W = Wl_bf + 128; jobs.cvec = vecs + 6 * 128;
    jobs.j[0] = {buf_net, P_net, buf_net}; jobs.j[1] = jobs.j[0];
    fused_k<<<dim3(gb, 1), 256, 0, stream>>>(jobs);
  }
  elem_k<<<(NN * 128 / 8 + 255) / 256, 256, 0, stream>>>(P_cell, vecs, buf_cell);

  // ---- r = 1 : net -> cell
  {
    BJobs3 jobs;
    jobs.j[0] = {feat_net, Wg_bf + 16384, 128, 0, hbuf};
    jobs.j[1] = jobs.j[0]; jobs.j[2] = jobs.j[0];
    gemm_bf_k<<<dim3(gb, 1), 256, 0, stream>>>(jobs);
  }
  agg_k<1><<<ab, 256, 0, stream>>>(hbuf, recs + (size_t)NE, rowptr + (NN + 1),
                                   logit + (size_t)2 * NN, logit + (size_t)3 * NN, buf_cell);
  {
    FJobs2 jobs; jobs.W = Wl_bf + 128; jobs.cvec = vecs + 6 * 128;
    jobs.j[0] = {buf_net, P_net, buf_net};
    jobs.j[1] = {buf_cell, P_cell, buf_cell};
    fused_k<<<dim3(gb, 2), 256, 0, stream>>>(jobs);
  }

  // ---- r = 2 : net -> net
  {
    BJobs3 jobs;
    jobs.j[0] = {feat_net, Wg_bf + 32768, 128, 0, hbuf};
    jobs.j[1] = jobs.j[0]; jobs.j[2] = jobs.j[0];
    gemm_bf_k<<<dim3(gb, 1), 256, 0, stream>>>(jobs);
  }
  agg_k<1><<<ab, 256, 0, stream>>>(hbuf, recs + (size_t)2 * NE, rowptr + 2 * (NN + 1),
                                   logit + (size_t)4 * NN, logit + (size_t)5 * NN, buf_net);
  {
    FJobs2 jobs; jobs.W = Wl_bf + 128; jobs.cvec = vecs + 6 * 128;
    jobs.j[0] = {buf_net, P_net, out_f};
    jobs.j[1] = {buf_cell, P_cell, out_f + (size_t)NN * 128};
    fused_k<<<dim3(gb, 2), 256, 0, stream>>>(jobs);
  }
}

// Round 4
// 608.979 us; speedup vs baseline: 1.4437x; 1.1266x over previous
//
#include <hip/hip_runtime.h>
#include <hip/hip_bf16.h>
#include <stdint.h>

// ParaGraph: 2 node types (net/cell, N=100000), 3 relations (E=600000 each), D=128.
// I/O FP32. GEMMs: W pre-converted bf16 + LDS-staged (plain 16B copies), A direct
// global->VGPR bf16 fragments. ALL intermediates bf16 (buf_net/buf_cell). Bias folded
// via c=W2@bias. Block-local LDS radix partition -> per-bucket counting sort ->
// node-CSR; wave-per-node agg with lane-parallel edge weights + shfl broadcast.
#define NN 100000
#define NE 600000
#define SP 136        // GEMM LDS row stride (ushorts): 128 + 8 pad
#define NB 782        // ceil(NN/128) dst buckets of 128 nodes
#define BCAP 1600     // LDS rec capacity per bucket (mean 767, sd ~28)
#define CHUNK 4096    // edges per partition block
#define NCH ((NE + CHUNK - 1) / CHUNK)   // 147

typedef unsigned short u16;
typedef unsigned int u32;
typedef __attribute__((ext_vector_type(8))) short short8;
typedef __attribute__((ext_vector_type(8))) __bf16 bf16x8;
typedef __attribute__((ext_vector_type(4))) float floatx4;

__device__ __forceinline__ float b2f(u16 u) {
  union { float f; u32 i; } c; c.i = ((u32)u) << 16; return c.f;
}
__device__ __forceinline__ u16 f2b(float f) {
  union { float f; u32 i; } c; c.f = f;
  u32 r = c.i + 0x7FFFu + ((c.i >> 16) & 1u);  // RNE
  return (u16)(r >> 16);
}

// ---------- weight pre-conversion to bf16 (once): Wl [128][256], Wg0/1/2 [128][128]
__global__ __launch_bounds__(256) void conv_k(const float* __restrict__ Wl,
                                              const float* __restrict__ Wg0,
                                              const float* __restrict__ Wg1,
                                              const float* __restrict__ Wg2,
                                              u16* __restrict__ Wl_bf, u16* __restrict__ Wg_bf) {
  int y = blockIdx.y;
  const float* src = (y == 0) ? Wl : (y == 1) ? Wg0 : (y == 2) ? Wg1 : Wg2;
  u16* dst = (y == 0) ? Wl_bf : Wg_bf + (size_t)(y - 1) * 16384;
  int n = (y == 0) ? 32768 : 16384;
  int i = (blockIdx.x * 256 + threadIdx.x) * 4;
  if (i >= n) return;
  float4 v = *(const float4*)(src + i);
  ushort4 p; p.x = f2b(v.x); p.y = f2b(v.y); p.z = f2b(v.z); p.w = f2b(v.w);
  *(ushort4*)(dst + i) = p;
}

// ---------- feature projection: feat = x @ Wp.T, [N,16]x[16,128] -> bf16 [N,128]
__global__ __launch_bounds__(256) void proj_k(const float* __restrict__ x_net, const float* __restrict__ x_cell,
                                              const float* __restrict__ Wp_net, const float* __restrict__ Wp_cell,
                                              u16* __restrict__ feat_net, u16* __restrict__ feat_cell) {
  const float* x  = blockIdx.y ? x_cell : x_net;
  const float* Wp = blockIdx.y ? Wp_cell : Wp_net;
  u16* feat       = blockIdx.y ? feat_cell : feat_net;
  __shared__ float Ws[128 * 17];
  __shared__ float xs[16][17];
  int tid = threadIdx.x;
#pragma unroll
  for (int it = 0; it < 8; ++it) {
    int idx = it * 256 + tid;
    int j = idx >> 4, k = idx & 15;
    Ws[j * 17 + k] = Wp[idx];
  }
  int n0 = blockIdx.x * 16;
  { int nn = tid >> 4, k = tid & 15;
    xs[nn][k] = x[(size_t)(n0 + nn) * 16 + k]; }
  __syncthreads();
  int j = tid & 127, g = tid >> 7;
  float acc[8];
#pragma unroll
  for (int r = 0; r < 8; ++r) acc[r] = 0.f;
#pragma unroll
  for (int k = 0; k < 16; ++k) {
    float w = Ws[j * 17 + k];
#pragma unroll
    for (int r = 0; r < 8; ++r) acc[r] += xs[g * 8 + r][k] * w;
  }
#pragma unroll
  for (int r = 0; r < 8; ++r)
    feat[(size_t)(n0 + g * 8 + r) * 128 + j] = f2b(acc[r]);
}

// ---------- vectors: a<6: vecs[a][k] = sum_j Wg[j,k]*(al|ar)[j];  a==6: c[j] = sum_k W2[j,k]*bias[k]
__global__ __launch_bounds__(128) void vec_k(const float* Wg0, const float* al0, const float* ar0,
                                             const float* Wg1, const float* al1, const float* ar1,
                                             const float* Wg2, const float* al2, const float* ar2,
                                             const float* Wl, const float* bias,
                                             float* __restrict__ vecs) {
  int a = blockIdx.x;
  int j = threadIdx.x;
  float s = 0.f;
  if (a < 6) {
    const float* W = (a < 2) ? Wg0 : (a < 4) ? Wg1 : Wg2;
    const float* v = (a == 0) ? al0 : (a == 1) ? ar0 : (a == 2) ? al1 : (a == 3) ? ar1 : (a == 4) ? al2 : ar2;
    for (int i = 0; i < 128; ++i) s += W[i * 128 + j] * v[i];
  } else {
    for (int i = 0; i < 128; ++i) s += Wl[(size_t)j * 256 + 128 + i] * bias[i];
  }
  vecs[a * 128 + j] = s;
}

// ---------- per-node logits, single pass per ntype
// y=0 (net): a=1 er0, a=2 el1, a=4 el2, a=5 er2;  y=1 (cell): a=0 el0, a=3 er1
__global__ __launch_bounds__(256) void logits_k(const u16* __restrict__ feat_net, const u16* __restrict__ feat_cell,
                                                const float* __restrict__ vecs, float* __restrict__ outs) {
  __shared__ float vs[6 * 128];
  int tid = threadIdx.x;
#pragma unroll
  for (int it = 0; it < 3; ++it) vs[it * 256 + tid] = vecs[it * 256 + tid];
  __syncthreads();
  int y = blockIdx.y;
  const u16* f = y ? feat_cell : feat_net;
  int n = blockIdx.x * 256 + tid;
  if (n >= NN) return;
  const u16* row = f + (size_t)n * 128;
  if (y == 0) {
    float s1 = 0.f, s2 = 0.f, s4 = 0.f, s5 = 0.f;
#pragma unroll
    for (int k = 0; k < 128; k += 8) {
      short8 u = *(const short8*)(row + k);
#pragma unroll
      for (int t = 0; t < 8; ++t) {
        float fv = b2f((u16)u[t]);
        s1 += fv * vs[1 * 128 + k + t]; s2 += fv * vs[2 * 128 + k + t];
        s4 += fv * vs[4 * 128 + k + t]; s5 += fv * vs[5 * 128 + k + t];
      }
    }
    outs[(size_t)1 * NN + n] = s1; outs[(size_t)2 * NN + n] = s2;
    outs[(size_t)4 * NN + n] = s4; outs[(size_t)5 * NN + n] = s5;
  } else {
    float s0 = 0.f, s3 = 0.f;
#pragma unroll
    for (int k = 0; k < 128; k += 8) {
      short8 u = *(const short8*)(row + k);
#pragma unroll
      for (int t = 0; t < 8; ++t) {
        float fv = b2f((u16)u[t]);
        s0 += fv * vs[0 * 128 + k + t]; s3 += fv * vs[3 * 128 + k + t];
      }
    }
    outs[(size_t)0 * NN + n] = s0; outs[(size_t)3 * NN + n] = s3;
  }
}

// ---------- histogram over dst buckets, LDS-aggregated
__global__ __launch_bounds__(256) void bhist_k(const int* __restrict__ dst0, const int* __restrict__ dst1,
                                               const int* __restrict__ dst2, int* __restrict__ bcnt) {
  int r = blockIdx.y;
  const int* dst = (r == 0) ? dst0 : (r == 1) ? dst1 : dst2;
  __shared__ int h[NB];
  int tid = threadIdx.x;
  for (int i = tid; i < NB; i += 256) h[i] = 0;
  __syncthreads();
  int e0 = blockIdx.x * CHUNK;
  int cnt = NE - e0; if (cnt > CHUNK) cnt = CHUNK;
  for (int i = tid; i < cnt; i += 256) atomicAdd(&h[((u32)dst[e0 + i]) >> 7], 1);
  __syncthreads();
  for (int b = tid; b < NB; b += 256) {
    int c = h[b];
    if (c) atomicAdd(&bcnt[(size_t)r * NB + b], c);
  }
}

// ---------- exclusive scan of NB counters per relation (one 1024-block each)
__global__ __launch_bounds__(1024) void bscan_k(const int* __restrict__ bcnt, int* __restrict__ bptr,
                                                int* __restrict__ bcur) {
  int r = blockIdx.x, t = threadIdx.x;
  const int* c = bcnt + (size_t)r * NB;
  int* p = bptr + (size_t)r * (NB + 1);
  int* cur = bcur + (size_t)r * NB;
  int v = (t < NB) ? c[t] : 0;
  __shared__ int ss[1024];
  ss[t] = v; __syncthreads();
  for (int off = 1; off < 1024; off <<= 1) {
    int u = (t >= off) ? ss[t - off] : 0;
    __syncthreads();
    ss[t] += u;
    __syncthreads();
  }
  if (t < NB) { int e = ss[t] - v; p[t] = e; cur[t] = e; }
  if (t == 1023) p[NB] = ss[1023];
}

// ---------- block-local radix partition: LDS-bin a 4096-edge chunk by dst bucket,
// reserve contiguous global space per (block,bucket), stream out coalesced runs.
__global__ __launch_bounds__(256) void bscatter_k(const int* __restrict__ src0, const int* __restrict__ dst0,
                                                  const int* __restrict__ src1, const int* __restrict__ dst1,
                                                  const int* __restrict__ src2, const int* __restrict__ dst2,
                                                  int* __restrict__ bcur, u32* __restrict__ recs) {
  int r = blockIdx.y;
  const int* src = (r == 0) ? src0 : (r == 1) ? src1 : src2;
  const int* dst = (r == 0) ? dst0 : (r == 1) ? dst1 : dst2;
  __shared__ int hist[NB];
  __shared__ int lstart[NB];
  __shared__ int lcur[NB];
  __shared__ int badj[NB];
  __shared__ u32 rbuf[CHUNK];
  __shared__ u16 kbuf[CHUNK];
  __shared__ int ss[256];
  int tid = threadIdx.x;
  int e0 = blockIdx.x * CHUNK;
  int cnt = NE - e0; if (cnt > CHUNK) cnt = CHUNK;

  for (int i = tid; i < NB; i += 256) hist[i] = 0;
  __syncthreads();
  // phase 1: local histogram
  for (int i = tid; i < cnt; i += 256) atomicAdd(&hist[((u32)dst[e0 + i]) >> 7], 1);
  __syncthreads();
  // phase 2: local exclusive scan (256 threads x 4 bins) + global reservation
  int loc[4]; int s = 0;
  int base4 = tid * 4;
#pragma unroll
  for (int j = 0; j < 4; ++j) {
    int idx = base4 + j;
    int v = (idx < NB) ? hist[idx] : 0;
    loc[j] = s; s += v;
  }
  ss[tid] = s; __syncthreads();
  for (int off = 1; off < 256; off <<= 1) {
    int u = (tid >= off) ? ss[tid - off] : 0;
    __syncthreads();
    ss[tid] += u;
    __syncthreads();
  }
  int ex = ss[tid] - s;
#pragma unroll
  for (int j = 0; j < 4; ++j) {
    int idx = base4 + j;
    if (idx < NB) { int e = ex + loc[j]; lstart[idx] = e; lcur[idx] = e; }
  }
  __syncthreads();
  for (int b = tid; b < NB; b += 256) {
    int c = hist[b];
    int g = 0;
    if (c) g = atomicAdd(&bcur[(size_t)r * NB + b], c);
    badj[b] = g - lstart[b];
  }
  __syncthreads();
  // phase 3: reorder records into LDS, sorted by bucket
  for (int i = tid; i < cnt; i += 256) {
    int dN = dst[e0 + i], sN = src[e0 + i];
    int b = ((u32)dN) >> 7;
    int pos = atomicAdd(&lcur[b], 1);
    rbuf[pos] = ((u32)(dN & 127) << 17) | (u32)sN;
    kbuf[pos] = (u16)b;
  }
  __syncthreads();
  // phase 4: coalesced run-writes (consecutive slots in a bucket -> consecutive addrs)
  u32* out = recs + (size_t)r * NE;
  for (int i = tid; i < cnt; i += 256) {
    int b = kbuf[i];
    out[badj[b] + i] = rbuf[i];
  }
}

// ---------- per-bucket LDS counting sort (in place) + node rowptr
__global__ __launch_bounds__(256) void sort_k(u32* __restrict__ recs, const int* __restrict__ bptr,
                                              int* __restrict__ rowptr) {
  int r = blockIdx.y, b = blockIdx.x, tid = threadIdx.x;
  const int* p = bptr + (size_t)r * (NB + 1);
  u32* rec = recs + (size_t)r * NE;
  int* rp = rowptr + (size_t)r * (NN + 1);
  int base = p[b], end = p[b + 1];
  int cnt = end - base; if (cnt > BCAP) cnt = BCAP;   // statistically impossible to exceed
  __shared__ u32 rs[BCAP];
  __shared__ int hist[128], excl[128], cur[128];
  for (int i = tid; i < cnt; i += 256) rs[i] = rec[base + i];
  if (tid < 128) hist[tid] = 0;
  __syncthreads();
  for (int i = tid; i < cnt; i += 256) atomicAdd(&hist[rs[i] >> 17], 1);
  __syncthreads();
  if (tid < 128) cur[tid] = hist[tid];
  __syncthreads();
  for (int off = 1; off < 128; off <<= 1) {
    int v = 0;
    if (tid < 128 && tid >= off) v = cur[tid - off];
    __syncthreads();
    if (tid < 128) cur[tid] += v;
    __syncthreads();
  }
  if (tid < 128) {
    int e = cur[tid] - hist[tid];      // exclusive
    excl[tid] = e;
    int node = b * 128 + tid;
    if (node < NN) rp[node] = base + e;
  }
  if (b == NB - 1 && tid == 0) rp[NN] = p[NB];
  if (tid < 128) cur[tid] = excl[tid];
  __syncthreads();
  for (int i = tid; i < cnt; i += 256) {
    u32 v = rs[i];
    int pos = atomicAdd(&cur[v >> 17], 1);
    rec[base + pos] = v & 0x1FFFFu;    // store src only, node-sorted
  }
}

// ---------- aggregation: one wave per dst node, bf16 out (+RMW)
// lanes 0..deg-1 compute edge weights in parallel (one coalesced load per up-to-64
// edges); shfl-broadcast (w,src) per edge; h-row loads issue back-to-back.
template<int RMW>
__global__ __launch_bounds__(256) void agg_k(const u16* __restrict__ h, const u32* __restrict__ srecs,
                                             const int* __restrict__ rp,
                                             const float* __restrict__ el, const float* __restrict__ er,
                                             u16* __restrict__ out) {
  int n = blockIdx.x * 4 + (threadIdx.x >> 6);
  if (n >= NN) return;
  int lane = threadIdx.x & 63;
  int start = rp[n], end = rp[n + 1];
  u32* o = (u32*)(out + (size_t)n * 128) + lane;
  if (start == end) { if (!RMW) *o = 0u; return; }
  float ern = er[n];
  float2 acc = make_float2(0.f, 0.f);
  float sl = 0.f;
  const u32* h32 = (const u32*)h + lane;
  for (int base = start; base < end; base += 64) {
    int m = end - base; if (m > 64) m = 64;
    int srci = 0; float w = 0.f;
    if (lane < m) {
      srci = (int)srecs[base + lane];
      float l = el[srci] + ern;
      l = (l >= 0.f) ? l : 0.2f * l;
      w = __expf(l);
    }
    sl += w;
    for (int i = 0; i < m; ++i) {
      float x = __shfl(w, i);
      int sv = __shfl(srci, i);
      u32 hv = h32[(size_t)sv * 64];
      acc.x += x * b2f((u16)(hv & 0xffffu));
      acc.y += x * b2f((u16)(hv >> 16));
    }
  }
  float s = sl;
#pragma unroll
  for (int off = 32; off > 0; off >>= 1) s += __shfl_xor(s, off);
  float inv = 1.f / s;
  float px = 0.f, py = 0.f;
  if (RMW) { u32 pv = *o; px = b2f((u16)(pv & 0xffffu)); py = b2f((u16)(pv >> 16)); }
  px += acc.x * inv; py += acc.y * inv;
  *o = ((u32)f2b(py) << 16) | (u32)f2b(px);
}

// ---------- bf16 GEMM (up to 3 jobs): C[n][j] = sum_k A[n][k] * W[j*ldw+woff+k], bf16 out
// W: pre-converted bf16, staged to LDS via plain 16B copies. A: direct global frags.
struct BJob { const u16* A; const u16* W; int ldw; int woff; u16* C; };
struct BJobs3 { BJob j[3]; };
__global__ __launch_bounds__(256) void gemm_bf_k(BJobs3 jobs) {
  BJob jb = jobs.j[blockIdx.y];
  __shared__ u16 Wlds[128 * SP];
  const int tid = threadIdx.x;
  const int row0 = blockIdx.x * 64;
#pragma unroll
  for (int it = 0; it < 8; ++it) {
    int idx = it * 256 + tid;
    int r = idx >> 4, c = (idx & 15) << 3;
    *(short8*)(&Wlds[r * SP + c]) = *(const short8*)(jb.W + (size_t)r * jb.ldw + jb.woff + c);
  }
  const int lane = tid & 63, wv = tid >> 6;
  const int m16 = lane & 15, quad = lane >> 4;
  int arow = row0 + wv * 16 + m16;
  if (arow >= NN) arow = NN - 1;          // clamp: stores guarded below
  const u16* Ab = jb.A + (size_t)arow * 128 + quad * 8;
  bf16x8 a[4];
#pragma unroll
  for (int kk = 0; kk < 4; ++kk) a[kk] = *(const bf16x8*)(Ab + kk * 32);
  __syncthreads();
  const u16* brow = &Wlds[m16 * SP + quad * 8];
  floatx4 acc[8];
#pragma unroll
  for (int c = 0; c < 8; ++c) acc[c] = floatx4{0.f, 0.f, 0.f, 0.f};
#pragma unroll
  for (int kk = 0; kk < 4; ++kk) {
#pragma unroll
    for (int c = 0; c < 8; ++c) {
      bf16x8 bfr = *(const bf16x8*)(brow + c * 16 * SP + kk * 32);
      acc[c] = __builtin_amdgcn_mfma_f32_16x16x32_bf16(a[kk], bfr, acc[c], 0, 0, 0);
    }
  }
#pragma unroll
  for (int c = 0; c < 8; ++c) {
    int col = c * 16 + m16;
#pragma unroll
    for (int r = 0; r < 4; ++r) {
      int grow = row0 + wv * 16 + quad * 4 + r;
      if (grow < NN) jb.C[(size_t)grow * 128 + col] = f2b(acc[c][r]);
    }
  }
}

// ---------- fused concat-linear-relu (up to 2 jobs):
// C = relu(P + A @ W2cols128.T + c), c = W2@bias precomputed (bias fold).
// A bf16 direct loads; C bf16 intermediate or fp32 final (template).
struct FJob { const u16* A; const u16* P; void* C; };
struct FJobs2 { FJob j[2]; const u16* W; const float* cvec; };  // W = Wl_bf + 128, ldw 256
template<int FINAL>
__global__ __launch_bounds__(256) void fused_k(FJobs2 jobs) {
  FJob jb = jobs.j[blockIdx.y];
  __shared__ u16 Wlds[128 * SP];
  const int tid = threadIdx.x;
  const int row0 = blockIdx.x * 64;
#pragma unroll
  for (int it = 0; it < 8; ++it) {
    int idx = it * 256 + tid;
    int r = idx >> 4, c = (idx & 15) << 3;
    *(short8*)(&Wlds[r * SP + c]) = *(const short8*)(jobs.W + (size_t)r * 256 + c);
  }
  const int lane = tid & 63, wv = tid >> 6;
  const int m16 = lane & 15, quad = lane >> 4;
  int arow = row0 + wv * 16 + m16;
  if (arow >= NN) arow = NN - 1;          // clamp: stores guarded below
  const u16* Ab = jb.A + (size_t)arow * 128 + quad * 8;
  bf16x8 a[4];
#pragma unroll
  for (int kk = 0; kk < 4; ++kk) a[kk] = *(const bf16x8*)(Ab + kk * 32);
  __syncthreads();
  const u16* brow = &Wlds[m16 * SP + quad * 8];
  floatx4 acc[8];
#pragma unroll
  for (int c = 0; c < 8; ++c) acc[c] = floatx4{0.f, 0.f, 0.f, 0.f};
#pragma unroll
  for (int kk = 0; kk < 4; ++kk) {
#pragma unroll
    for (int c = 0; c < 8; ++c) {
      bf16x8 bfr = *(const bf16x8*)(brow + c * 16 * SP + kk * 32);
      acc[c] = __builtin_amdgcn_mfma_f32_16x16x32_bf16(a[kk], bfr, acc[c], 0, 0, 0);
    }
  }
#pragma unroll
  for (int c = 0; c < 8; ++c) {
    int col = c * 16 + m16;
    float cv = jobs.cvec[col];
#pragma unroll
    for (int r = 0; r < 4; ++r) {
      int grow = row0 + wv * 16 + quad * 4 + r;
      if (grow < NN) {
        float v = acc[c][r] + b2f(jb.P[(size_t)grow * 128 + col]) + cv;
        v = fmaxf(v, 0.f);
        if (FINAL) ((float*)jb.C)[(size_t)grow * 128 + col] = v;
        else       ((u16*)jb.C)[(size_t)grow * 128 + col] = f2b(v);
      }
    }
  }
}

// ---------- r0 cell shortcut: buf_cell = relu(P_cell + W2@bias), bf16 out
__global__ __launch_bounds__(256) void elem_k(const u16* __restrict__ P, const float* __restrict__ vecs,
                                              u16* __restrict__ out) {
  __shared__ float cs[128];
  if (threadIdx.x < 128) cs[threadIdx.x] = vecs[6 * 128 + threadIdx.x];
  __syncthreads();
  size_t idx = ((size_t)blockIdx.x * 256 + threadIdx.x) * 8;
  if (idx >= (size_t)NN * 128) return;
  int col = (int)(idx & 127);
  short8 u = *(const short8*)(P + idx);
  short8 w;
#pragma unroll
  for (int t = 0; t < 8; ++t)
    w[t] = (short)f2b(fmaxf(b2f((u16)u[t]) + cs[col + t], 0.f));
  *(short8*)(out + idx) = w;
}

extern "C" void kernel_launch(void* const* d_in, const int* in_sizes, int n_in,
                              void* d_out, int out_size, void* d_ws, size_t ws_size,
                              hipStream_t stream) {
  const float* x_net   = (const float*)d_in[0];
  const float* x_cell  = (const float*)d_in[1];
  const float* Wp_net  = (const float*)d_in[2];
  const float* Wp_cell = (const float*)d_in[3];
  const float* Wg[3] = {(const float*)d_in[4], (const float*)d_in[7], (const float*)d_in[10]};
  const float* al[3] = {(const float*)d_in[5], (const float*)d_in[8], (const float*)d_in[11]};
  const float* ar[3] = {(const float*)d_in[6], (const float*)d_in[9], (const float*)d_in[12]};
  const float* Wl    = (const float*)d_in[13];
  const float* bias  = (const float*)d_in[14];
  const int* src[3] = {(const int*)d_in[15], (const int*)d_in[17], (const int*)d_in[19]};
  const int* dst[3] = {(const int*)d_in[16], (const int*)d_in[18], (const int*)d_in[20]};

  char* ws = (char*)d_ws;
  size_t off = 0;
  auto alloc = [&](size_t b) { void* p = ws + off; off = (off + b + 255) & ~(size_t)255; return p; };
  u16*  feat_net  = (u16*)alloc((size_t)NN * 128 * 2);
  u16*  feat_cell = (u16*)alloc((size_t)NN * 128 * 2);
  u16*  hbuf      = (u16*)alloc((size_t)NN * 128 * 2);
  u16*  P_net     = (u16*)alloc((size_t)NN * 128 * 2);
  u16*  P_cell    = (u16*)alloc((size_t)NN * 128 * 2);
  u16*  buf_net   = (u16*)alloc((size_t)NN * 128 * 2);
  u16*  buf_cell  = (u16*)alloc((size_t)NN * 128 * 2);
  float* vecs     = (float*)alloc(7 * 128 * 4);
  float* logit    = (float*)alloc((size_t)6 * NN * 4);
  u16*   Wl_bf    = (u16*)alloc((size_t)128 * 256 * 2);
  u16*   Wg_bf    = (u16*)alloc((size_t)3 * 128 * 128 * 2);
  int*   bcnt     = (int*)alloc((size_t)3 * NB * 4);
  int*   bcur     = (int*)alloc((size_t)3 * NB * 4);
  int*   bptr     = (int*)alloc((size_t)3 * (NB + 1) * 4);
  int*   rowptr   = (int*)alloc((size_t)3 * (NN + 1) * 4);
  u32*   recs     = (u32*)alloc((size_t)3 * NE * 4);

  hipMemsetAsync(bcnt, 0, (size_t)3 * NB * 4, stream);

  conv_k<<<dim3(32, 4), 256, 0, stream>>>(Wl, Wg[0], Wg[1], Wg[2], Wl_bf, Wg_bf);
  proj_k<<<dim3(NN / 16, 2), 256, 0, stream>>>(x_net, x_cell, Wp_net, Wp_cell, feat_net, feat_cell);
  vec_k<<<7, 128, 0, stream>>>(Wg[0], al[0], ar[0], Wg[1], al[1], ar[1], Wg[2], al[2], ar[2], Wl, bias, vecs);
  logits_k<<<dim3((NN + 255) / 256, 2), 256, 0, stream>>>(feat_net, feat_cell, vecs, logit);

  bhist_k<<<dim3(NCH, 3), 256, 0, stream>>>(dst[0], dst[1], dst[2], bcnt);
  bscan_k<<<3, 1024, 0, stream>>>(bcnt, bptr, bcur);
  bscatter_k<<<dim3(NCH, 3), 256, 0, stream>>>(src[0], dst[0], src[1], dst[1], src[2], dst[2],
                                               bcur, recs);
  sort_k<<<dim3(NB, 3), 256, 0, stream>>>(recs, bptr, rowptr);

  const int gb = (NN + 63) / 64;  // 1563
  {
    BJobs3 jobs;
    jobs.j[0] = {feat_net,  Wl_bf, 256, 0, P_net};
    jobs.j[1] = {feat_cell, Wl_bf, 256, 0, P_cell};
    jobs.j[2] = {feat_cell, Wg_bf, 128, 0, hbuf};   // h0 = feat_cell @ Wg0.T
    gemm_bf_k<<<dim3(gb, 3), 256, 0, stream>>>(jobs);
  }

  float* out_f = (float*)d_out;  // [2,N,D] fp32: net then cell
  const int ab = (NN + 3) / 4;   // 25000

  // ---- r = 0 : cell -> net
  agg_k<0><<<ab, 256, 0, stream>>>(hbuf, recs, rowptr, logit, logit + (size_t)NN, buf_net);
  {
    FJobs2 jobs; jobs.W = Wl_bf + 128; jobs.cvec = vecs + 6 * 128;
    jobs.j[0] = {buf_net, P_net, buf_net}; jobs.j[1] = jobs.j[0];
    fused_k<0><<<dim3(gb, 1), 256, 0, stream>>>(jobs);
  }
  elem_k<<<(NN * 128 / 8 + 255) / 256, 256, 0, stream>>>(P_cell, vecs, buf_cell);

  // ---- r = 1 : net -> cell
  {
    BJobs3 jobs;
    jobs.j[0] = {feat_net, Wg_bf + 16384, 128, 0, hbuf};
    jobs.j[1] = jobs.j[0]; jobs.j[2] = jobs.j[0];
    gemm_bf_k<<<dim3(gb, 1), 256, 0, stream>>>(jobs);
  }
  agg_k<1><<<ab, 256, 0, stream>>>(hbuf, recs + (size_t)NE, rowptr + (NN + 1),
                                   logit + (size_t)2 * NN, logit + (size_t)3 * NN, buf_cell);
  {
    FJobs2 jobs; jobs.W = Wl_bf + 128; jobs.cvec = vecs + 6 * 128;
    jobs.j[0] = {buf_net, P_net, buf_net};
    jobs.j[1] = {buf_cell, P_cell, buf_cell};
    fused_k<0><<<dim3(gb, 2), 256, 0, stream>>>(jobs);
  }

  // ---- r = 2 : net -> net
  {
    BJobs3 jobs;
    jobs.j[0] = {feat_net, Wg_bf + 32768, 128, 0, hbuf};
    jobs.j[1] = jobs.j[0]; jobs.j[2] = jobs.j[0];
    gemm_bf_k<<<dim3(gb, 1), 256, 0, stream>>>(jobs);
  }
  agg_k<1><<<ab, 256, 0, stream>>>(hbuf, recs + (size_t)2 * NE, rowptr + 2 * (NN + 1),
                                   logit + (size_t)4 * NN, logit + (size_t)5 * NN, buf_net);
  {
    FJobs2 jobs; jobs.W = Wl_bf + 128; jobs.cvec = vecs + 6 * 128;
    jobs.j[0] = {buf_net, P_net, out_f};
    jobs.j[1] = {buf_cell, P_cell, out_f + (size_t)NN * 128};
    fused_k<1><<<dim3(gb, 2), 256, 0, stream>>>(jobs);
  }
}

// Round 5
// 517.877 us; speedup vs baseline: 1.6977x; 1.1759x over previous
//
#include <hip/hip_runtime.h>
#include <hip/hip_bf16.h>
#include <stdint.h>

// ParaGraph: 2 node types (net/cell, N=100000), 3 relations (E=600000 each), D=128.
// I/O FP32. GEMMs: W pre-converted bf16 + LDS-staged, A direct global bf16 fragments,
// all 5 node-GEMMs in ONE dispatch. All intermediates bf16. Bias folded via c=W2@bias.
// Block-local LDS radix partition -> per-bucket counting sort -> node-CSR.
// Aggregation: 16-lane group per node (4 nodes/wave), lane-parallel edge weights,
// group-shfl broadcast, 16B h-row fragments.
#define NN 100000
#define NE 600000
#define SP 136        // GEMM LDS row stride (ushorts): 128 + 8 pad
#define NB 782        // ceil(NN/128) dst buckets of 128 nodes
#define BCAP 1600     // LDS rec capacity per bucket (mean 767, sd ~28)
#define CHUNK 4096    // edges per partition block
#define NCH ((NE + CHUNK - 1) / CHUNK)   // 147

typedef unsigned short u16;
typedef unsigned int u32;
typedef __attribute__((ext_vector_type(8))) short short8;
typedef __attribute__((ext_vector_type(8))) __bf16 bf16x8;
typedef __attribute__((ext_vector_type(4))) float floatx4;

__device__ __forceinline__ float b2f(u16 u) {
  union { float f; u32 i; } c; c.i = ((u32)u) << 16; return c.f;
}
__device__ __forceinline__ u16 f2b(float f) {
  union { float f; u32 i; } c; c.f = f;
  u32 r = c.i + 0x7FFFu + ((c.i >> 16) & 1u);  // RNE
  return (u16)(r >> 16);
}

// ---------- weight pre-conversion to bf16 (once): Wl [128][256], Wg0/1/2 [128][128]
__global__ __launch_bounds__(256) void conv_k(const float* __restrict__ Wl,
                                              const float* __restrict__ Wg0,
                                              const float* __restrict__ Wg1,
                                              const float* __restrict__ Wg2,
                                              u16* __restrict__ Wl_bf, u16* __restrict__ Wg_bf) {
  int y = blockIdx.y;
  const float* src = (y == 0) ? Wl : (y == 1) ? Wg0 : (y == 2) ? Wg1 : Wg2;
  u16* dst = (y == 0) ? Wl_bf : Wg_bf + (size_t)(y - 1) * 16384;
  int n = (y == 0) ? 32768 : 16384;
  int i = (blockIdx.x * 256 + threadIdx.x) * 4;
  if (i >= n) return;
  float4 v = *(const float4*)(src + i);
  ushort4 p; p.x = f2b(v.x); p.y = f2b(v.y); p.z = f2b(v.z); p.w = f2b(v.w);
  *(ushort4*)(dst + i) = p;
}

// ---------- feature projection: feat = x @ Wp.T, [N,16]x[16,128] -> bf16 [N,128]
__global__ __launch_bounds__(256) void proj_k(const float* __restrict__ x_net, const float* __restrict__ x_cell,
                                              const float* __restrict__ Wp_net, const float* __restrict__ Wp_cell,
                                              u16* __restrict__ feat_net, u16* __restrict__ feat_cell) {
  const float* x  = blockIdx.y ? x_cell : x_net;
  const float* Wp = blockIdx.y ? Wp_cell : Wp_net;
  u16* feat       = blockIdx.y ? feat_cell : feat_net;
  __shared__ float Ws[128 * 17];
  __shared__ float xs[16][17];
  int tid = threadIdx.x;
#pragma unroll
  for (int it = 0; it < 8; ++it) {
    int idx = it * 256 + tid;
    int j = idx >> 4, k = idx & 15;
    Ws[j * 17 + k] = Wp[idx];
  }
  int n0 = blockIdx.x * 16;
  { int nn = tid >> 4, k = tid & 15;
    xs[nn][k] = x[(size_t)(n0 + nn) * 16 + k]; }
  __syncthreads();
  int j = tid & 127, g = tid >> 7;
  float acc[8];
#pragma unroll
  for (int r = 0; r < 8; ++r) acc[r] = 0.f;
#pragma unroll
  for (int k = 0; k < 16; ++k) {
    float w = Ws[j * 17 + k];
#pragma unroll
    for (int r = 0; r < 8; ++r) acc[r] += xs[g * 8 + r][k] * w;
  }
#pragma unroll
  for (int r = 0; r < 8; ++r)
    feat[(size_t)(n0 + g * 8 + r) * 128 + j] = f2b(acc[r]);
}

// ---------- vectors: a<6: vecs[a][k] = sum_j Wg[j,k]*(al|ar)[j];  a==6: c[j] = sum_k W2[j,k]*bias[k]
__global__ __launch_bounds__(128) void vec_k(const float* Wg0, const float* al0, const float* ar0,
                                             const float* Wg1, const float* al1, const float* ar1,
                                             const float* Wg2, const float* al2, const float* ar2,
                                             const float* Wl, const float* bias,
                                             float* __restrict__ vecs) {
  int a = blockIdx.x;
  int j = threadIdx.x;
  float s = 0.f;
  if (a < 6) {
    const float* W = (a < 2) ? Wg0 : (a < 4) ? Wg1 : Wg2;
    const float* v = (a == 0) ? al0 : (a == 1) ? ar0 : (a == 2) ? al1 : (a == 3) ? ar1 : (a == 4) ? al2 : ar2;
    for (int i = 0; i < 128; ++i) s += W[i * 128 + j] * v[i];
  } else {
    for (int i = 0; i < 128; ++i) s += Wl[(size_t)j * 256 + 128 + i] * bias[i];
  }
  vecs[a * 128 + j] = s;
}

// ---------- per-node logits, single pass per ntype
// y=0 (net): a=1 er0, a=2 el1, a=4 el2, a=5 er2;  y=1 (cell): a=0 el0, a=3 er1
__global__ __launch_bounds__(256) void logits_k(const u16* __restrict__ feat_net, const u16* __restrict__ feat_cell,
                                                const float* __restrict__ vecs, float* __restrict__ outs) {
  __shared__ float vs[6 * 128];
  int tid = threadIdx.x;
#pragma unroll
  for (int it = 0; it < 3; ++it) vs[it * 256 + tid] = vecs[it * 256 + tid];
  __syncthreads();
  int y = blockIdx.y;
  const u16* f = y ? feat_cell : feat_net;
  int n = blockIdx.x * 256 + tid;
  if (n >= NN) return;
  const u16* row = f + (size_t)n * 128;
  if (y == 0) {
    float s1 = 0.f, s2 = 0.f, s4 = 0.f, s5 = 0.f;
#pragma unroll
    for (int k = 0; k < 128; k += 8) {
      short8 u = *(const short8*)(row + k);
#pragma unroll
      for (int t = 0; t < 8; ++t) {
        float fv = b2f((u16)u[t]);
        s1 += fv * vs[1 * 128 + k + t]; s2 += fv * vs[2 * 128 + k + t];
        s4 += fv * vs[4 * 128 + k + t]; s5 += fv * vs[5 * 128 + k + t];
      }
    }
    outs[(size_t)1 * NN + n] = s1; outs[(size_t)2 * NN + n] = s2;
    outs[(size_t)4 * NN + n] = s4; outs[(size_t)5 * NN + n] = s5;
  } else {
    float s0 = 0.f, s3 = 0.f;
#pragma unroll
    for (int k = 0; k < 128; k += 8) {
      short8 u = *(const short8*)(row + k);
#pragma unroll
      for (int t = 0; t < 8; ++t) {
        float fv = b2f((u16)u[t]);
        s0 += fv * vs[0 * 128 + k + t]; s3 += fv * vs[3 * 128 + k + t];
      }
    }
    outs[(size_t)0 * NN + n] = s0; outs[(size_t)3 * NN + n] = s3;
  }
}

// ---------- histogram over dst buckets, LDS-aggregated
__global__ __launch_bounds__(256) void bhist_k(const int* __restrict__ dst0, const int* __restrict__ dst1,
                                               const int* __restrict__ dst2, int* __restrict__ bcnt) {
  int r = blockIdx.y;
  const int* dst = (r == 0) ? dst0 : (r == 1) ? dst1 : dst2;
  __shared__ int h[NB];
  int tid = threadIdx.x;
  for (int i = tid; i < NB; i += 256) h[i] = 0;
  __syncthreads();
  int e0 = blockIdx.x * CHUNK;
  int cnt = NE - e0; if (cnt > CHUNK) cnt = CHUNK;
  for (int i = tid; i < cnt; i += 256) atomicAdd(&h[((u32)dst[e0 + i]) >> 7], 1);
  __syncthreads();
  for (int b = tid; b < NB; b += 256) {
    int c = h[b];
    if (c) atomicAdd(&bcnt[(size_t)r * NB + b], c);
  }
}

// ---------- exclusive scan of NB counters per relation (one 1024-block each)
__global__ __launch_bounds__(1024) void bscan_k(const int* __restrict__ bcnt, int* __restrict__ bptr,
                                                int* __restrict__ bcur) {
  int r = blockIdx.x, t = threadIdx.x;
  const int* c = bcnt + (size_t)r * NB;
  int* p = bptr + (size_t)r * (NB + 1);
  int* cur = bcur + (size_t)r * NB;
  int v = (t < NB) ? c[t] : 0;
  __shared__ int ss[1024];
  ss[t] = v; __syncthreads();
  for (int off = 1; off < 1024; off <<= 1) {
    int u = (t >= off) ? ss[t - off] : 0;
    __syncthreads();
    ss[t] += u;
    __syncthreads();
  }
  if (t < NB) { int e = ss[t] - v; p[t] = e; cur[t] = e; }
  if (t == 1023) p[NB] = ss[1023];
}

// ---------- block-local radix partition: LDS-bin a 4096-edge chunk by dst bucket,
// reserve contiguous global space per (block,bucket), stream out coalesced runs.
__global__ __launch_bounds__(256) void bscatter_k(const int* __restrict__ src0, const int* __restrict__ dst0,
                                                  const int* __restrict__ src1, const int* __restrict__ dst1,
                                                  const int* __restrict__ src2, const int* __restrict__ dst2,
                                                  int* __restrict__ bcur, u32* __restrict__ recs) {
  int r = blockIdx.y;
  const int* src = (r == 0) ? src0 : (r == 1) ? src1 : src2;
  const int* dst = (r == 0) ? dst0 : (r == 1) ? dst1 : dst2;
  __shared__ int hist[NB];
  __shared__ int lstart[NB];
  __shared__ int lcur[NB];
  __shared__ int badj[NB];
  __shared__ u32 rbuf[CHUNK];
  __shared__ u16 kbuf[CHUNK];
  __shared__ int ss[256];
  int tid = threadIdx.x;
  int e0 = blockIdx.x * CHUNK;
  int cnt = NE - e0; if (cnt > CHUNK) cnt = CHUNK;

  for (int i = tid; i < NB; i += 256) hist[i] = 0;
  __syncthreads();
  // phase 1: local histogram
  for (int i = tid; i < cnt; i += 256) atomicAdd(&hist[((u32)dst[e0 + i]) >> 7], 1);
  __syncthreads();
  // phase 2: local exclusive scan (256 threads x 4 bins) + global reservation
  int loc[4]; int s = 0;
  int base4 = tid * 4;
#pragma unroll
  for (int j = 0; j < 4; ++j) {
    int idx = base4 + j;
    int v = (idx < NB) ? hist[idx] : 0;
    loc[j] = s; s += v;
  }
  ss[tid] = s; __syncthreads();
  for (int off = 1; off < 256; off <<= 1) {
    int u = (tid >= off) ? ss[tid - off] : 0;
    __syncthreads();
    ss[tid] += u;
    __syncthreads();
  }
  int ex = ss[tid] - s;
#pragma unroll
  for (int j = 0; j < 4; ++j) {
    int idx = base4 + j;
    if (idx < NB) { int e = ex + loc[j]; lstart[idx] = e; lcur[idx] = e; }
  }
  __syncthreads();
  for (int b = tid; b < NB; b += 256) {
    int c = hist[b];
    int g = 0;
    if (c) g = atomicAdd(&bcur[(size_t)r * NB + b], c);
    badj[b] = g - lstart[b];
  }
  __syncthreads();
  // phase 3: reorder records into LDS, sorted by bucket
  for (int i = tid; i < cnt; i += 256) {
    int dN = dst[e0 + i], sN = src[e0 + i];
    int b = ((u32)dN) >> 7;
    int pos = atomicAdd(&lcur[b], 1);
    rbuf[pos] = ((u32)(dN & 127) << 17) | (u32)sN;
    kbuf[pos] = (u16)b;
  }
  __syncthreads();
  // phase 4: coalesced run-writes (consecutive slots in a bucket -> consecutive addrs)
  u32* out = recs + (size_t)r * NE;
  for (int i = tid; i < cnt; i += 256) {
    int b = kbuf[i];
    out[badj[b] + i] = rbuf[i];
  }
}

// ---------- per-bucket LDS counting sort (in place) + node rowptr
__global__ __launch_bounds__(256) void sort_k(u32* __restrict__ recs, const int* __restrict__ bptr,
                                              int* __restrict__ rowptr) {
  int r = blockIdx.y, b = blockIdx.x, tid = threadIdx.x;
  const int* p = bptr + (size_t)r * (NB + 1);
  u32* rec = recs + (size_t)r * NE;
  int* rp = rowptr + (size_t)r * (NN + 1);
  int base = p[b], end = p[b + 1];
  int cnt = end - base; if (cnt > BCAP) cnt = BCAP;   // statistically impossible to exceed
  __shared__ u32 rs[BCAP];
  __shared__ int hist[128], excl[128], cur[128];
  for (int i = tid; i < cnt; i += 256) rs[i] = rec[base + i];
  if (tid < 128) hist[tid] = 0;
  __syncthreads();
  for (int i = tid; i < cnt; i += 256) atomicAdd(&hist[rs[i] >> 17], 1);
  __syncthreads();
  if (tid < 128) cur[tid] = hist[tid];
  __syncthreads();
  for (int off = 1; off < 128; off <<= 1) {
    int v = 0;
    if (tid < 128 && tid >= off) v = cur[tid - off];
    __syncthreads();
    if (tid < 128) cur[tid] += v;
    __syncthreads();
  }
  if (tid < 128) {
    int e = cur[tid] - hist[tid];      // exclusive
    excl[tid] = e;
    int node = b * 128 + tid;
    if (node < NN) rp[node] = base + e;
  }
  if (b == NB - 1 && tid == 0) rp[NN] = p[NB];
  if (tid < 128) cur[tid] = excl[tid];
  __syncthreads();
  for (int i = tid; i < cnt; i += 256) {
    u32 v = rs[i];
    int pos = atomicAdd(&cur[v >> 17], 1);
    rec[base + pos] = v & 0x1FFFFu;    // store src only, node-sorted
  }
}

// ---------- aggregation: 16-lane group per node (4 nodes/wave, 16 nodes/block)
// lane sub covers 8 cols (16B h-row fragment); lanes 0..m-1 of group compute edge
// weights; group-shfl broadcast (w,src); group tree-reduce denominator; bf16 RMW out.
template<int RMW>
__global__ __launch_bounds__(256) void agg_k(const u16* __restrict__ h, const u32* __restrict__ srecs,
                                             const int* __restrict__ rp,
                                             const float* __restrict__ el, const float* __restrict__ er,
                                             u16* __restrict__ out) {
  int tid = threadIdx.x;
  int sub = tid & 15;
  int n = blockIdx.x * 16 + (tid >> 4);   // NN = 6250*16, no tail
  int start = rp[n], end = rp[n + 1];
  u16* orow = out + (size_t)n * 128 + sub * 8;
  if (start == end) {
    if (!RMW) *(short8*)orow = short8{0, 0, 0, 0, 0, 0, 0, 0};
    return;
  }
  float ern = er[n];
  float acc[8];
#pragma unroll
  for (int t = 0; t < 8; ++t) acc[t] = 0.f;
  float sl = 0.f;
  const u16* hsub = h + sub * 8;
  for (int base = start; base < end; base += 16) {
    int m = end - base; if (m > 16) m = 16;
    int srci = 0; float w = 0.f;
    if (sub < m) {
      srci = (int)srecs[base + sub];
      float l = el[srci] + ern;
      l = (l >= 0.f) ? l : 0.2f * l;
      w = __expf(l);
    }
    sl += w;
    for (int i = 0; i < m; ++i) {
      float x = __shfl(w, i, 16);
      int sv = __shfl(srci, i, 16);
      short8 hv = *(const short8*)(hsub + (size_t)sv * 128);
#pragma unroll
      for (int t = 0; t < 8; ++t) acc[t] += x * b2f((u16)hv[t]);
    }
  }
  float s = sl;
#pragma unroll
  for (int off = 8; off > 0; off >>= 1) s += __shfl_xor(s, off, 16);
  float inv = 1.f / s;
  short8 o;
  if (RMW) {
    short8 pv = *(const short8*)orow;
#pragma unroll
    for (int t = 0; t < 8; ++t) o[t] = (short)f2b(b2f((u16)pv[t]) + acc[t] * inv);
  } else {
#pragma unroll
    for (int t = 0; t < 8; ++t) o[t] = (short)f2b(acc[t] * inv);
  }
  *(short8*)orow = o;
}

// ---------- bf16 GEMM (up to 5 jobs): C[n][j] = sum_k A[n][k] * W[j*ldw+woff+k], bf16 out
// W: pre-converted bf16, staged to LDS via plain 16B copies. A: direct global frags.
struct BJob { const u16* A; const u16* W; int ldw; int woff; u16* C; };
struct BJobs5 { BJob j[5]; };
__global__ __launch_bounds__(256) void gemm_bf_k(BJobs5 jobs) {
  BJob jb = jobs.j[blockIdx.y];
  __shared__ u16 Wlds[128 * SP];
  const int tid = threadIdx.x;
  const int row0 = blockIdx.x * 64;
#pragma unroll
  for (int it = 0; it < 8; ++it) {
    int idx = it * 256 + tid;
    int r = idx >> 4, c = (idx & 15) << 3;
    *(short8*)(&Wlds[r * SP + c]) = *(const short8*)(jb.W + (size_t)r * jb.ldw + jb.woff + c);
  }
  const int lane = tid & 63, wv = tid >> 6;
  const int m16 = lane & 15, quad = lane >> 4;
  int arow = row0 + wv * 16 + m16;
  if (arow >= NN) arow = NN - 1;          // clamp: stores guarded below
  const u16* Ab = jb.A + (size_t)arow * 128 + quad * 8;
  bf16x8 a[4];
#pragma unroll
  for (int kk = 0; kk < 4; ++kk) a[kk] = *(const bf16x8*)(Ab + kk * 32);
  __syncthreads();
  const u16* brow = &Wlds[m16 * SP + quad * 8];
  floatx4 acc[8];
#pragma unroll
  for (int c = 0; c < 8; ++c) acc[c] = floatx4{0.f, 0.f, 0.f, 0.f};
#pragma unroll
  for (int kk = 0; kk < 4; ++kk) {
#pragma unroll
    for (int c = 0; c < 8; ++c) {
      bf16x8 bfr = *(const bf16x8*)(brow + c * 16 * SP + kk * 32);
      acc[c] = __builtin_amdgcn_mfma_f32_16x16x32_bf16(a[kk], bfr, acc[c], 0, 0, 0);
    }
  }
#pragma unroll
  for (int c = 0; c < 8; ++c) {
    int col = c * 16 + m16;
#pragma unroll
    for (int r = 0; r < 4; ++r) {
      int grow = row0 + wv * 16 + quad * 4 + r;
      if (grow < NN) jb.C[(size_t)grow * 128 + col] = f2b(acc[c][r]);
    }
  }
}

// ---------- fused concat-linear-relu (up to 2 jobs):
// C = relu(P + A @ W2cols128.T + c), c = W2@bias precomputed (bias fold).
// A bf16 direct loads; C bf16 intermediate or fp32 final (template).
struct FJob { const u16* A; const u16* P; void* C; };
struct FJobs2 { FJob j[2]; const u16* W; const float* cvec; };  // W = Wl_bf + 128, ldw 256
template<int FINAL>
__global__ __launch_bounds__(256) void fused_k(FJobs2 jobs) {
  FJob jb = jobs.j[blockIdx.y];
  __shared__ u16 Wlds[128 * SP];
  const int tid = threadIdx.x;
  const int row0 = blockIdx.x * 64;
#pragma unroll
  for (int it = 0; it < 8; ++it) {
    int idx = it * 256 + tid;
    int r = idx >> 4, c = (idx & 15) << 3;
    *(short8*)(&Wlds[r * SP + c]) = *(const short8*)(jobs.W + (size_t)r * 256 + c);
  }
  const int lane = tid & 63, wv = tid >> 6;
  const int m16 = lane & 15, quad = lane >> 4;
  int arow = row0 + wv * 16 + m16;
  if (arow >= NN) arow = NN - 1;          // clamp: stores guarded below
  const u16* Ab = jb.A + (size_t)arow * 128 + quad * 8;
  bf16x8 a[4];
#pragma unroll
  for (int kk = 0; kk < 4; ++kk) a[kk] = *(const bf16x8*)(Ab + kk * 32);
  __syncthreads();
  const u16* brow = &Wlds[m16 * SP + quad * 8];
  floatx4 acc[8];
#pragma unroll
  for (int c = 0; c < 8; ++c) acc[c] = floatx4{0.f, 0.f, 0.f, 0.f};
#pragma unroll
  for (int kk = 0; kk < 4; ++kk) {
#pragma unroll
    for (int c = 0; c < 8; ++c) {
      bf16x8 bfr = *(const bf16x8*)(brow + c * 16 * SP + kk * 32);
      acc[c] = __builtin_amdgcn_mfma_f32_16x16x32_bf16(a[kk], bfr, acc[c], 0, 0, 0);
    }
  }
#pragma unroll
  for (int c = 0; c < 8; ++c) {
    int col = c * 16 + m16;
    float cv = jobs.cvec[col];
#pragma unroll
    for (int r = 0; r < 4; ++r) {
      int grow = row0 + wv * 16 + quad * 4 + r;
      if (grow < NN) {
        float v = acc[c][r] + b2f(jb.P[(size_t)grow * 128 + col]) + cv;
        v = fmaxf(v, 0.f);
        if (FINAL) ((float*)jb.C)[(size_t)grow * 128 + col] = v;
        else       ((u16*)jb.C)[(size_t)grow * 128 + col] = f2b(v);
      }
    }
  }
}

// ---------- r0 cell shortcut: buf_cell = relu(P_cell + W2@bias), bf16 out
__global__ __launch_bounds__(256) void elem_k(const u16* __restrict__ P, const float* __restrict__ vecs,
                                              u16* __restrict__ out) {
  __shared__ float cs[128];
  if (threadIdx.x < 128) cs[threadIdx.x] = vecs[6 * 128 + threadIdx.x];
  __syncthreads();
  size_t idx = ((size_t)blockIdx.x * 256 + threadIdx.x) * 8;
  if (idx >= (size_t)NN * 128) return;
  int col = (int)(idx & 127);
  short8 u = *(const short8*)(P + idx);
  short8 w;
#pragma unroll
  for (int t = 0; t < 8; ++t)
    w[t] = (short)f2b(fmaxf(b2f((u16)u[t]) + cs[col + t], 0.f));
  *(short8*)(out + idx) = w;
}

extern "C" void kernel_launch(void* const* d_in, const int* in_sizes, int n_in,
                              void* d_out, int out_size, void* d_ws, size_t ws_size,
                              hipStream_t stream) {
  const float* x_net   = (const float*)d_in[0];
  const float* x_cell  = (const float*)d_in[1];
  const float* Wp_net  = (const float*)d_in[2];
  const float* Wp_cell = (const float*)d_in[3];
  const float* Wg[3] = {(const float*)d_in[4], (const float*)d_in[7], (const float*)d_in[10]};
  const float* al[3] = {(const float*)d_in[5], (const float*)d_in[8], (const float*)d_in[11]};
  const float* ar[3] = {(const float*)d_in[6], (const float*)d_in[9], (const float*)d_in[12]};
  const float* Wl    = (const float*)d_in[13];
  const float* bias  = (const float*)d_in[14];
  const int* src[3] = {(const int*)d_in[15], (const int*)d_in[17], (const int*)d_in[19]};
  const int* dst[3] = {(const int*)d_in[16], (const int*)d_in[18], (const int*)d_in[20]};

  char* ws = (char*)d_ws;
  size_t off = 0;
  auto alloc = [&](size_t b) { void* p = ws + off; off = (off + b + 255) & ~(size_t)255; return p; };
  u16*  feat_net  = (u16*)alloc((size_t)NN * 128 * 2);
  u16*  feat_cell = (u16*)alloc((size_t)NN * 128 * 2);
  u16*  hbuf0     = (u16*)alloc((size_t)NN * 128 * 2);
  u16*  hbuf1     = (u16*)alloc((size_t)NN * 128 * 2);
  u16*  hbuf2     = (u16*)alloc((size_t)NN * 128 * 2);
  u16*  P_net     = (u16*)alloc((size_t)NN * 128 * 2);
  u16*  P_cell    = (u16*)alloc((size_t)NN * 128 * 2);
  u16*  buf_net   = (u16*)alloc((size_t)NN * 128 * 2);
  u16*  buf_cell  = (u16*)alloc((size_t)NN * 128 * 2);
  float* vecs     = (float*)alloc(7 * 128 * 4);
  float* logit    = (float*)alloc((size_t)6 * NN * 4);
  u16*   Wl_bf    = (u16*)alloc((size_t)128 * 256 * 2);
  u16*   Wg_bf    = (u16*)alloc((size_t)3 * 128 * 128 * 2);
  int*   bcnt     = (int*)alloc((size_t)3 * NB * 4);
  int*   bcur     = (int*)alloc((size_t)3 * NB * 4);
  int*   bptr     = (int*)alloc((size_t)3 * (NB + 1) * 4);
  int*   rowptr   = (int*)alloc((size_t)3 * (NN + 1) * 4);
  u32*   recs     = (u32*)alloc((size_t)3 * NE * 4);

  hipMemsetAsync(bcnt, 0, (size_t)3 * NB * 4, stream);

  conv_k<<<dim3(32, 4), 256, 0, stream>>>(Wl, Wg[0], Wg[1], Wg[2], Wl_bf, Wg_bf);
  proj_k<<<dim3(NN / 16, 2), 256, 0, stream>>>(x_net, x_cell, Wp_net, Wp_cell, feat_net, feat_cell);
  vec_k<<<7, 128, 0, stream>>>(Wg[0], al[0], ar[0], Wg[1], al[1], ar[1], Wg[2], al[2], ar[2], Wl, bias, vecs);
  logits_k<<<dim3((NN + 255) / 256, 2), 256, 0, stream>>>(feat_net, feat_cell, vecs, logit);

  bhist_k<<<dim3(NCH, 3), 256, 0, stream>>>(dst[0], dst[1], dst[2], bcnt);
  bscan_k<<<3, 1024, 0, stream>>>(bcnt, bptr, bcur);
  bscatter_k<<<dim3(NCH, 3), 256, 0, stream>>>(src[0], dst[0], src[1], dst[1], src[2], dst[2],
                                               bcur, recs);
  sort_k<<<dim3(NB, 3), 256, 0, stream>>>(recs, bptr, rowptr);

  const int gb = (NN + 63) / 64;  // 1563
  {
    BJobs5 jobs;
    jobs.j[0] = {feat_net,  Wl_bf,          256, 0, P_net};
    jobs.j[1] = {feat_cell, Wl_bf,          256, 0, P_cell};
    jobs.j[2] = {feat_cell, Wg_bf,          128, 0, hbuf0};  // h0 = feat_cell @ Wg0.T
    jobs.j[3] = {feat_net,  Wg_bf + 16384,  128, 0, hbuf1};  // h1 = feat_net  @ Wg1.T
    jobs.j[4] = {feat_net,  Wg_bf + 32768,  128, 0, hbuf2};  // h2 = feat_net  @ Wg2.T
    gemm_bf_k<<<dim3(gb, 5), 256, 0, stream>>>(jobs);
  }

  float* out_f = (float*)d_out;  // [2,N,D] fp32: net then cell
  const int ab = NN / 16;        // 6250

  // ---- r = 0 : cell -> net
  agg_k<0><<<ab, 256, 0, stream>>>(hbuf0, recs, rowptr, logit, logit + (size_t)NN, buf_net);
  {
    FJobs2 jobs; jobs.W = Wl_bf + 128; jobs.cvec = vecs + 6 * 128;
    jobs.j[0] = {buf_net, P_net, buf_net}; jobs.j[1] = jobs.j[0];
    fused_k<0><<<dim3(gb, 1), 256, 0, stream>>>(jobs);
  }
  elem_k<<<(NN * 128 / 8 + 255) / 256, 256, 0, stream>>>(P_cell, vecs, buf_cell);

  // ---- r = 1 : net -> cell
  agg_k<1><<<ab, 256, 0, stream>>>(hbuf1, recs + (size_t)NE, rowptr + (NN + 1),
                                   logit + (size_t)2 * NN, logit + (size_t)3 * NN, buf_cell);
  {
    FJobs2 jobs; jobs.W = Wl_bf + 128; jobs.cvec = vecs + 6 * 128;
    jobs.j[0] = {buf_net, P_net, buf_net};
    jobs.j[1] = {buf_cell, P_cell, buf_cell};
    fused_k<0><<<dim3(gb, 2), 256, 0, stream>>>(jobs);
  }

  // ---- r = 2 : net -> net
  agg_k<1><<<ab, 256, 0, stream>>>(hbuf2, recs + (size_t)2 * NE, rowptr + 2 * (NN + 1),
                                   logit + (size_t)4 * NN, logit + (size_t)5 * NN, buf_net);
  {
    FJobs2 jobs; jobs.W = Wl_bf + 128; jobs.cvec = vecs + 6 * 128;
    jobs.j[0] = {buf_net, P_net, out_f};
    jobs.j[1] = {buf_cell, P_cell, out_f + (size_t)NN * 128};
    fused_k<1><<<dim3(gb, 2), 256, 0, stream>>>(jobs);
  }
}

// Round 6
// 503.459 us; speedup vs baseline: 1.7463x; 1.0286x over previous
//
#include <hip/hip_runtime.h>
#include <hip/hip_bf16.h>
#include <stdint.h>

// ParaGraph: 2 node types (net/cell, N=100000), 3 relations (E=600000 each), D=128.
// I/O FP32. All intermediates bf16. W pre-converted bf16; GEMMs hold A-fragments in
// registers and iterate W tiles (stage->MFMA->store->barrier), A read once per ntype.
// Independent pipeline stages packed into single dispatches (block-range split):
// prep(proj|conv|vec|zero), logbh(logits|bhist), sortgemm(sort|GEMMs),
// aggelem(agg0|elem), fusedagg(agg1|fused0), aggfused(agg2|fused2cell).
#define NN 100000
#define NE 600000
#define SP 136        // GEMM LDS row stride (ushorts): 128 + 8 pad
#define NB 782        // ceil(NN/128) dst buckets of 128 nodes
#define BCAP 1600     // LDS rec capacity per bucket (mean 767, sd ~28)
#define CHUNK 4096    // edges per partition block
#define NCH 147       // ceil(NE/CHUNK)
#define GB 1563       // ceil(NN/64) GEMM row-blocks
#define AB 6250       // NN/16 agg blocks (exact)

typedef unsigned short u16;
typedef unsigned int u32;
typedef __attribute__((ext_vector_type(8))) short short8;
typedef __attribute__((ext_vector_type(8))) __bf16 bf16x8;
typedef __attribute__((ext_vector_type(4))) float floatx4;

__device__ __forceinline__ float b2f(u16 u) {
  union { float f; u32 i; } c; c.i = ((u32)u) << 16; return c.f;
}
__device__ __forceinline__ u16 f2b(float f) {
  union { float f; u32 i; } c; c.f = f;
  u32 r = c.i + 0x7FFFu + ((c.i >> 16) & 1u);  // RNE
  return (u16)(r >> 16);
}

// ================= device bodies =================

// one W-tile pass: stage W (plain 16B copies) -> sync -> MFMA -> store C
__device__ __forceinline__ void gemm_w(const u16* __restrict__ W, int ldw, u16* __restrict__ C,
                                       u16* lds, int tid, int row0, const bf16x8* a,
                                       int m16, int quad, int wv) {
#pragma unroll
  for (int it = 0; it < 8; ++it) {
    int idx = it * 256 + tid;
    int r = idx >> 4, c = (idx & 15) << 3;
    *(short8*)(&lds[r * SP + c]) = *(const short8*)(W + (size_t)r * ldw + c);
  }
  __syncthreads();
  const u16* brow = &lds[m16 * SP + quad * 8];
  floatx4 acc[8];
#pragma unroll
  for (int c = 0; c < 8; ++c) acc[c] = floatx4{0.f, 0.f, 0.f, 0.f};
#pragma unroll
  for (int kk = 0; kk < 4; ++kk) {
#pragma unroll
    for (int c = 0; c < 8; ++c) {
      bf16x8 bfr = *(const bf16x8*)(brow + c * 16 * SP + kk * 32);
      acc[c] = __builtin_amdgcn_mfma_f32_16x16x32_bf16(a[kk], bfr, acc[c], 0, 0, 0);
    }
  }
#pragma unroll
  for (int c = 0; c < 8; ++c) {
    int col = c * 16 + m16;
#pragma unroll
    for (int r = 0; r < 4; ++r) {
      int grow = row0 + wv * 16 + quad * 4 + r;
      if (grow < NN) C[(size_t)grow * 128 + col] = f2b(acc[c][r]);
    }
  }
}

// fused concat-linear-relu: C = relu(P + A @ W2.T + c)  (bias fold via cvec)
template<int FINAL>
__device__ __forceinline__ void fused_body(int blk, int tid, const u16* __restrict__ A,
                                           const u16* __restrict__ P, void* __restrict__ C,
                                           const u16* __restrict__ W, const float* __restrict__ cvec,
                                           u16* Wlds) {
  const int row0 = blk * 64;
#pragma unroll
  for (int it = 0; it < 8; ++it) {
    int idx = it * 256 + tid;
    int r = idx >> 4, c = (idx & 15) << 3;
    *(short8*)(&Wlds[r * SP + c]) = *(const short8*)(W + (size_t)r * 256 + c);
  }
  const int lane = tid & 63, wv = tid >> 6;
  const int m16 = lane & 15, quad = lane >> 4;
  int arow = row0 + wv * 16 + m16;
  if (arow >= NN) arow = NN - 1;          // clamp: stores guarded below
  const u16* Ab = A + (size_t)arow * 128 + quad * 8;
  bf16x8 a[4];
#pragma unroll
  for (int kk = 0; kk < 4; ++kk) a[kk] = *(const bf16x8*)(Ab + kk * 32);
  __syncthreads();
  const u16* brow = &Wlds[m16 * SP + quad * 8];
  floatx4 acc[8];
#pragma unroll
  for (int c = 0; c < 8; ++c) acc[c] = floatx4{0.f, 0.f, 0.f, 0.f};
#pragma unroll
  for (int kk = 0; kk < 4; ++kk) {
#pragma unroll
    for (int c = 0; c < 8; ++c) {
      bf16x8 bfr = *(const bf16x8*)(brow + c * 16 * SP + kk * 32);
      acc[c] = __builtin_amdgcn_mfma_f32_16x16x32_bf16(a[kk], bfr, acc[c], 0, 0, 0);
    }
  }
#pragma unroll
  for (int c = 0; c < 8; ++c) {
    int col = c * 16 + m16;
    float cv = cvec[col];
#pragma unroll
    for (int r = 0; r < 4; ++r) {
      int grow = row0 + wv * 16 + quad * 4 + r;
      if (grow < NN) {
        float v = acc[c][r] + b2f(P[(size_t)grow * 128 + col]) + cv;
        v = fmaxf(v, 0.f);
        if (FINAL) ((float*)C)[(size_t)grow * 128 + col] = v;
        else       ((u16*)C)[(size_t)grow * 128 + col] = f2b(v);
      }
    }
  }
}

// aggregation: 16-lane group per node; lane-parallel edge weights; group-shfl broadcast
template<int RMW>
__device__ __forceinline__ void agg_body(int nb, int tid, const u16* __restrict__ h,
                                         const u32* __restrict__ srecs, const int* __restrict__ rp,
                                         const float* __restrict__ el, const float* __restrict__ er,
                                         u16* __restrict__ out) {
  int sub = tid & 15;
  int n = nb * 16 + (tid >> 4);   // NN = 6250*16, no tail
  int start = rp[n], end = rp[n + 1];
  u16* orow = out + (size_t)n * 128 + sub * 8;
  if (start == end) {
    if (!RMW) *(short8*)orow = short8{0, 0, 0, 0, 0, 0, 0, 0};
    return;
  }
  float ern = er[n];
  float acc[8];
#pragma unroll
  for (int t = 0; t < 8; ++t) acc[t] = 0.f;
  float sl = 0.f;
  const u16* hsub = h + sub * 8;
  for (int base = start; base < end; base += 16) {
    int m = end - base; if (m > 16) m = 16;
    int srci = 0; float w = 0.f;
    if (sub < m) {
      srci = (int)srecs[base + sub];
      float l = el[srci] + ern;
      l = (l >= 0.f) ? l : 0.2f * l;
      w = __expf(l);
    }
    sl += w;
    for (int i = 0; i < m; ++i) {
      float x = __shfl(w, i, 16);
      int sv = __shfl(srci, i, 16);
      short8 hv = *(const short8*)(hsub + (size_t)sv * 128);
#pragma unroll
      for (int t = 0; t < 8; ++t) acc[t] += x * b2f((u16)hv[t]);
    }
  }
  float s = sl;
#pragma unroll
  for (int off = 8; off > 0; off >>= 1) s += __shfl_xor(s, off, 16);
  float inv = 1.f / s;
  short8 o;
  if (RMW) {
    short8 pv = *(const short8*)orow;
#pragma unroll
    for (int t = 0; t < 8; ++t) o[t] = (short)f2b(b2f((u16)pv[t]) + acc[t] * inv);
  } else {
#pragma unroll
    for (int t = 0; t < 8; ++t) o[t] = (short)f2b(acc[t] * inv);
  }
  *(short8*)orow = o;
}

// ================= kernels =================

// prep: proj (12500) | conv (128) | vec (7) | zero bcnt (3)
__global__ __launch_bounds__(256) void prep_k(const float* __restrict__ x_net, const float* __restrict__ x_cell,
                                              const float* __restrict__ Wp_net, const float* __restrict__ Wp_cell,
                                              u16* __restrict__ feat_net, u16* __restrict__ feat_cell,
                                              const float* __restrict__ Wl, const float* __restrict__ Wg0,
                                              const float* __restrict__ Wg1, const float* __restrict__ Wg2,
                                              u16* __restrict__ Wl_bf, u16* __restrict__ Wg_bf,
                                              const float* al0, const float* ar0, const float* al1,
                                              const float* ar1, const float* al2, const float* ar2,
                                              const float* bias, float* __restrict__ vecs,
                                              int* __restrict__ bcnt) {
  int bid = blockIdx.x, tid = threadIdx.x;
  if (bid < 2 * AB) {
    // ---- proj: feat = x @ Wp.T
    int y = bid >= AB;
    int bx = y ? bid - AB : bid;
    const float* x  = y ? x_cell : x_net;
    const float* Wp = y ? Wp_cell : Wp_net;
    u16* feat       = y ? feat_cell : feat_net;
    __shared__ float Ws[128 * 17];
    __shared__ float xs[16][17];
#pragma unroll
    for (int it = 0; it < 8; ++it) {
      int idx = it * 256 + tid;
      int j = idx >> 4, k = idx & 15;
      Ws[j * 17 + k] = Wp[idx];
    }
    int n0 = bx * 16;
    { int nn = tid >> 4, k = tid & 15;
      xs[nn][k] = x[(size_t)(n0 + nn) * 16 + k]; }
    __syncthreads();
    int j = tid & 127, g = tid >> 7;
    float acc[8];
#pragma unroll
    for (int r = 0; r < 8; ++r) acc[r] = 0.f;
#pragma unroll
    for (int k = 0; k < 16; ++k) {
      float w = Ws[j * 17 + k];
#pragma unroll
      for (int r = 0; r < 8; ++r) acc[r] += xs[g * 8 + r][k] * w;
    }
#pragma unroll
    for (int r = 0; r < 8; ++r)
      feat[(size_t)(n0 + g * 8 + r) * 128 + j] = f2b(acc[r]);
  } else if (bid < 2 * AB + 128) {
    // ---- conv: weights fp32 -> bf16
    int cid = bid - 2 * AB;
    int y = cid >> 5, bx = cid & 31;
    const float* src = (y == 0) ? Wl : (y == 1) ? Wg0 : (y == 2) ? Wg1 : Wg2;
    u16* dst = (y == 0) ? Wl_bf : Wg_bf + (size_t)(y - 1) * 16384;
    int n = (y == 0) ? 32768 : 16384;
    int i = (bx * 256 + tid) * 4;
    if (i >= n) return;
    float4 v = *(const float4*)(src + i);
    ushort4 p; p.x = f2b(v.x); p.y = f2b(v.y); p.z = f2b(v.z); p.w = f2b(v.w);
    *(ushort4*)(dst + i) = p;
  } else if (bid < 2 * AB + 135) {
    // ---- vec: a<6: Wg.T @ (al|ar); a==6: W2 @ bias
    int a = bid - (2 * AB + 128);
    if (tid >= 128) return;
    int j = tid;
    float s = 0.f;
    if (a < 6) {
      const float* W = (a < 2) ? Wg0 : (a < 4) ? Wg1 : Wg2;
      const float* v = (a == 0) ? al0 : (a == 1) ? ar0 : (a == 2) ? al1 : (a == 3) ? ar1 : (a == 4) ? al2 : ar2;
      for (int i = 0; i < 128; ++i) s += W[i * 128 + j] * v[i];
    } else {
      for (int i = 0; i < 128; ++i) s += Wl[(size_t)j * 256 + 128 + i] * bias[i];
    }
    vecs[a * 128 + j] = s;
  } else {
    // ---- zero bcnt
    int r = bid - (2 * AB + 135);
    for (int i = tid; i < NB; i += 256) bcnt[(size_t)r * NB + i] = 0;
  }
}

// logbh: logits (782) | bhist (441)
__global__ __launch_bounds__(256) void logbh_k(const u16* __restrict__ feat_net, const u16* __restrict__ feat_cell,
                                               const float* __restrict__ vecs, float* __restrict__ outs,
                                               const int* __restrict__ dst0, const int* __restrict__ dst1,
                                               const int* __restrict__ dst2, int* __restrict__ bcnt) {
  __shared__ int sm[NB];
  int bid = blockIdx.x, tid = threadIdx.x;
  if (bid < 782) {
    float* vs = (float*)sm;
#pragma unroll
    for (int it = 0; it < 3; ++it) vs[it * 256 + tid] = vecs[it * 256 + tid];
    __syncthreads();
    int y = bid >= 391;
    int bx = y ? bid - 391 : bid;
    const u16* f = y ? feat_cell : feat_net;
    int n = bx * 256 + tid;
    if (n >= NN) return;
    const u16* row = f + (size_t)n * 128;
    if (y == 0) {
      float s1 = 0.f, s2 = 0.f, s4 = 0.f, s5 = 0.f;
#pragma unroll
      for (int k = 0; k < 128; k += 8) {
        short8 u = *(const short8*)(row + k);
#pragma unroll
        for (int t = 0; t < 8; ++t) {
          float fv = b2f((u16)u[t]);
          s1 += fv * vs[1 * 128 + k + t]; s2 += fv * vs[2 * 128 + k + t];
          s4 += fv * vs[4 * 128 + k + t]; s5 += fv * vs[5 * 128 + k + t];
        }
      }
      outs[(size_t)1 * NN + n] = s1; outs[(size_t)2 * NN + n] = s2;
      outs[(size_t)4 * NN + n] = s4; outs[(size_t)5 * NN + n] = s5;
    } else {
      float s0 = 0.f, s3 = 0.f;
#pragma unroll
      for (int k = 0; k < 128; k += 8) {
        short8 u = *(const short8*)(row + k);
#pragma unroll
        for (int t = 0; t < 8; ++t) {
          float fv = b2f((u16)u[t]);
          s0 += fv * vs[0 * 128 + k + t]; s3 += fv * vs[3 * 128 + k + t];
        }
      }
      outs[(size_t)0 * NN + n] = s0; outs[(size_t)3 * NN + n] = s3;
    }
  } else {
    int e = bid - 782;
    int r = e / NCH, bx = e % NCH;
    const int* dst = (r == 0) ? dst0 : (r == 1) ? dst1 : dst2;
    for (int i = tid; i < NB; i += 256) sm[i] = 0;
    __syncthreads();
    int e0 = bx * CHUNK;
    int cnt = NE - e0; if (cnt > CHUNK) cnt = CHUNK;
    for (int i = tid; i < cnt; i += 256) atomicAdd(&sm[((u32)dst[e0 + i]) >> 7], 1);
    __syncthreads();
    for (int b = tid; b < NB; b += 256) {
      int c = sm[b];
      if (c) atomicAdd(&bcnt[(size_t)r * NB + b], c);
    }
  }
}

// ---------- exclusive scan of NB counters per relation (one 1024-block each)
__global__ __launch_bounds__(1024) void bscan_k(const int* __restrict__ bcnt, int* __restrict__ bptr,
                                                int* __restrict__ bcur) {
  int r = blockIdx.x, t = threadIdx.x;
  const int* c = bcnt + (size_t)r * NB;
  int* p = bptr + (size_t)r * (NB + 1);
  int* cur = bcur + (size_t)r * NB;
  int v = (t < NB) ? c[t] : 0;
  __shared__ int ss[1024];
  ss[t] = v; __syncthreads();
  for (int off = 1; off < 1024; off <<= 1) {
    int u = (t >= off) ? ss[t - off] : 0;
    __syncthreads();
    ss[t] += u;
    __syncthreads();
  }
  if (t < NB) { int e = ss[t] - v; p[t] = e; cur[t] = e; }
  if (t == 1023) p[NB] = ss[1023];
}

// ---------- block-local radix partition (coalesced run-writes)
__global__ __launch_bounds__(256) void bscatter_k(const int* __restrict__ src0, const int* __restrict__ dst0,
                                                  const int* __restrict__ src1, const int* __restrict__ dst1,
                                                  const int* __restrict__ src2, const int* __restrict__ dst2,
                                                  int* __restrict__ bcur, u32* __restrict__ recs) {
  int r = blockIdx.y;
  const int* src = (r == 0) ? src0 : (r == 1) ? src1 : src2;
  const int* dst = (r == 0) ? dst0 : (r == 1) ? dst1 : dst2;
  __shared__ int hist[NB];
  __shared__ int lstart[NB];
  __shared__ int lcur[NB];
  __shared__ int badj[NB];
  __shared__ u32 rbuf[CHUNK];
  __shared__ u16 kbuf[CHUNK];
  __shared__ int ss[256];
  int tid = threadIdx.x;
  int e0 = blockIdx.x * CHUNK;
  int cnt = NE - e0; if (cnt > CHUNK) cnt = CHUNK;

  for (int i = tid; i < NB; i += 256) hist[i] = 0;
  __syncthreads();
  for (int i = tid; i < cnt; i += 256) atomicAdd(&hist[((u32)dst[e0 + i]) >> 7], 1);
  __syncthreads();
  int loc[4]; int s = 0;
  int base4 = tid * 4;
#pragma unroll
  for (int j = 0; j < 4; ++j) {
    int idx = base4 + j;
    int v = (idx < NB) ? hist[idx] : 0;
    loc[j] = s; s += v;
  }
  ss[tid] = s; __syncthreads();
  for (int off = 1; off < 256; off <<= 1) {
    int u = (tid >= off) ? ss[tid - off] : 0;
    __syncthreads();
    ss[tid] += u;
    __syncthreads();
  }
  int ex = ss[tid] - s;
#pragma unroll
  for (int j = 0; j < 4; ++j) {
    int idx = base4 + j;
    if (idx < NB) { int e = ex + loc[j]; lstart[idx] = e; lcur[idx] = e; }
  }
  __syncthreads();
  for (int b = tid; b < NB; b += 256) {
    int c = hist[b];
    int g = 0;
    if (c) g = atomicAdd(&bcur[(size_t)r * NB + b], c);
    badj[b] = g - lstart[b];
  }
  __syncthreads();
  for (int i = tid; i < cnt; i += 256) {
    int dN = dst[e0 + i], sN = src[e0 + i];
    int b = ((u32)dN) >> 7;
    int pos = atomicAdd(&lcur[b], 1);
    rbuf[pos] = ((u32)(dN & 127) << 17) | (u32)sN;
    kbuf[pos] = (u16)b;
  }
  __syncthreads();
  u32* out = recs + (size_t)r * NE;
  for (int i = tid; i < cnt; i += 256) {
    int b = kbuf[i];
    out[badj[b] + i] = rbuf[i];
  }
}

// sortgemm: per-bucket counting sort (2346) | A-shared multi-W GEMMs (3126)
__global__ __launch_bounds__(256) void sortgemm_k(u32* __restrict__ recs, const int* __restrict__ bptr,
                                                  int* __restrict__ rowptr,
                                                  const u16* __restrict__ feat_net, const u16* __restrict__ feat_cell,
                                                  const u16* __restrict__ Wl_bf, const u16* __restrict__ Wg_bf,
                                                  u16* __restrict__ P_net, u16* __restrict__ P_cell,
                                                  u16* __restrict__ h0, u16* __restrict__ h1, u16* __restrict__ h2) {
  __shared__ u32 smem[128 * SP / 2];   // 34816 B, shared by both paths
  int bid = blockIdx.x, tid = threadIdx.x;
  if (bid < 3 * NB) {
    // ---- sort
    int r = bid / NB, b = bid % NB;
    const int* p = bptr + (size_t)r * (NB + 1);
    u32* rec = recs + (size_t)r * NE;
    int* rp = rowptr + (size_t)r * (NN + 1);
    int base = p[b], end = p[b + 1];
    int cnt = end - base; if (cnt > BCAP) cnt = BCAP;
    u32* rs = smem;
    int* hist = (int*)(smem + BCAP);
    int* excl = hist + 128;
    int* cur  = excl + 128;
    for (int i = tid; i < cnt; i += 256) rs[i] = rec[base + i];
    if (tid < 128) hist[tid] = 0;
    __syncthreads();
    for (int i = tid; i < cnt; i += 256) atomicAdd(&hist[rs[i] >> 17], 1);
    __syncthreads();
    if (tid < 128) cur[tid] = hist[tid];
    __syncthreads();
    for (int off = 1; off < 128; off <<= 1) {
      int v = 0;
      if (tid < 128 && tid >= off) v = cur[tid - off];
      __syncthreads();
      if (tid < 128) cur[tid] += v;
      __syncthreads();
    }
    if (tid < 128) {
      int e = cur[tid] - hist[tid];
      excl[tid] = e;
      int node = b * 128 + tid;
      if (node < NN) rp[node] = base + e;
    }
    if (b == NB - 1 && tid == 0) rp[NN] = p[NB];
    if (tid < 128) cur[tid] = excl[tid];
    __syncthreads();
    for (int i = tid; i < cnt; i += 256) {
      u32 v = rs[i];
      int pos = atomicAdd(&cur[v >> 17], 1);
      rec[base + pos] = v & 0x1FFFFu;
    }
  } else {
    // ---- GEMM: A fragments in registers, iterate W tiles
    int g = bid - 3 * NB;
    int ntype = g >= GB;
    int blk = ntype ? g - GB : g;
    u16* lds = (u16*)smem;
    const u16* A = ntype ? feat_cell : feat_net;
    const int row0 = blk * 64;
    const int lane = tid & 63, wv = tid >> 6;
    const int m16 = lane & 15, quad = lane >> 4;
    int arow = row0 + wv * 16 + m16;
    if (arow >= NN) arow = NN - 1;
    const u16* Ab = A + (size_t)arow * 128 + quad * 8;
    bf16x8 a[4];
#pragma unroll
    for (int kk = 0; kk < 4; ++kk) a[kk] = *(const bf16x8*)(Ab + kk * 32);
    if (!ntype) {
      gemm_w(Wl_bf,          256, P_net, lds, tid, row0, a, m16, quad, wv);
      __syncthreads();
      gemm_w(Wg_bf + 16384,  128, h1,    lds, tid, row0, a, m16, quad, wv);
      __syncthreads();
      gemm_w(Wg_bf + 32768,  128, h2,    lds, tid, row0, a, m16, quad, wv);
    } else {
      gemm_w(Wl_bf,          256, P_cell, lds, tid, row0, a, m16, quad, wv);
      __syncthreads();
      gemm_w(Wg_bf,          128, h0,     lds, tid, row0, a, m16, quad, wv);
    }
  }
}

// aggelem: agg r0 (net) | elem shortcut (cell)
__global__ __launch_bounds__(256) void aggelem_k(const u16* __restrict__ h0, const u32* __restrict__ srecs,
                                                 const int* __restrict__ rp,
                                                 const float* __restrict__ el, const float* __restrict__ er,
                                                 u16* __restrict__ buf_net,
                                                 const u16* __restrict__ P_cell, const float* __restrict__ vecs,
                                                 u16* __restrict__ buf_cell) {
  int bid = blockIdx.x, tid = threadIdx.x;
  if (bid < AB) {
    agg_body<0>(bid, tid, h0, srecs, rp, el, er, buf_net);
  } else {
    __shared__ float cs[128];
    int bx = bid - AB;
    if (tid < 128) cs[tid] = vecs[6 * 128 + tid];
    __syncthreads();
    size_t idx = ((size_t)bx * 256 + tid) * 8;
    if (idx >= (size_t)NN * 128) return;
    int col = (int)(idx & 127);
    short8 u = *(const short8*)(P_cell + idx);
    short8 w;
#pragma unroll
    for (int t = 0; t < 8; ++t)
      w[t] = (short)f2b(fmaxf(b2f((u16)u[t]) + cs[col + t], 0.f));
    *(short8*)(buf_cell + idx) = w;
  }
}

// fusedagg: agg r1 (cell) | fused r0 (net, bf16 out)
__global__ __launch_bounds__(256) void fusedagg_k(const u16* __restrict__ h1, const u32* __restrict__ srecs,
                                                  const int* __restrict__ rp,
                                                  const float* __restrict__ el, const float* __restrict__ er,
                                                  u16* __restrict__ buf_cell,
                                                  const u16* __restrict__ A, const u16* __restrict__ P_net,
                                                  u16* __restrict__ Cnet,
                                                  const u16* __restrict__ W, const float* __restrict__ cvec) {
  __shared__ u16 Wlds[128 * SP];
  int bid = blockIdx.x, tid = threadIdx.x;
  if (bid < AB) agg_body<1>(bid, tid, h1, srecs, rp, el, er, buf_cell);
  else fused_body<0>(bid - AB, tid, A, P_net, (void*)Cnet, W, cvec, Wlds);
}

// aggfused: agg r2 (net) | fused final (cell, fp32 out)
__global__ __launch_bounds__(256) void aggfused_k(const u16* __restrict__ h2, const u32* __restrict__ srecs,
                                                  const int* __restrict__ rp,
                                                  const float* __restrict__ el, const float* __restrict__ er,
                                                  u16* __restrict__ buf_net,
                                                  const u16* __restrict__ Acell, const u16* __restrict__ P_cell,
                                                  float* __restrict__ Ccell,
                                                  const u16* __restrict__ W, const float* __restrict__ cvec) {
  __shared__ u16 Wlds[128 * SP];
  int bid = blockIdx.x, tid = threadIdx.x;
  if (bid < AB) agg_body<1>(bid, tid, h2, srecs, rp, el, er, buf_net);
  else fused_body<1>(bid - AB, tid, Acell, P_cell, (void*)Ccell, W, cvec, Wlds);
}

// standalone fused (up to 2 jobs)
struct FJob { const u16* A; const u16* P; void* C; };
struct FJobs2 { FJob j[2]; const u16* W; const float* cvec; };
template<int FINAL>
__global__ __launch_bounds__(256) void fused_k(FJobs2 jobs) {
  __shared__ u16 Wlds[128 * SP];
  FJob jb = jobs.j[blockIdx.y];
  fused_body<FINAL>(blockIdx.x, threadIdx.x, jb.A, jb.P, jb.C, jobs.W, jobs.cvec, Wlds);
}

extern "C" void kernel_launch(void* const* d_in, const int* in_sizes, int n_in,
                              void* d_out, int out_size, void* d_ws, size_t ws_size,
                              hipStream_t stream) {
  const float* x_net   = (const float*)d_in[0];
  const float* x_cell  = (const float*)d_in[1];
  const float* Wp_net  = (const float*)d_in[2];
  const float* Wp_cell = (const float*)d_in[3];
  const float* Wg[3] = {(const float*)d_in[4], (const float*)d_in[7], (const float*)d_in[10]};
  const float* al[3] = {(const float*)d_in[5], (const float*)d_in[8], (const float*)d_in[11]};
  const float* ar[3] = {(const float*)d_in[6], (const float*)d_in[9], (const float*)d_in[12]};
  const float* Wl    = (const float*)d_in[13];
  const float* bias  = (const float*)d_in[14];
  const int* src[3] = {(const int*)d_in[15], (const int*)d_in[17], (const int*)d_in[19]};
  const int* dst[3] = {(const int*)d_in[16], (const int*)d_in[18], (const int*)d_in[20]};

  char* ws = (char*)d_ws;
  size_t off = 0;
  auto alloc = [&](size_t b) { void* p = ws + off; off = (off + b + 255) & ~(size_t)255; return p; };
  u16*  feat_net  = (u16*)alloc((size_t)NN * 128 * 2);
  u16*  feat_cell = (u16*)alloc((size_t)NN * 128 * 2);
  u16*  hbuf0     = (u16*)alloc((size_t)NN * 128 * 2);
  u16*  hbuf1     = (u16*)alloc((size_t)NN * 128 * 2);
  u16*  hbuf2     = (u16*)alloc((size_t)NN * 128 * 2);
  u16*  P_net     = (u16*)alloc((size_t)NN * 128 * 2);
  u16*  P_cell    = (u16*)alloc((size_t)NN * 128 * 2);
  u16*  buf_net   = (u16*)alloc((size_t)NN * 128 * 2);
  u16*  buf_cell  = (u16*)alloc((size_t)NN * 128 * 2);
  float* vecs     = (float*)alloc(7 * 128 * 4);
  float* logit    = (float*)alloc((size_t)6 * NN * 4);
  u16*   Wl_bf    = (u16*)alloc((size_t)128 * 256 * 2);
  u16*   Wg_bf    = (u16*)alloc((size_t)3 * 128 * 128 * 2);
  int*   bcnt     = (int*)alloc((size_t)3 * NB * 4);
  int*   bcur     = (int*)alloc((size_t)3 * NB * 4);
  int*   bptr     = (int*)alloc((size_t)3 * (NB + 1) * 4);
  int*   rowptr   = (int*)alloc((size_t)3 * (NN + 1) * 4);
  u32*   recs     = (u32*)alloc((size_t)3 * NE * 4);

  float* out_f = (float*)d_out;  // [2,N,D] fp32: net then cell

  // 1. prep: proj | conv | vec | zero bcnt
  prep_k<<<2 * AB + 138, 256, 0, stream>>>(x_net, x_cell, Wp_net, Wp_cell, feat_net, feat_cell,
                                           Wl, Wg[0], Wg[1], Wg[2], Wl_bf, Wg_bf,
                                           al[0], ar[0], al[1], ar[1], al[2], ar[2], bias, vecs, bcnt);
  // 2. logits | bhist
  logbh_k<<<782 + 3 * NCH, 256, 0, stream>>>(feat_net, feat_cell, vecs, logit,
                                             dst[0], dst[1], dst[2], bcnt);
  // 3. scan
  bscan_k<<<3, 1024, 0, stream>>>(bcnt, bptr, bcur);
  // 4. scatter
  bscatter_k<<<dim3(NCH, 3), 256, 0, stream>>>(src[0], dst[0], src[1], dst[1], src[2], dst[2],
                                               bcur, recs);
  // 5. sort | all 5 GEMMs (A-shared per ntype)
  sortgemm_k<<<3 * NB + 2 * GB, 256, 0, stream>>>(recs, bptr, rowptr, feat_net, feat_cell,
                                                  Wl_bf, Wg_bf, P_net, P_cell, hbuf0, hbuf1, hbuf2);
  // 6. agg r0 (net) | elem (cell)
  aggelem_k<<<2 * AB, 256, 0, stream>>>(hbuf0, recs, rowptr, logit, logit + (size_t)NN, buf_net,
                                        P_cell, vecs, buf_cell);
  // 7. agg r1 (cell) | fused r0 (net)
  fusedagg_k<<<AB + GB, 256, 0, stream>>>(hbuf1, recs + (size_t)NE, rowptr + (NN + 1),
                                          logit + (size_t)2 * NN, logit + (size_t)3 * NN, buf_cell,
                                          buf_net, P_net, buf_net, Wl_bf + 128, vecs + 6 * 128);
  // 8. fused r1 (net + cell)
  {
    FJobs2 jobs; jobs.W = Wl_bf + 128; jobs.cvec = vecs + 6 * 128;
    jobs.j[0] = {buf_net, P_net, buf_net};
    jobs.j[1] = {buf_cell, P_cell, buf_cell};
    fused_k<0><<<dim3(GB, 2), 256, 0, stream>>>(jobs);
  }
  // 9. agg r2 (net) | fused final cell (fp32)
  aggfused_k<<<AB + GB, 256, 0, stream>>>(hbuf2, recs + (size_t)2 * NE, rowptr + 2 * (NN + 1),
                                          logit + (size_t)4 * NN, logit + (size_t)5 * NN, buf_net,
                                          buf_cell, P_cell, out_f + (size_t)NN * 128,
                                          Wl_bf + 128, vecs + 6 * 128);
  // 10. fused final net (fp32)
  {
    FJobs2 jobs; jobs.W = Wl_bf + 128; jobs.cvec = vecs + 6 * 128;
    jobs.j[0] = {buf_net, P_net, out_f};
    jobs.j[1] = jobs.j[0];
    fused_k<1><<<dim3(GB, 1), 256, 0, stream>>>(jobs);
  }
}

// Round 7
// 469.899 us; speedup vs baseline: 1.8710x; 1.0714x over previous
//
#include <hip/hip_runtime.h>
#include <hip/hip_bf16.h>
#include <stdint.h>

// ParaGraph: 2 node types (net/cell, N=100000), 3 relations (E=600000 each), D=128.
// I/O FP32. All intermediates bf16. W pre-converted bf16. GEMMs hold A-fragments in
// registers, iterate W tiles. Aggregation blocks FUSE the concat-linear-relu GEMM:
// 16 groups gather 16 rows -> LDS -> one M=16 MFMA tile -> relu(P + AW2 + c) out.
// Pipeline (8 dispatches): prep | logbh | bscan | bscatter | sortgemm |
// aggF0+elem | aggF1+fusedF(net) | aggF2final+fusedF(cell final).
#define NN 100000
#define NE 600000
#define SP 136        // LDS row stride (ushorts): 128 + 8 pad
#define NB 782        // ceil(NN/128) dst buckets of 128 nodes
#define BCAP 1600     // LDS rec capacity per bucket (mean 767, sd ~28)
#define CHUNK 4096    // edges per partition block
#define NCH 147       // ceil(NE/CHUNK)
#define GB 1563       // ceil(NN/64) GEMM row-blocks
#define AB 6250       // NN/16 agg blocks (exact)

typedef unsigned short u16;
typedef unsigned int u32;
typedef __attribute__((ext_vector_type(8))) short short8;
typedef __attribute__((ext_vector_type(8))) __bf16 bf16x8;
typedef __attribute__((ext_vector_type(4))) float floatx4;

__device__ __forceinline__ float b2f(u16 u) {
  union { float f; u32 i; } c; c.i = ((u32)u) << 16; return c.f;
}
__device__ __forceinline__ u16 f2b(float f) {
  union { float f; u32 i; } c; c.f = f;
  u32 r = c.i + 0x7FFFu + ((c.i >> 16) & 1u);  // RNE
  return (u16)(r >> 16);
}

// ================= device bodies =================

// one W-tile pass: stage W (plain 16B copies) -> sync -> MFMA -> store C
__device__ __forceinline__ void gemm_w(const u16* __restrict__ W, int ldw, u16* __restrict__ C,
                                       u16* lds, int tid, int row0, const bf16x8* a,
                                       int m16, int quad, int wv) {
#pragma unroll
  for (int it = 0; it < 8; ++it) {
    int idx = it * 256 + tid;
    int r = idx >> 4, c = (idx & 15) << 3;
    *(short8*)(&lds[r * SP + c]) = *(const short8*)(W + (size_t)r * ldw + c);
  }
  __syncthreads();
  const u16* brow = &lds[m16 * SP + quad * 8];
  floatx4 acc[8];
#pragma unroll
  for (int c = 0; c < 8; ++c) acc[c] = floatx4{0.f, 0.f, 0.f, 0.f};
#pragma unroll
  for (int kk = 0; kk < 4; ++kk) {
#pragma unroll
    for (int c = 0; c < 8; ++c) {
      bf16x8 bfr = *(const bf16x8*)(brow + c * 16 * SP + kk * 32);
      acc[c] = __builtin_amdgcn_mfma_f32_16x16x32_bf16(a[kk], bfr, acc[c], 0, 0, 0);
    }
  }
#pragma unroll
  for (int c = 0; c < 8; ++c) {
    int col = c * 16 + m16;
#pragma unroll
    for (int r = 0; r < 4; ++r) {
      int grow = row0 + wv * 16 + quad * 4 + r;
      if (grow < NN) C[(size_t)grow * 128 + col] = f2b(acc[c][r]);
    }
  }
}

// fused concat-linear-relu (64-row block): C = relu(P + A @ W2.T + c)
template<int FINAL>
__device__ __forceinline__ void fused_body(int blk, int tid, const u16* __restrict__ A,
                                           const u16* __restrict__ P, void* __restrict__ C,
                                           const u16* __restrict__ W, const float* __restrict__ cvec,
                                           u16* Wlds) {
  const int row0 = blk * 64;
#pragma unroll
  for (int it = 0; it < 8; ++it) {
    int idx = it * 256 + tid;
    int r = idx >> 4, c = (idx & 15) << 3;
    *(short8*)(&Wlds[r * SP + c]) = *(const short8*)(W + (size_t)r * 256 + c);
  }
  const int lane = tid & 63, wv = tid >> 6;
  const int m16 = lane & 15, quad = lane >> 4;
  int arow = row0 + wv * 16 + m16;
  if (arow >= NN) arow = NN - 1;          // clamp: stores guarded below
  const u16* Ab = A + (size_t)arow * 128 + quad * 8;
  bf16x8 a[4];
#pragma unroll
  for (int kk = 0; kk < 4; ++kk) a[kk] = *(const bf16x8*)(Ab + kk * 32);
  __syncthreads();
  const u16* brow = &Wlds[m16 * SP + quad * 8];
  floatx4 acc[8];
#pragma unroll
  for (int c = 0; c < 8; ++c) acc[c] = floatx4{0.f, 0.f, 0.f, 0.f};
#pragma unroll
  for (int kk = 0; kk < 4; ++kk) {
#pragma unroll
    for (int c = 0; c < 8; ++c) {
      bf16x8 bfr = *(const bf16x8*)(brow + c * 16 * SP + kk * 32);
      acc[c] = __builtin_amdgcn_mfma_f32_16x16x32_bf16(a[kk], bfr, acc[c], 0, 0, 0);
    }
  }
#pragma unroll
  for (int c = 0; c < 8; ++c) {
    int col = c * 16 + m16;
    float cv = cvec[col];
#pragma unroll
    for (int r = 0; r < 4; ++r) {
      int grow = row0 + wv * 16 + quad * 4 + r;
      if (grow < NN) {
        float v = acc[c][r] + b2f(P[(size_t)grow * 128 + col]) + cv;
        v = fmaxf(v, 0.f);
        if (FINAL) ((float*)C)[(size_t)grow * 128 + col] = v;
        else       ((u16*)C)[(size_t)grow * 128 + col] = f2b(v);
      }
    }
  }
}

// agg + fused-F in one block: 16 groups gather 16 rows -> LDS -> M=16 MFMA F-tile
template<int RMW, int FINAL>
__device__ __forceinline__ void aggF_body(int nb, int tid,
                                          const u16* __restrict__ h, const u32* __restrict__ srecs,
                                          const int* __restrict__ rp,
                                          const float* __restrict__ el, const float* __restrict__ er,
                                          const u16* __restrict__ prevbuf,   // RMW source (bf16)
                                          const u16* __restrict__ P, const float* __restrict__ cvec,
                                          const u16* __restrict__ W,         // W2 (ldw 256)
                                          void* __restrict__ out,            // FINAL? float* : u16*
                                          u16* Wlds, u16* Alds) {
  // stage W2 (plain 16B copies); consumed after the barrier below
#pragma unroll
  for (int it = 0; it < 8; ++it) {
    int idx = it * 256 + tid;
    int r = idx >> 4, c = (idx & 15) << 3;
    *(short8*)(&Wlds[r * SP + c]) = *(const short8*)(W + (size_t)r * 256 + c);
  }
  // --- agg phase: group g handles node n
  int sub = tid & 15;
  int g = tid >> 4;
  int n = nb * 16 + g;                    // NN = 6250*16, no tail
  int start = rp[n], end = rp[n + 1];
  float row[8];
  if (RMW) {
    short8 pv = *(const short8*)(prevbuf + (size_t)n * 128 + sub * 8);
#pragma unroll
    for (int t = 0; t < 8; ++t) row[t] = b2f((u16)pv[t]);
  } else {
#pragma unroll
    for (int t = 0; t < 8; ++t) row[t] = 0.f;
  }
  if (start < end) {
    float ern = er[n];
    float acc[8];
#pragma unroll
    for (int t = 0; t < 8; ++t) acc[t] = 0.f;
    float sl = 0.f;
    const u16* hsub = h + sub * 8;
    for (int base = start; base < end; base += 16) {
      int m = end - base; if (m > 16) m = 16;
      int srci = 0; float w = 0.f;
      if (sub < m) {
        srci = (int)srecs[base + sub];
        float l = el[srci] + ern;
        l = (l >= 0.f) ? l : 0.2f * l;
        w = __expf(l);
      }
      sl += w;
      for (int i = 0; i < m; ++i) {
        float x = __shfl(w, i, 16);
        int sv = __shfl(srci, i, 16);
        short8 hv = *(const short8*)(hsub + (size_t)sv * 128);
#pragma unroll
        for (int t = 0; t < 8; ++t) acc[t] += x * b2f((u16)hv[t]);
      }
    }
    float s = sl;
#pragma unroll
    for (int off = 8; off > 0; off >>= 1) s += __shfl_xor(s, off, 16);
    float inv = 1.f / s;
#pragma unroll
    for (int t = 0; t < 8; ++t) row[t] += acc[t] * inv;
  }
  // bf16 round (bit-parity with old buf store) -> LDS A tile
  short8 rb;
#pragma unroll
  for (int t = 0; t < 8; ++t) rb[t] = (short)f2b(row[t]);
  *(short8*)(&Alds[g * SP + sub * 8]) = rb;
  __syncthreads();
  // --- F phase: [16][128] @ W2.T -> relu(P + . + c)
  const int lane = tid & 63, wv = tid >> 6;
  const int m16 = lane & 15, quad = lane >> 4;
  const u16* arow = &Alds[m16 * SP + quad * 8];
  bf16x8 a[4];
#pragma unroll
  for (int kk = 0; kk < 4; ++kk) a[kk] = *(const bf16x8*)(arow + kk * 32);
  const u16* brow = &Wlds[m16 * SP + quad * 8];
  floatx4 acc2[2];
#pragma unroll
  for (int cc = 0; cc < 2; ++cc) acc2[cc] = floatx4{0.f, 0.f, 0.f, 0.f};
#pragma unroll
  for (int kk = 0; kk < 4; ++kk) {
#pragma unroll
    for (int cc = 0; cc < 2; ++cc) {
      int ct = wv * 2 + cc;
      bf16x8 bfr = *(const bf16x8*)(brow + ct * 16 * SP + kk * 32);
      acc2[cc] = __builtin_amdgcn_mfma_f32_16x16x32_bf16(a[kk], bfr, acc2[cc], 0, 0, 0);
    }
  }
#pragma unroll
  for (int cc = 0; cc < 2; ++cc) {
    int ct = wv * 2 + cc;
    int col = ct * 16 + m16;
    float cv = cvec[col];
#pragma unroll
    for (int r = 0; r < 4; ++r) {
      int node = nb * 16 + quad * 4 + r;
      float v = acc2[cc][r] + b2f(P[(size_t)node * 128 + col]) + cv;
      v = fmaxf(v, 0.f);
      if (FINAL) ((float*)out)[(size_t)node * 128 + col] = v;
      else       ((u16*)out)[(size_t)node * 128 + col] = f2b(v);
    }
  }
}

// ================= kernels =================

// prep: proj (12500) | conv (128) | vec (7) | zero bcnt (3)
__global__ __launch_bounds__(256) void prep_k(const float* __restrict__ x_net, const float* __restrict__ x_cell,
                                              const float* __restrict__ Wp_net, const float* __restrict__ Wp_cell,
                                              u16* __restrict__ feat_net, u16* __restrict__ feat_cell,
                                              const float* __restrict__ Wl, const float* __restrict__ Wg0,
                                              const float* __restrict__ Wg1, const float* __restrict__ Wg2,
                                              u16* __restrict__ Wl_bf, u16* __restrict__ Wg_bf,
                                              const float* al0, const float* ar0, const float* al1,
                                              const float* ar1, const float* al2, const float* ar2,
                                              const float* bias, float* __restrict__ vecs,
                                              int* __restrict__ bcnt) {
  int bid = blockIdx.x, tid = threadIdx.x;
  if (bid < 2 * AB) {
    int y = bid >= AB;
    int bx = y ? bid - AB : bid;
    const float* x  = y ? x_cell : x_net;
    const float* Wp = y ? Wp_cell : Wp_net;
    u16* feat       = y ? feat_cell : feat_net;
    __shared__ float Ws[128 * 17];
    __shared__ float xs[16][17];
#pragma unroll
    for (int it = 0; it < 8; ++it) {
      int idx = it * 256 + tid;
      int j = idx >> 4, k = idx & 15;
      Ws[j * 17 + k] = Wp[idx];
    }
    int n0 = bx * 16;
    { int nn = tid >> 4, k = tid & 15;
      xs[nn][k] = x[(size_t)(n0 + nn) * 16 + k]; }
    __syncthreads();
    int j = tid & 127, g = tid >> 7;
    float acc[8];
#pragma unroll
    for (int r = 0; r < 8; ++r) acc[r] = 0.f;
#pragma unroll
    for (int k = 0; k < 16; ++k) {
      float w = Ws[j * 17 + k];
#pragma unroll
      for (int r = 0; r < 8; ++r) acc[r] += xs[g * 8 + r][k] * w;
    }
#pragma unroll
    for (int r = 0; r < 8; ++r)
      feat[(size_t)(n0 + g * 8 + r) * 128 + j] = f2b(acc[r]);
  } else if (bid < 2 * AB + 128) {
    int cid = bid - 2 * AB;
    int y = cid >> 5, bx = cid & 31;
    const float* src = (y == 0) ? Wl : (y == 1) ? Wg0 : (y == 2) ? Wg1 : Wg2;
    u16* dst = (y == 0) ? Wl_bf : Wg_bf + (size_t)(y - 1) * 16384;
    int n = (y == 0) ? 32768 : 16384;
    int i = (bx * 256 + tid) * 4;
    if (i >= n) return;
    float4 v = *(const float4*)(src + i);
    ushort4 p; p.x = f2b(v.x); p.y = f2b(v.y); p.z = f2b(v.z); p.w = f2b(v.w);
    *(ushort4*)(dst + i) = p;
  } else if (bid < 2 * AB + 135) {
    int a = bid - (2 * AB + 128);
    if (tid >= 128) return;
    int j = tid;
    float s = 0.f;
    if (a < 6) {
      const float* W = (a < 2) ? Wg0 : (a < 4) ? Wg1 : Wg2;
      const float* v = (a == 0) ? al0 : (a == 1) ? ar0 : (a == 2) ? al1 : (a == 3) ? ar1 : (a == 4) ? al2 : ar2;
      for (int i = 0; i < 128; ++i) s += W[i * 128 + j] * v[i];
    } else {
      for (int i = 0; i < 128; ++i) s += Wl[(size_t)j * 256 + 128 + i] * bias[i];
    }
    vecs[a * 128 + j] = s;
  } else {
    int r = bid - (2 * AB + 135);
    for (int i = tid; i < NB; i += 256) bcnt[(size_t)r * NB + i] = 0;
  }
}

// logbh: logits (782) | bhist (441)
__global__ __launch_bounds__(256) void logbh_k(const u16* __restrict__ feat_net, const u16* __restrict__ feat_cell,
                                               const float* __restrict__ vecs, float* __restrict__ outs,
                                               const int* __restrict__ dst0, const int* __restrict__ dst1,
                                               const int* __restrict__ dst2, int* __restrict__ bcnt) {
  __shared__ int sm[NB];
  int bid = blockIdx.x, tid = threadIdx.x;
  if (bid < 782) {
    float* vs = (float*)sm;
#pragma unroll
    for (int it = 0; it < 3; ++it) vs[it * 256 + tid] = vecs[it * 256 + tid];
    __syncthreads();
    int y = bid >= 391;
    int bx = y ? bid - 391 : bid;
    const u16* f = y ? feat_cell : feat_net;
    int n = bx * 256 + tid;
    if (n >= NN) return;
    const u16* row = f + (size_t)n * 128;
    if (y == 0) {
      float s1 = 0.f, s2 = 0.f, s4 = 0.f, s5 = 0.f;
#pragma unroll
      for (int k = 0; k < 128; k += 8) {
        short8 u = *(const short8*)(row + k);
#pragma unroll
        for (int t = 0; t < 8; ++t) {
          float fv = b2f((u16)u[t]);
          s1 += fv * vs[1 * 128 + k + t]; s2 += fv * vs[2 * 128 + k + t];
          s4 += fv * vs[4 * 128 + k + t]; s5 += fv * vs[5 * 128 + k + t];
        }
      }
      outs[(size_t)1 * NN + n] = s1; outs[(size_t)2 * NN + n] = s2;
      outs[(size_t)4 * NN + n] = s4; outs[(size_t)5 * NN + n] = s5;
    } else {
      float s0 = 0.f, s3 = 0.f;
#pragma unroll
      for (int k = 0; k < 128; k += 8) {
        short8 u = *(const short8*)(row + k);
#pragma unroll
        for (int t = 0; t < 8; ++t) {
          float fv = b2f((u16)u[t]);
          s0 += fv * vs[0 * 128 + k + t]; s3 += fv * vs[3 * 128 + k + t];
        }
      }
      outs[(size_t)0 * NN + n] = s0; outs[(size_t)3 * NN + n] = s3;
    }
  } else {
    int e = bid - 782;
    int r = e / NCH, bx = e % NCH;
    const int* dst = (r == 0) ? dst0 : (r == 1) ? dst1 : dst2;
    for (int i = tid; i < NB; i += 256) sm[i] = 0;
    __syncthreads();
    int e0 = bx * CHUNK;
    int cnt = NE - e0; if (cnt > CHUNK) cnt = CHUNK;
    for (int i = tid; i < cnt; i += 256) atomicAdd(&sm[((u32)dst[e0 + i]) >> 7], 1);
    __syncthreads();
    for (int b = tid; b < NB; b += 256) {
      int c = sm[b];
      if (c) atomicAdd(&bcnt[(size_t)r * NB + b], c);
    }
  }
}

// ---------- exclusive scan of NB counters per relation (one 1024-block each)
__global__ __launch_bounds__(1024) void bscan_k(const int* __restrict__ bcnt, int* __restrict__ bptr,
                                                int* __restrict__ bcur) {
  int r = blockIdx.x, t = threadIdx.x;
  const int* c = bcnt + (size_t)r * NB;
  int* p = bptr + (size_t)r * (NB + 1);
  int* cur = bcur + (size_t)r * NB;
  int v = (t < NB) ? c[t] : 0;
  __shared__ int ss[1024];
  ss[t] = v; __syncthreads();
  for (int off = 1; off < 1024; off <<= 1) {
    int u = (t >= off) ? ss[t - off] : 0;
    __syncthreads();
    ss[t] += u;
    __syncthreads();
  }
  if (t < NB) { int e = ss[t] - v; p[t] = e; cur[t] = e; }
  if (t == 1023) p[NB] = ss[1023];
}

// ---------- block-local radix partition (coalesced run-writes)
__global__ __launch_bounds__(256) void bscatter_k(const int* __restrict__ src0, const int* __restrict__ dst0,
                                                  const int* __restrict__ src1, const int* __restrict__ dst1,
                                                  const int* __restrict__ src2, const int* __restrict__ dst2,
                                                  int* __restrict__ bcur, u32* __restrict__ recs) {
  int r = blockIdx.y;
  const int* src = (r == 0) ? src0 : (r == 1) ? src1 : src2;
  const int* dst = (r == 0) ? dst0 : (r == 1) ? dst1 : dst2;
  __shared__ int hist[NB];
  __shared__ int lstart[NB];
  __shared__ int lcur[NB];
  __shared__ int badj[NB];
  __shared__ u32 rbuf[CHUNK];
  __shared__ u16 kbuf[CHUNK];
  __shared__ int ss[256];
  int tid = threadIdx.x;
  int e0 = blockIdx.x * CHUNK;
  int cnt = NE - e0; if (cnt > CHUNK) cnt = CHUNK;

  for (int i = tid; i < NB; i += 256) hist[i] = 0;
  __syncthreads();
  for (int i = tid; i < cnt; i += 256) atomicAdd(&hist[((u32)dst[e0 + i]) >> 7], 1);
  __syncthreads();
  int loc[4]; int s = 0;
  int base4 = tid * 4;
#pragma unroll
  for (int j = 0; j < 4; ++j) {
    int idx = base4 + j;
    int v = (idx < NB) ? hist[idx] : 0;
    loc[j] = s; s += v;
  }
  ss[tid] = s; __syncthreads();
  for (int off = 1; off < 256; off <<= 1) {
    int u = (tid >= off) ? ss[tid - off] : 0;
    __syncthreads();
    ss[tid] += u;
    __syncthreads();
  }
  int ex = ss[tid] - s;
#pragma unroll
  for (int j = 0; j < 4; ++j) {
    int idx = base4 + j;
    if (idx < NB) { int e = ex + loc[j]; lstart[idx] = e; lcur[idx] = e; }
  }
  __syncthreads();
  for (int b = tid; b < NB; b += 256) {
    int c = hist[b];
    int g = 0;
    if (c) g = atomicAdd(&bcur[(size_t)r * NB + b], c);
    badj[b] = g - lstart[b];
  }
  __syncthreads();
  for (int i = tid; i < cnt; i += 256) {
    int dN = dst[e0 + i], sN = src[e0 + i];
    int b = ((u32)dN) >> 7;
    int pos = atomicAdd(&lcur[b], 1);
    rbuf[pos] = ((u32)(dN & 127) << 17) | (u32)sN;
    kbuf[pos] = (u16)b;
  }
  __syncthreads();
  u32* out = recs + (size_t)r * NE;
  for (int i = tid; i < cnt; i += 256) {
    int b = kbuf[i];
    out[badj[b] + i] = rbuf[i];
  }
}

// sortgemm: GEMM blocks FIRST (long blocks early, tail balance), then sort blocks
__global__ __launch_bounds__(256) void sortgemm_k(u32* __restrict__ recs, const int* __restrict__ bptr,
                                                  int* __restrict__ rowptr,
                                                  const u16* __restrict__ feat_net, const u16* __restrict__ feat_cell,
                                                  const u16* __restrict__ Wl_bf, const u16* __restrict__ Wg_bf,
                                                  u16* __restrict__ P_net, u16* __restrict__ P_cell,
                                                  u16* __restrict__ h0, u16* __restrict__ h1, u16* __restrict__ h2) {
  __shared__ u32 smem[128 * SP / 2];   // 34816 B, shared by both paths
  int bid = blockIdx.x, tid = threadIdx.x;
  if (bid < 2 * GB) {
    // ---- GEMM: A fragments in registers, iterate W tiles
    int ntype = bid >= GB;
    int blk = ntype ? bid - GB : bid;
    u16* lds = (u16*)smem;
    const u16* A = ntype ? feat_cell : feat_net;
    const int row0 = blk * 64;
    const int lane = tid & 63, wv = tid >> 6;
    const int m16 = lane & 15, quad = lane >> 4;
    int arow = row0 + wv * 16 + m16;
    if (arow >= NN) arow = NN - 1;
    const u16* Ab = A + (size_t)arow * 128 + quad * 8;
    bf16x8 a[4];
#pragma unroll
    for (int kk = 0; kk < 4; ++kk) a[kk] = *(const bf16x8*)(Ab + kk * 32);
    if (!ntype) {
      gemm_w(Wl_bf,          256, P_net, lds, tid, row0, a, m16, quad, wv);
      __syncthreads();
      gemm_w(Wg_bf + 16384,  128, h1,    lds, tid, row0, a, m16, quad, wv);
      __syncthreads();
      gemm_w(Wg_bf + 32768,  128, h2,    lds, tid, row0, a, m16, quad, wv);
    } else {
      gemm_w(Wl_bf,          256, P_cell, lds, tid, row0, a, m16, quad, wv);
      __syncthreads();
      gemm_w(Wg_bf,          128, h0,     lds, tid, row0, a, m16, quad, wv);
    }
  } else {
    // ---- sort
    int sb = bid - 2 * GB;
    int r = sb / NB, b = sb % NB;
    const int* p = bptr + (size_t)r * (NB + 1);
    u32* rec = recs + (size_t)r * NE;
    int* rp = rowptr + (size_t)r * (NN + 1);
    int base = p[b], end = p[b + 1];
    int cnt = end - base; if (cnt > BCAP) cnt = BCAP;
    u32* rs = smem;
    int* hist = (int*)(smem + BCAP);
    int* excl = hist + 128;
    int* cur  = excl + 128;
    for (int i = tid; i < cnt; i += 256) rs[i] = rec[base + i];
    if (tid < 128) hist[tid] = 0;
    __syncthreads();
    for (int i = tid; i < cnt; i += 256) atomicAdd(&hist[rs[i] >> 17], 1);
    __syncthreads();
    if (tid < 128) cur[tid] = hist[tid];
    __syncthreads();
    for (int off = 1; off < 128; off <<= 1) {
      int v = 0;
      if (tid < 128 && tid >= off) v = cur[tid - off];
      __syncthreads();
      if (tid < 128) cur[tid] += v;
      __syncthreads();
    }
    if (tid < 128) {
      int e = cur[tid] - hist[tid];
      excl[tid] = e;
      int node = b * 128 + tid;
      if (node < NN) rp[node] = base + e;
    }
    if (b == NB - 1 && tid == 0) rp[NN] = p[NB];
    if (tid < 128) cur[tid] = excl[tid];
    __syncthreads();
    for (int i = tid; i < cnt; i += 256) {
      u32 v = rs[i];
      int pos = atomicAdd(&cur[v >> 17], 1);
      rec[base + pos] = v & 0x1FFFFu;
    }
  }
}

// dispatch 6: aggF0 (net: gat0 -> F -> buf_net) | elem (cell: F(0) -> buf_cell)
__global__ __launch_bounds__(256) void aggelem_k(const u16* __restrict__ h0, const u32* __restrict__ srecs,
                                                 const int* __restrict__ rp,
                                                 const float* __restrict__ el, const float* __restrict__ er,
                                                 const u16* __restrict__ P_net, const float* __restrict__ cvec,
                                                 const u16* __restrict__ W2, u16* __restrict__ buf_net,
                                                 const u16* __restrict__ P_cell, u16* __restrict__ buf_cell) {
  __shared__ u16 Wlds[128 * SP];
  __shared__ u16 Alds[16 * SP];
  int bid = blockIdx.x, tid = threadIdx.x;
  if (bid < AB) {
    aggF_body<0, 0>(bid, tid, h0, srecs, rp, el, er, nullptr, P_net, cvec, W2,
                    (void*)buf_net, Wlds, Alds);
  } else {
    float* cs = (float*)Alds;
    int bx = bid - AB;
    if (tid < 128) cs[tid] = cvec[tid];
    __syncthreads();
    size_t idx = ((size_t)bx * 256 + tid) * 8;
    if (idx >= (size_t)NN * 128) return;
    int col = (int)(idx & 127);
    short8 u = *(const short8*)(P_cell + idx);
    short8 w;
#pragma unroll
    for (int t = 0; t < 8; ++t)
      w[t] = (short)f2b(fmaxf(b2f((u16)u[t]) + cs[col + t], 0.f));
    *(short8*)(buf_cell + idx) = w;
  }
}

// dispatch 7: aggF1 (cell: buf_cell+gat1 -> F -> buf_cell) | fusedF net (F(buf_net) -> buf_net)
__global__ __launch_bounds__(256) void aggfused1_k(const u16* __restrict__ h1, const u32* __restrict__ srecs,
                                                   const int* __restrict__ rp,
                                                   const float* __restrict__ el, const float* __restrict__ er,
                                                   const u16* __restrict__ P_cell, u16* __restrict__ buf_cell,
                                                   const u16* __restrict__ buf_net, const u16* __restrict__ P_net,
                                                   u16* __restrict__ buf_net_out,
                                                   const u16* __restrict__ W2, const float* __restrict__ cvec) {
  __shared__ u16 Wlds[128 * SP];
  __shared__ u16 Alds[16 * SP];
  int bid = blockIdx.x, tid = threadIdx.x;
  if (bid < AB) {
    aggF_body<1, 0>(bid, tid, h1, srecs, rp, el, er, buf_cell, P_cell, cvec, W2,
                    (void*)buf_cell, Wlds, Alds);
  } else {
    fused_body<0>(bid - AB, tid, buf_net, P_net, (void*)buf_net_out, W2, cvec, Wlds);
  }
}

// dispatch 8: aggF2 final (net: buf_net+gat2 -> F -> out fp32) | fusedF cell final
__global__ __launch_bounds__(256) void aggfused2_k(const u16* __restrict__ h2, const u32* __restrict__ srecs,
                                                   const int* __restrict__ rp,
                                                   const float* __restrict__ el, const float* __restrict__ er,
                                                   const u16* __restrict__ buf_net, const u16* __restrict__ P_net,
                                                   float* __restrict__ out_net,
                                                   const u16* __restrict__ buf_cell, const u16* __restrict__ P_cell,
                                                   float* __restrict__ out_cell,
                                                   const u16* __restrict__ W2, const float* __restrict__ cvec) {
  __shared__ u16 Wlds[128 * SP];
  __shared__ u16 Alds[16 * SP];
  int bid = blockIdx.x, tid = threadIdx.x;
  if (bid < AB) {
    aggF_body<1, 1>(bid, tid, h2, srecs, rp, el, er, buf_net, P_net, cvec, W2,
                    (void*)out_net, Wlds, Alds);
  } else {
    fused_body<1>(bid - AB, tid, buf_cell, P_cell, (void*)out_cell, W2, cvec, Wlds);
  }
}

extern "C" void kernel_launch(void* const* d_in, const int* in_sizes, int n_in,
                              void* d_out, int out_size, void* d_ws, size_t ws_size,
                              hipStream_t stream) {
  const float* x_net   = (const float*)d_in[0];
  const float* x_cell  = (const float*)d_in[1];
  const float* Wp_net  = (const float*)d_in[2];
  const float* Wp_cell = (const float*)d_in[3];
  const float* Wg[3] = {(const float*)d_in[4], (const float*)d_in[7], (const float*)d_in[10]};
  const float* al[3] = {(const float*)d_in[5], (const float*)d_in[8], (const float*)d_in[11]};
  const float* ar[3] = {(const float*)d_in[6], (const float*)d_in[9], (const float*)d_in[12]};
  const float* Wl    = (const float*)d_in[13];
  const float* bias  = (const float*)d_in[14];
  const int* src[3] = {(const int*)d_in[15], (const int*)d_in[17], (const int*)d_in[19]};
  const int* dst[3] = {(const int*)d_in[16], (const int*)d_in[18], (const int*)d_in[20]};

  char* ws = (char*)d_ws;
  size_t off = 0;
  auto alloc = [&](size_t b) { void* p = ws + off; off = (off + b + 255) & ~(size_t)255; return p; };
  u16*  feat_net  = (u16*)alloc((size_t)NN * 128 * 2);
  u16*  feat_cell = (u16*)alloc((size_t)NN * 128 * 2);
  u16*  hbuf0     = (u16*)alloc((size_t)NN * 128 * 2);
  u16*  hbuf1     = (u16*)alloc((size_t)NN * 128 * 2);
  u16*  hbuf2     = (u16*)alloc((size_t)NN * 128 * 2);
  u16*  P_net     = (u16*)alloc((size_t)NN * 128 * 2);
  u16*  P_cell    = (u16*)alloc((size_t)NN * 128 * 2);
  u16*  buf_net   = (u16*)alloc((size_t)NN * 128 * 2);
  u16*  buf_cell  = (u16*)alloc((size_t)NN * 128 * 2);
  float* vecs     = (float*)alloc(7 * 128 * 4);
  float* logit    = (float*)alloc((size_t)6 * NN * 4);
  u16*   Wl_bf    = (u16*)alloc((size_t)128 * 256 * 2);
  u16*   Wg_bf    = (u16*)alloc((size_t)3 * 128 * 128 * 2);
  int*   bcnt     = (int*)alloc((size_t)3 * NB * 4);
  int*   bcur     = (int*)alloc((size_t)3 * NB * 4);
  int*   bptr     = (int*)alloc((size_t)3 * (NB + 1) * 4);
  int*   rowptr   = (int*)alloc((size_t)3 * (NN + 1) * 4);
  u32*   recs     = (u32*)alloc((size_t)3 * NE * 4);

  float* out_f = (float*)d_out;  // [2,N,D] fp32: net then cell
  const u16* W2 = Wl_bf + 128;   // Wl cols 128..255 (ldw 256)
  const float* cvec = vecs + 6 * 128;

  // 1. prep: proj | conv | vec | zero bcnt
  prep_k<<<2 * AB + 138, 256, 0, stream>>>(x_net, x_cell, Wp_net, Wp_cell, feat_net, feat_cell,
                                           Wl, Wg[0], Wg[1], Wg[2], Wl_bf, Wg_bf,
                                           al[0], ar[0], al[1], ar[1], al[2], ar[2], bias, vecs, bcnt);
  // 2. logits | bhist
  logbh_k<<<782 + 3 * NCH, 256, 0, stream>>>(feat_net, feat_cell, vecs, logit,
                                             dst[0], dst[1], dst[2], bcnt);
  // 3. scan
  bscan_k<<<3, 1024, 0, stream>>>(bcnt, bptr, bcur);
  // 4. scatter
  bscatter_k<<<dim3(NCH, 3), 256, 0, stream>>>(src[0], dst[0], src[1], dst[1], src[2], dst[2],
                                               bcur, recs);
  // 5. GEMMs (A-shared per ntype, long blocks first) | sort
  sortgemm_k<<<2 * GB + 3 * NB, 256, 0, stream>>>(recs, bptr, rowptr, feat_net, feat_cell,
                                                  Wl_bf, Wg_bf, P_net, P_cell, hbuf0, hbuf1, hbuf2);
  // 6. aggF r0 (net) | elem (cell)
  aggelem_k<<<2 * AB, 256, 0, stream>>>(hbuf0, recs, rowptr, logit, logit + (size_t)NN,
                                        P_net, cvec, W2, buf_net, P_cell, buf_cell);
  // 7. aggF r1 (cell) | fusedF net
  aggfused1_k<<<AB + GB, 256, 0, stream>>>(hbuf1, recs + (size_t)NE, rowptr + (NN + 1),
                                           logit + (size_t)2 * NN, logit + (size_t)3 * NN,
                                           P_cell, buf_cell, buf_net, P_net, buf_net, W2, cvec);
  // 8. aggF r2 final (net fp32) | fusedF cell final (fp32)
  aggfused2_k<<<AB + GB, 256, 0, stream>>>(hbuf2, recs + (size_t)2 * NE, rowptr + 2 * (NN + 1),
                                           logit + (size_t)4 * NN, logit + (size_t)5 * NN,
                                           buf_net, P_net, out_f,
                                           buf_cell, P_cell, out_f + (size_t)NN * 128, W2, cvec);
}

// Round 8
// 433.648 us; speedup vs baseline: 2.0274x; 1.0836x over previous
//
#include <hip/hip_runtime.h>
#include <hip/hip_bf16.h>
#include <stdint.h>

// ParaGraph: 2 node types (net/cell, N=100000), 3 relations (E=600000 each), D=128.
// I/O FP32. All intermediates bf16. W pre-converted bf16. 6 dispatches:
// prep | logbh | bscan | bscatter | sortgemm | tail.
// tail_k: the whole post-GEMM pipeline is node-local (GAT reads precomputed h, not
// the evolving out), so one block = 16 nodes runs gat/F phases back-to-back with the
// node tile resident in LDS -- no buf HBM round trips.
#define NN 100000
#define NE 600000
#define SP 136        // LDS row stride (ushorts): 128 + 8 pad
#define NB 782        // ceil(NN/128) dst buckets of 128 nodes
#define BCAP 1600     // LDS rec capacity per bucket (mean 767, sd ~28)
#define CHUNK 4096    // edges per partition block
#define NCH 147       // ceil(NE/CHUNK)
#define GB 1563       // ceil(NN/64) GEMM row-blocks
#define AB 6250       // NN/16 node-tile blocks (exact)

typedef unsigned short u16;
typedef unsigned int u32;
typedef __attribute__((ext_vector_type(8))) short short8;
typedef __attribute__((ext_vector_type(8))) __bf16 bf16x8;
typedef __attribute__((ext_vector_type(4))) float floatx4;

__device__ __forceinline__ float b2f(u16 u) {
  union { float f; u32 i; } c; c.i = ((u32)u) << 16; return c.f;
}
__device__ __forceinline__ u16 f2b(float f) {
  union { float f; u32 i; } c; c.f = f;
  u32 r = c.i + 0x7FFFu + ((c.i >> 16) & 1u);  // RNE
  return (u16)(r >> 16);
}

// ================= device bodies =================

// one W-tile pass (64-row GEMM): stage W -> sync -> MFMA -> store C
__device__ __forceinline__ void gemm_w(const u16* __restrict__ W, int ldw, u16* __restrict__ C,
                                       u16* lds, int tid, int row0, const bf16x8* a,
                                       int m16, int quad, int wv) {
#pragma unroll
  for (int it = 0; it < 8; ++it) {
    int idx = it * 256 + tid;
    int r = idx >> 4, c = (idx & 15) << 3;
    *(short8*)(&lds[r * SP + c]) = *(const short8*)(W + (size_t)r * ldw + c);
  }
  __syncthreads();
  const u16* brow = &lds[m16 * SP + quad * 8];
  floatx4 acc[8];
#pragma unroll
  for (int c = 0; c < 8; ++c) acc[c] = floatx4{0.f, 0.f, 0.f, 0.f};
#pragma unroll
  for (int kk = 0; kk < 4; ++kk) {
#pragma unroll
    for (int c = 0; c < 8; ++c) {
      bf16x8 bfr = *(const bf16x8*)(brow + c * 16 * SP + kk * 32);
      acc[c] = __builtin_amdgcn_mfma_f32_16x16x32_bf16(a[kk], bfr, acc[c], 0, 0, 0);
    }
  }
#pragma unroll
  for (int c = 0; c < 8; ++c) {
    int col = c * 16 + m16;
#pragma unroll
    for (int r = 0; r < 4; ++r) {
      int grow = row0 + wv * 16 + quad * 4 + r;
      if (grow < NN) C[(size_t)grow * 128 + col] = f2b(acc[c][r]);
    }
  }
}

// stage W2 (Wl cols 128..255, ldw 256) into LDS -- plain 16B copies
__device__ __forceinline__ void stageW2(const u16* __restrict__ W2, u16* Wlds, int tid) {
#pragma unroll
  for (int it = 0; it < 8; ++it) {
    int idx = it * 256 + tid;
    int r = idx >> 4, c = (idx & 15) << 3;
    *(short8*)(&Wlds[r * SP + c]) = *(const short8*)(W2 + (size_t)r * 256 + c);
  }
}

// gather phase: group g (16 lanes) softmax-aggregates node n's edges into Alds row.
// INIT=1: start from current Alds row (same-thread slot, no barrier needed around RMW).
template<int INIT>
__device__ __forceinline__ void gat_phase(int nb, int tid, const u16* __restrict__ h,
                                          const u32* __restrict__ srecs, const int* __restrict__ rp,
                                          const float* __restrict__ el, const float* __restrict__ er,
                                          u16* Alds) {
  int sub = tid & 15, g = tid >> 4;
  int n = nb * 16 + g;                    // NN = 6250*16, no tail
  int start = rp[n], end = rp[n + 1];
  float row[8];
  if (INIT) {
    short8 pv = *(const short8*)(&Alds[g * SP + sub * 8]);
#pragma unroll
    for (int t = 0; t < 8; ++t) row[t] = b2f((u16)pv[t]);
  } else {
#pragma unroll
    for (int t = 0; t < 8; ++t) row[t] = 0.f;
  }
  if (start < end) {
    float ern = er[n];
    float acc[8];
#pragma unroll
    for (int t = 0; t < 8; ++t) acc[t] = 0.f;
    float sl = 0.f;
    const u16* hsub = h + sub * 8;
    for (int base = start; base < end; base += 16) {
      int m = end - base; if (m > 16) m = 16;
      int srci = 0; float w = 0.f;
      if (sub < m) {
        srci = (int)srecs[base + sub];
        float l = el[srci] + ern;
        l = (l >= 0.f) ? l : 0.2f * l;
        w = __expf(l);
      }
      sl += w;
      for (int i = 0; i < m; ++i) {
        float x = __shfl(w, i, 16);
        int sv = __shfl(srci, i, 16);
        short8 hv = *(const short8*)(hsub + (size_t)sv * 128);
#pragma unroll
        for (int t = 0; t < 8; ++t) acc[t] += x * b2f((u16)hv[t]);
      }
    }
    float s = sl;
#pragma unroll
    for (int off = 8; off > 0; off >>= 1) s += __shfl_xor(s, off, 16);
    float inv = 1.f / s;
#pragma unroll
    for (int t = 0; t < 8; ++t) row[t] += acc[t] * inv;
  }
  short8 rb;
#pragma unroll
  for (int t = 0; t < 8; ++t) rb[t] = (short)f2b(row[t]);
  *(short8*)(&Alds[g * SP + sub * 8]) = rb;
}

// F phase: tile = relu(P + Alds @ W2.T + c). TO_GLOBAL: write fp32 out; else bf16 -> Alds.
// Caller must barrier between the producing phase and this (Alds reads).
template<int TO_GLOBAL>
__device__ __forceinline__ void F_phase(int nb, int tid, const u16* __restrict__ P,
                                        const float* __restrict__ cvec,
                                        const u16* Wlds, u16* Alds, void* __restrict__ out) {
  const int lane = tid & 63, wv = tid >> 6;
  const int m16 = lane & 15, quad = lane >> 4;
  const u16* arow = &Alds[m16 * SP + quad * 8];
  bf16x8 a[4];
#pragma unroll
  for (int kk = 0; kk < 4; ++kk) a[kk] = *(const bf16x8*)(arow + kk * 32);
  if (!TO_GLOBAL) __syncthreads();      // all A reads landed before overwrite
  const u16* brow = &Wlds[m16 * SP + quad * 8];
  floatx4 acc2[2];
#pragma unroll
  for (int cc = 0; cc < 2; ++cc) acc2[cc] = floatx4{0.f, 0.f, 0.f, 0.f};
#pragma unroll
  for (int kk = 0; kk < 4; ++kk) {
#pragma unroll
    for (int cc = 0; cc < 2; ++cc) {
      int ct = wv * 2 + cc;
      bf16x8 bfr = *(const bf16x8*)(brow + ct * 16 * SP + kk * 32);
      acc2[cc] = __builtin_amdgcn_mfma_f32_16x16x32_bf16(a[kk], bfr, acc2[cc], 0, 0, 0);
    }
  }
#pragma unroll
  for (int cc = 0; cc < 2; ++cc) {
    int ct = wv * 2 + cc;
    int col = ct * 16 + m16;
    float cv = cvec[col];
#pragma unroll
    for (int r = 0; r < 4; ++r) {
      int nrow = quad * 4 + r;
      int node = nb * 16 + nrow;
      float v = acc2[cc][r] + b2f(P[(size_t)node * 128 + col]) + cv;
      v = fmaxf(v, 0.f);
      if (TO_GLOBAL) ((float*)out)[(size_t)node * 128 + col] = v;
      else           Alds[nrow * SP + col] = f2b(v);
    }
  }
  if (!TO_GLOBAL) __syncthreads();      // tile complete before next phase reads
}

// ================= kernels =================

// prep: proj (12500) | conv (128) | vec (7) | zero bcnt (3)
__global__ __launch_bounds__(256) void prep_k(const float* __restrict__ x_net, const float* __restrict__ x_cell,
                                              const float* __restrict__ Wp_net, const float* __restrict__ Wp_cell,
                                              u16* __restrict__ feat_net, u16* __restrict__ feat_cell,
                                              const float* __restrict__ Wl, const float* __restrict__ Wg0,
                                              const float* __restrict__ Wg1, const float* __restrict__ Wg2,
                                              u16* __restrict__ Wl_bf, u16* __restrict__ Wg_bf,
                                              const float* al0, const float* ar0, const float* al1,
                                              const float* ar1, const float* al2, const float* ar2,
                                              const float* bias, float* __restrict__ vecs,
                                              int* __restrict__ bcnt) {
  int bid = blockIdx.x, tid = threadIdx.x;
  if (bid < 2 * AB) {
    int y = bid >= AB;
    int bx = y ? bid - AB : bid;
    const float* x  = y ? x_cell : x_net;
    const float* Wp = y ? Wp_cell : Wp_net;
    u16* feat       = y ? feat_cell : feat_net;
    __shared__ float Ws[128 * 17];
    __shared__ float xs[16][17];
#pragma unroll
    for (int it = 0; it < 8; ++it) {
      int idx = it * 256 + tid;
      int j = idx >> 4, k = idx & 15;
      Ws[j * 17 + k] = Wp[idx];
    }
    int n0 = bx * 16;
    { int nn = tid >> 4, k = tid & 15;
      xs[nn][k] = x[(size_t)(n0 + nn) * 16 + k]; }
    __syncthreads();
    int j = tid & 127, g = tid >> 7;
    float acc[8];
#pragma unroll
    for (int r = 0; r < 8; ++r) acc[r] = 0.f;
#pragma unroll
    for (int k = 0; k < 16; ++k) {
      float w = Ws[j * 17 + k];
#pragma unroll
      for (int r = 0; r < 8; ++r) acc[r] += xs[g * 8 + r][k] * w;
    }
#pragma unroll
    for (int r = 0; r < 8; ++r)
      feat[(size_t)(n0 + g * 8 + r) * 128 + j] = f2b(acc[r]);
  } else if (bid < 2 * AB + 128) {
    int cid = bid - 2 * AB;
    int y = cid >> 5, bx = cid & 31;
    const float* src = (y == 0) ? Wl : (y == 1) ? Wg0 : (y == 2) ? Wg1 : Wg2;
    u16* dst = (y == 0) ? Wl_bf : Wg_bf + (size_t)(y - 1) * 16384;
    int n = (y == 0) ? 32768 : 16384;
    int i = (bx * 256 + tid) * 4;
    if (i >= n) return;
    float4 v = *(const float4*)(src + i);
    ushort4 p; p.x = f2b(v.x); p.y = f2b(v.y); p.z = f2b(v.z); p.w = f2b(v.w);
    *(ushort4*)(dst + i) = p;
  } else if (bid < 2 * AB + 135) {
    int a = bid - (2 * AB + 128);
    if (tid >= 128) return;
    int j = tid;
    float s = 0.f;
    if (a < 6) {
      const float* W = (a < 2) ? Wg0 : (a < 4) ? Wg1 : Wg2;
      const float* v = (a == 0) ? al0 : (a == 1) ? ar0 : (a == 2) ? al1 : (a == 3) ? ar1 : (a == 4) ? al2 : ar2;
      for (int i = 0; i < 128; ++i) s += W[i * 128 + j] * v[i];
    } else {
      for (int i = 0; i < 128; ++i) s += Wl[(size_t)j * 256 + 128 + i] * bias[i];
    }
    vecs[a * 128 + j] = s;
  } else {
    int r = bid - (2 * AB + 135);
    for (int i = tid; i < NB; i += 256) bcnt[(size_t)r * NB + i] = 0;
  }
}

// logbh: logits (782) | bhist (441)
__global__ __launch_bounds__(256) void logbh_k(const u16* __restrict__ feat_net, const u16* __restrict__ feat_cell,
                                               const float* __restrict__ vecs, float* __restrict__ outs,
                                               const int* __restrict__ dst0, const int* __restrict__ dst1,
                                               const int* __restrict__ dst2, int* __restrict__ bcnt) {
  __shared__ int sm[NB];
  int bid = blockIdx.x, tid = threadIdx.x;
  if (bid < 782) {
    float* vs = (float*)sm;
#pragma unroll
    for (int it = 0; it < 3; ++it) vs[it * 256 + tid] = vecs[it * 256 + tid];
    __syncthreads();
    int y = bid >= 391;
    int bx = y ? bid - 391 : bid;
    const u16* f = y ? feat_cell : feat_net;
    int n = bx * 256 + tid;
    if (n >= NN) return;
    const u16* row = f + (size_t)n * 128;
    if (y == 0) {
      float s1 = 0.f, s2 = 0.f, s4 = 0.f, s5 = 0.f;
#pragma unroll
      for (int k = 0; k < 128; k += 8) {
        short8 u = *(const short8*)(row + k);
#pragma unroll
        for (int t = 0; t < 8; ++t) {
          float fv = b2f((u16)u[t]);
          s1 += fv * vs[1 * 128 + k + t]; s2 += fv * vs[2 * 128 + k + t];
          s4 += fv * vs[4 * 128 + k + t]; s5 += fv * vs[5 * 128 + k + t];
        }
      }
      outs[(size_t)1 * NN + n] = s1; outs[(size_t)2 * NN + n] = s2;
      outs[(size_t)4 * NN + n] = s4; outs[(size_t)5 * NN + n] = s5;
    } else {
      float s0 = 0.f, s3 = 0.f;
#pragma unroll
      for (int k = 0; k < 128; k += 8) {
        short8 u = *(const short8*)(row + k);
#pragma unroll
        for (int t = 0; t < 8; ++t) {
          float fv = b2f((u16)u[t]);
          s0 += fv * vs[0 * 128 + k + t]; s3 += fv * vs[3 * 128 + k + t];
        }
      }
      outs[(size_t)0 * NN + n] = s0; outs[(size_t)3 * NN + n] = s3;
    }
  } else {
    int e = bid - 782;
    int r = e / NCH, bx = e % NCH;
    const int* dst = (r == 0) ? dst0 : (r == 1) ? dst1 : dst2;
    for (int i = tid; i < NB; i += 256) sm[i] = 0;
    __syncthreads();
    int e0 = bx * CHUNK;
    int cnt = NE - e0; if (cnt > CHUNK) cnt = CHUNK;
    for (int i = tid; i < cnt; i += 256) atomicAdd(&sm[((u32)dst[e0 + i]) >> 7], 1);
    __syncthreads();
    for (int b = tid; b < NB; b += 256) {
      int c = sm[b];
      if (c) atomicAdd(&bcnt[(size_t)r * NB + b], c);
    }
  }
}

// exclusive scan of NB counters per relation
__global__ __launch_bounds__(1024) void bscan_k(const int* __restrict__ bcnt, int* __restrict__ bptr,
                                                int* __restrict__ bcur) {
  int r = blockIdx.x, t = threadIdx.x;
  const int* c = bcnt + (size_t)r * NB;
  int* p = bptr + (size_t)r * (NB + 1);
  int* cur = bcur + (size_t)r * NB;
  int v = (t < NB) ? c[t] : 0;
  __shared__ int ss[1024];
  ss[t] = v; __syncthreads();
  for (int off = 1; off < 1024; off <<= 1) {
    int u = (t >= off) ? ss[t - off] : 0;
    __syncthreads();
    ss[t] += u;
    __syncthreads();
  }
  if (t < NB) { int e = ss[t] - v; p[t] = e; cur[t] = e; }
  if (t == 1023) p[NB] = ss[1023];
}

// block-local radix partition (coalesced run-writes)
__global__ __launch_bounds__(256) void bscatter_k(const int* __restrict__ src0, const int* __restrict__ dst0,
                                                  const int* __restrict__ src1, const int* __restrict__ dst1,
                                                  const int* __restrict__ src2, const int* __restrict__ dst2,
                                                  int* __restrict__ bcur, u32* __restrict__ recs) {
  int r = blockIdx.y;
  const int* src = (r == 0) ? src0 : (r == 1) ? src1 : src2;
  const int* dst = (r == 0) ? dst0 : (r == 1) ? dst1 : dst2;
  __shared__ int hist[NB];
  __shared__ int lstart[NB];
  __shared__ int lcur[NB];
  __shared__ int badj[NB];
  __shared__ u32 rbuf[CHUNK];
  __shared__ u16 kbuf[CHUNK];
  __shared__ int ss[256];
  int tid = threadIdx.x;
  int e0 = blockIdx.x * CHUNK;
  int cnt = NE - e0; if (cnt > CHUNK) cnt = CHUNK;

  for (int i = tid; i < NB; i += 256) hist[i] = 0;
  __syncthreads();
  for (int i = tid; i < cnt; i += 256) atomicAdd(&hist[((u32)dst[e0 + i]) >> 7], 1);
  __syncthreads();
  int loc[4]; int s = 0;
  int base4 = tid * 4;
#pragma unroll
  for (int j = 0; j < 4; ++j) {
    int idx = base4 + j;
    int v = (idx < NB) ? hist[idx] : 0;
    loc[j] = s; s += v;
  }
  ss[tid] = s; __syncthreads();
  for (int off = 1; off < 256; off <<= 1) {
    int u = (tid >= off) ? ss[tid - off] : 0;
    __syncthreads();
    ss[tid] += u;
    __syncthreads();
  }
  int ex = ss[tid] - s;
#pragma unroll
  for (int j = 0; j < 4; ++j) {
    int idx = base4 + j;
    if (idx < NB) { int e = ex + loc[j]; lstart[idx] = e; lcur[idx] = e; }
  }
  __syncthreads();
  for (int b = tid; b < NB; b += 256) {
    int c = hist[b];
    int g = 0;
    if (c) g = atomicAdd(&bcur[(size_t)r * NB + b], c);
    badj[b] = g - lstart[b];
  }
  __syncthreads();
  for (int i = tid; i < cnt; i += 256) {
    int dN = dst[e0 + i], sN = src[e0 + i];
    int b = ((u32)dN) >> 7;
    int pos = atomicAdd(&lcur[b], 1);
    rbuf[pos] = ((u32)(dN & 127) << 17) | (u32)sN;
    kbuf[pos] = (u16)b;
  }
  __syncthreads();
  u32* out = recs + (size_t)r * NE;
  for (int i = tid; i < cnt; i += 256) {
    int b = kbuf[i];
    out[badj[b] + i] = rbuf[i];
  }
}

// sortgemm: GEMM blocks first (long blocks early), then sort blocks
__global__ __launch_bounds__(256) void sortgemm_k(u32* __restrict__ recs, const int* __restrict__ bptr,
                                                  int* __restrict__ rowptr,
                                                  const u16* __restrict__ feat_net, const u16* __restrict__ feat_cell,
                                                  const u16* __restrict__ Wl_bf, const u16* __restrict__ Wg_bf,
                                                  u16* __restrict__ P_net, u16* __restrict__ P_cell,
                                                  u16* __restrict__ h0, u16* __restrict__ h1, u16* __restrict__ h2) {
  __shared__ u32 smem[128 * SP / 2];   // 34816 B, shared by both paths
  int bid = blockIdx.x, tid = threadIdx.x;
  if (bid < 2 * GB) {
    int ntype = bid >= GB;
    int blk = ntype ? bid - GB : bid;
    u16* lds = (u16*)smem;
    const u16* A = ntype ? feat_cell : feat_net;
    const int row0 = blk * 64;
    const int lane = tid & 63, wv = tid >> 6;
    const int m16 = lane & 15, quad = lane >> 4;
    int arow = row0 + wv * 16 + m16;
    if (arow >= NN) arow = NN - 1;
    const u16* Ab = A + (size_t)arow * 128 + quad * 8;
    bf16x8 a[4];
#pragma unroll
    for (int kk = 0; kk < 4; ++kk) a[kk] = *(const bf16x8*)(Ab + kk * 32);
    if (!ntype) {
      gemm_w(Wl_bf,          256, P_net, lds, tid, row0, a, m16, quad, wv);
      __syncthreads();
      gemm_w(Wg_bf + 16384,  128, h1,    lds, tid, row0, a, m16, quad, wv);
      __syncthreads();
      gemm_w(Wg_bf + 32768,  128, h2,    lds, tid, row0, a, m16, quad, wv);
    } else {
      gemm_w(Wl_bf,          256, P_cell, lds, tid, row0, a, m16, quad, wv);
      __syncthreads();
      gemm_w(Wg_bf,          128, h0,     lds, tid, row0, a, m16, quad, wv);
    }
  } else {
    int sb = bid - 2 * GB;
    int r = sb / NB, b = sb % NB;
    const int* p = bptr + (size_t)r * (NB + 1);
    u32* rec = recs + (size_t)r * NE;
    int* rp = rowptr + (size_t)r * (NN + 1);
    int base = p[b], end = p[b + 1];
    int cnt = end - base; if (cnt > BCAP) cnt = BCAP;
    u32* rs = smem;
    int* hist = (int*)(smem + BCAP);
    int* excl = hist + 128;
    int* cur  = excl + 128;
    for (int i = tid; i < cnt; i += 256) rs[i] = rec[base + i];
    if (tid < 128) hist[tid] = 0;
    __syncthreads();
    for (int i = tid; i < cnt; i += 256) atomicAdd(&hist[rs[i] >> 17], 1);
    __syncthreads();
    if (tid < 128) cur[tid] = hist[tid];
    __syncthreads();
    for (int off = 1; off < 128; off <<= 1) {
      int v = 0;
      if (tid < 128 && tid >= off) v = cur[tid - off];
      __syncthreads();
      if (tid < 128) cur[tid] += v;
      __syncthreads();
    }
    if (tid < 128) {
      int e = cur[tid] - hist[tid];
      excl[tid] = e;
      int node = b * 128 + tid;
      if (node < NN) rp[node] = base + e;
    }
    if (b == NB - 1 && tid == 0) rp[NN] = p[NB];
    if (tid < 128) cur[tid] = excl[tid];
    __syncthreads();
    for (int i = tid; i < cnt; i += 256) {
      u32 v = rs[i];
      int pos = atomicAdd(&cur[v >> 17], 1);
      rec[base + pos] = v & 0x1FFFFu;
    }
  }
}

// tail: whole post-GEMM pipeline, one block per 16 nodes.
// net (bid<AB):  A=gat0 -> F -> F -> A+=gat2 -> F(final fp32)
// cell:          A=relu(P+c) -> A+=gat1 -> F -> F(final fp32)
__global__ __launch_bounds__(256) void tail_k(const u16* __restrict__ h0, const u16* __restrict__ h1,
                                              const u16* __restrict__ h2,
                                              const u32* __restrict__ recs, const int* __restrict__ rowptr,
                                              const float* __restrict__ logit,
                                              const u16* __restrict__ P_net, const u16* __restrict__ P_cell,
                                              const u16* __restrict__ W2, const float* __restrict__ cvec,
                                              float* __restrict__ out_net, float* __restrict__ out_cell) {
  __shared__ u16 Wlds[128 * SP];
  __shared__ u16 Alds[16 * SP];
  int bid = blockIdx.x, tid = threadIdx.x;
  stageW2(W2, Wlds, tid);
  if (bid < AB) {
    int nb = bid;  // net tile
    gat_phase<0>(nb, tid, h0, recs, rowptr, logit, logit + (size_t)NN, Alds);
    __syncthreads();                                   // covers W2 staging too
    F_phase<0>(nb, tid, P_net, cvec, Wlds, Alds, nullptr);   // buf_net0 -> Alds
    F_phase<0>(nb, tid, P_net, cvec, Wlds, Alds, nullptr);   // buf_net1 -> Alds
    gat_phase<1>(nb, tid, h2, recs + (size_t)2 * NE, rowptr + 2 * (NN + 1),
                 logit + (size_t)4 * NN, logit + (size_t)5 * NN, Alds);
    __syncthreads();
    F_phase<1>(nb, tid, P_net, cvec, Wlds, Alds, (void*)out_net);   // final
  } else {
    int nb = bid - AB;  // cell tile
    {  // elem init: relu(P_cell + cvec) -> Alds (same-thread slot as gat)
      int sub = tid & 15, g = tid >> 4;
      int n = nb * 16 + g;
      short8 pv = *(const short8*)(P_cell + (size_t)n * 128 + sub * 8);
      short8 rb;
#pragma unroll
      for (int t = 0; t < 8; ++t)
        rb[t] = (short)f2b(fmaxf(b2f((u16)pv[t]) + cvec[sub * 8 + t], 0.f));
      *(short8*)(&Alds[g * SP + sub * 8]) = rb;
    }
    // no barrier needed: gat_phase<1> reads the slot this same thread just wrote
    gat_phase<1>(nb, tid, h1, recs + (size_t)NE, rowptr + (NN + 1),
                 logit + (size_t)2 * NN, logit + (size_t)3 * NN, Alds);
    __syncthreads();                                   // covers W2 staging too
    F_phase<0>(nb, tid, P_cell, cvec, Wlds, Alds, nullptr);  // buf_cell1 -> Alds
    F_phase<1>(nb, tid, P_cell, cvec, Wlds, Alds, (void*)out_cell);  // final
  }
}

extern "C" void kernel_launch(void* const* d_in, const int* in_sizes, int n_in,
                              void* d_out, int out_size, void* d_ws, size_t ws_size,
                              hipStream_t stream) {
  const float* x_net   = (const float*)d_in[0];
  const float* x_cell  = (const float*)d_in[1];
  const float* Wp_net  = (const float*)d_in[2];
  const float* Wp_cell = (const float*)d_in[3];
  const float* Wg[3] = {(const float*)d_in[4], (const float*)d_in[7], (const float*)d_in[10]};
  const float* al[3] = {(const float*)d_in[5], (const float*)d_in[8], (const float*)d_in[11]};
  const float* ar[3] = {(const float*)d_in[6], (const float*)d_in[9], (const float*)d_in[12]};
  const float* Wl    = (const float*)d_in[13];
  const float* bias  = (const float*)d_in[14];
  const int* src[3] = {(const int*)d_in[15], (const int*)d_in[17], (const int*)d_in[19]};
  const int* dst[3] = {(const int*)d_in[16], (const int*)d_in[18], (const int*)d_in[20]};

  char* ws = (char*)d_ws;
  size_t off = 0;
  auto alloc = [&](size_t b) { void* p = ws + off; off = (off + b + 255) & ~(size_t)255; return p; };
  u16*  feat_net  = (u16*)alloc((size_t)NN * 128 * 2);
  u16*  feat_cell = (u16*)alloc((size_t)NN * 128 * 2);
  u16*  hbuf0     = (u16*)alloc((size_t)NN * 128 * 2);
  u16*  hbuf1     = (u16*)alloc((size_t)NN * 128 * 2);
  u16*  hbuf2     = (u16*)alloc((size_t)NN * 128 * 2);
  u16*  P_net     = (u16*)alloc((size_t)NN * 128 * 2);
  u16*  P_cell    = (u16*)alloc((size_t)NN * 128 * 2);
  float* vecs     = (float*)alloc(7 * 128 * 4);
  float* logit    = (float*)alloc((size_t)6 * NN * 4);
  u16*   Wl_bf    = (u16*)alloc((size_t)128 * 256 * 2);
  u16*   Wg_bf    = (u16*)alloc((size_t)3 * 128 * 128 * 2);
  int*   bcnt     = (int*)alloc((size_t)3 * NB * 4);
  int*   bcur     = (int*)alloc((size_t)3 * NB * 4);
  int*   bptr     = (int*)alloc((size_t)3 * (NB + 1) * 4);
  int*   rowptr   = (int*)alloc((size_t)3 * (NN + 1) * 4);
  u32*   recs     = (u32*)alloc((size_t)3 * NE * 4);

  float* out_f = (float*)d_out;  // [2,N,D] fp32: net then cell
  const u16* W2 = Wl_bf + 128;   // Wl cols 128..255 (ldw 256)
  const float* cvec = vecs + 6 * 128;

  // 1. prep: proj | conv | vec | zero bcnt
  prep_k<<<2 * AB + 138, 256, 0, stream>>>(x_net, x_cell, Wp_net, Wp_cell, feat_net, feat_cell,
                                           Wl, Wg[0], Wg[1], Wg[2], Wl_bf, Wg_bf,
                                           al[0], ar[0], al[1], ar[1], al[2], ar[2], bias, vecs, bcnt);
  // 2. logits | bhist
  logbh_k<<<782 + 3 * NCH, 256, 0, stream>>>(feat_net, feat_cell, vecs, logit,
                                             dst[0], dst[1], dst[2], bcnt);
  // 3. scan
  bscan_k<<<3, 1024, 0, stream>>>(bcnt, bptr, bcur);
  // 4. scatter
  bscatter_k<<<dim3(NCH, 3), 256, 0, stream>>>(src[0], dst[0], src[1], dst[1], src[2], dst[2],
                                               bcur, recs);
  // 5. GEMMs | sort
  sortgemm_k<<<2 * GB + 3 * NB, 256, 0, stream>>>(recs, bptr, rowptr, feat_net, feat_cell,
                                                  Wl_bf, Wg_bf, P_net, P_cell, hbuf0, hbuf1, hbuf2);
  // 6. tail: full node-local pipeline
  tail_k<<<2 * AB, 256, 0, stream>>>(hbuf0, hbuf1, hbuf2, recs, rowptr, logit,
                                     P_net, P_cell, W2, cvec,
                                     out_f, out_f + (size_t)NN * 128);
}

// Round 9
// 429.187 us; speedup vs baseline: 2.0485x; 1.0104x over previous
//
#include <hip/hip_runtime.h>
#include <hip/hip_bf16.h>
#include <stdint.h>

// ParaGraph: 2 node types (net/cell, N=100000), 3 relations (E=600000 each), D=128.
// I/O FP32. All intermediates bf16. W pre-converted bf16. 6 dispatches:
// prep | logbh | bscan | bscatter | sortgemm | tail.
// tail_k: whole post-GEMM pipeline node-local, one block = 16 nodes, tile in LDS.
// Gather uses batched (8-deep) h-row prefetch: src shuffles issue independent loads
// before the exp computes -- breaks the per-edge serial latency chain.
#define NN 100000
#define NE 600000
#define SP 136        // LDS row stride (ushorts): 128 + 8 pad
#define NB 782        // ceil(NN/128) dst buckets of 128 nodes
#define BCAP 1600     // LDS rec capacity per bucket (mean 767, sd ~28)
#define CHUNK 4096    // edges per partition block
#define NCH 147       // ceil(NE/CHUNK)
#define GB 1563       // ceil(NN/64) GEMM row-blocks
#define AB 6250       // NN/16 node-tile blocks (exact)

typedef unsigned short u16;
typedef unsigned int u32;
typedef __attribute__((ext_vector_type(8))) short short8;
typedef __attribute__((ext_vector_type(8))) __bf16 bf16x8;
typedef __attribute__((ext_vector_type(4))) float floatx4;

__device__ __forceinline__ float b2f(u16 u) {
  union { float f; u32 i; } c; c.i = ((u32)u) << 16; return c.f;
}
__device__ __forceinline__ u16 f2b(float f) {
  union { float f; u32 i; } c; c.f = f;
  u32 r = c.i + 0x7FFFu + ((c.i >> 16) & 1u);  // RNE
  return (u16)(r >> 16);
}

// ================= device bodies =================

// one W-tile pass (64-row GEMM): stage W -> sync -> MFMA -> store C
__device__ __forceinline__ void gemm_w(const u16* __restrict__ W, int ldw, u16* __restrict__ C,
                                       u16* lds, int tid, int row0, const bf16x8* a,
                                       int m16, int quad, int wv) {
#pragma unroll
  for (int it = 0; it < 8; ++it) {
    int idx = it * 256 + tid;
    int r = idx >> 4, c = (idx & 15) << 3;
    *(short8*)(&lds[r * SP + c]) = *(const short8*)(W + (size_t)r * ldw + c);
  }
  __syncthreads();
  const u16* brow = &lds[m16 * SP + quad * 8];
  floatx4 acc[8];
#pragma unroll
  for (int c = 0; c < 8; ++c) acc[c] = floatx4{0.f, 0.f, 0.f, 0.f};
#pragma unroll
  for (int kk = 0; kk < 4; ++kk) {
#pragma unroll
    for (int c = 0; c < 8; ++c) {
      bf16x8 bfr = *(const bf16x8*)(brow + c * 16 * SP + kk * 32);
      acc[c] = __builtin_amdgcn_mfma_f32_16x16x32_bf16(a[kk], bfr, acc[c], 0, 0, 0);
    }
  }
#pragma unroll
  for (int c = 0; c < 8; ++c) {
    int col = c * 16 + m16;
#pragma unroll
    for (int r = 0; r < 4; ++r) {
      int grow = row0 + wv * 16 + quad * 4 + r;
      if (grow < NN) C[(size_t)grow * 128 + col] = f2b(acc[c][r]);
    }
  }
}

// stage W2 (Wl cols 128..255, ldw 256) into LDS -- plain 16B copies
__device__ __forceinline__ void stageW2(const u16* __restrict__ W2, u16* Wlds, int tid) {
#pragma unroll
  for (int it = 0; it < 8; ++it) {
    int idx = it * 256 + tid;
    int r = idx >> 4, c = (idx & 15) << 3;
    *(short8*)(&Wlds[r * SP + c]) = *(const short8*)(W2 + (size_t)r * 256 + c);
  }
}

// gather phase: group g (16 lanes) softmax-aggregates node n's edges into Alds row.
// Batched 8-deep h-row prefetch: loads depend only on shfl(srci), issued before the
// exp computes; accumulate once weights are shuffled. INIT=1: start from Alds row.
template<int INIT>
__device__ __forceinline__ void gat_phase(int nb, int tid, const u16* __restrict__ h,
                                          const u32* __restrict__ srecs, const int* __restrict__ rp,
                                          const float* __restrict__ el, const float* __restrict__ er,
                                          u16* Alds) {
  int sub = tid & 15, g = tid >> 4;
  int n = nb * 16 + g;                    // NN = 6250*16, no tail
  int start = rp[n], end = rp[n + 1];
  float row[8];
  if (INIT) {
    short8 pv = *(const short8*)(&Alds[g * SP + sub * 8]);
#pragma unroll
    for (int t = 0; t < 8; ++t) row[t] = b2f((u16)pv[t]);
  } else {
#pragma unroll
    for (int t = 0; t < 8; ++t) row[t] = 0.f;
  }
  if (start < end) {
    float ern = er[n];
    float acc[8];
#pragma unroll
    for (int t = 0; t < 8; ++t) acc[t] = 0.f;
    float sl = 0.f;
    const u16* hsub = h + sub * 8;
    for (int base = start; base < end; base += 16) {
      int m = end - base; if (m > 16) m = 16;
      int srci = 0;
      if (sub < m) srci = (int)srecs[base + sub];
      // batch 1: issue up to 8 independent h-row loads (need only srci shuffles)
      short8 hv[8];
      int mm1 = (m > 8) ? 8 : m;
#pragma unroll
      for (int j = 0; j < 8; ++j) {
        if (j < mm1) {
          int sv = __shfl(srci, j, 16);
          hv[j] = *(const short8*)(hsub + (size_t)sv * 128);
        }
      }
      // edge weight computes while loads are in flight
      float w = 0.f;
      if (sub < m) {
        float l = el[srci] + ern;
        l = (l >= 0.f) ? l : 0.2f * l;
        w = __expf(l);
      }
      sl += w;
#pragma unroll
      for (int j = 0; j < 8; ++j) {
        if (j < mm1) {
          float x = __shfl(w, j, 16);
#pragma unroll
          for (int t = 0; t < 8; ++t) acc[t] += x * b2f((u16)hv[j][t]);
        }
      }
      if (m > 8) {
        short8 hv2[8];
        int mm2 = m - 8;
#pragma unroll
        for (int j = 0; j < 8; ++j) {
          if (j < mm2) {
            int sv = __shfl(srci, 8 + j, 16);
            hv2[j] = *(const short8*)(hsub + (size_t)sv * 128);
          }
        }
#pragma unroll
        for (int j = 0; j < 8; ++j) {
          if (j < mm2) {
            float x = __shfl(w, 8 + j, 16);
#pragma unroll
            for (int t = 0; t < 8; ++t) acc[t] += x * b2f((u16)hv2[j][t]);
          }
        }
      }
    }
    float s = sl;
#pragma unroll
    for (int off = 8; off > 0; off >>= 1) s += __shfl_xor(s, off, 16);
    float inv = 1.f / s;
#pragma unroll
    for (int t = 0; t < 8; ++t) row[t] += acc[t] * inv;
  }
  short8 rb;
#pragma unroll
  for (int t = 0; t < 8; ++t) rb[t] = (short)f2b(row[t]);
  *(short8*)(&Alds[g * SP + sub * 8]) = rb;
}

// F phase: tile = relu(P + Alds @ W2.T + c). TO_GLOBAL: write fp32 out; else bf16 -> Alds.
template<int TO_GLOBAL>
__device__ __forceinline__ void F_phase(int nb, int tid, const u16* __restrict__ P,
                                        const float* __restrict__ cvec,
                                        const u16* Wlds, u16* Alds, void* __restrict__ out) {
  const int lane = tid & 63, wv = tid >> 6;
  const int m16 = lane & 15, quad = lane >> 4;
  const u16* arow = &Alds[m16 * SP + quad * 8];
  bf16x8 a[4];
#pragma unroll
  for (int kk = 0; kk < 4; ++kk) a[kk] = *(const bf16x8*)(arow + kk * 32);
  if (!TO_GLOBAL) __syncthreads();      // all A reads landed before overwrite
  const u16* brow = &Wlds[m16 * SP + quad * 8];
  floatx4 acc2[2];
#pragma unroll
  for (int cc = 0; cc < 2; ++cc) acc2[cc] = floatx4{0.f, 0.f, 0.f, 0.f};
#pragma unroll
  for (int kk = 0; kk < 4; ++kk) {
#pragma unroll
    for (int cc = 0; cc < 2; ++cc) {
      int ct = wv * 2 + cc;
      bf16x8 bfr = *(const bf16x8*)(brow + ct * 16 * SP + kk * 32);
      acc2[cc] = __builtin_amdgcn_mfma_f32_16x16x32_bf16(a[kk], bfr, acc2[cc], 0, 0, 0);
    }
  }
#pragma unroll
  for (int cc = 0; cc < 2; ++cc) {
    int ct = wv * 2 + cc;
    int col = ct * 16 + m16;
    float cv = cvec[col];
#pragma unroll
    for (int r = 0; r < 4; ++r) {
      int nrow = quad * 4 + r;
      int node = nb * 16 + nrow;
      float v = acc2[cc][r] + b2f(P[(size_t)node * 128 + col]) + cv;
      v = fmaxf(v, 0.f);
      if (TO_GLOBAL) ((float*)out)[(size_t)node * 128 + col] = v;
      else           Alds[nrow * SP + col] = f2b(v);
    }
  }
  if (!TO_GLOBAL) __syncthreads();      // tile complete before next phase reads
}

// ================= kernels =================

// prep: proj (12500) | conv (128) | vec (7) | zero bcnt (3)
__global__ __launch_bounds__(256) void prep_k(const float* __restrict__ x_net, const float* __restrict__ x_cell,
                                              const float* __restrict__ Wp_net, const float* __restrict__ Wp_cell,
                                              u16* __restrict__ feat_net, u16* __restrict__ feat_cell,
                                              const float* __restrict__ Wl, const float* __restrict__ Wg0,
                                              const float* __restrict__ Wg1, const float* __restrict__ Wg2,
                                              u16* __restrict__ Wl_bf, u16* __restrict__ Wg_bf,
                                              const float* al0, const float* ar0, const float* al1,
                                              const float* ar1, const float* al2, const float* ar2,
                                              const float* bias, float* __restrict__ vecs,
                                              int* __restrict__ bcnt) {
  int bid = blockIdx.x, tid = threadIdx.x;
  if (bid < 2 * AB) {
    int y = bid >= AB;
    int bx = y ? bid - AB : bid;
    const float* x  = y ? x_cell : x_net;
    const float* Wp = y ? Wp_cell : Wp_net;
    u16* feat       = y ? feat_cell : feat_net;
    __shared__ float Ws[128 * 17];
    __shared__ float xs[16][17];
#pragma unroll
    for (int it = 0; it < 8; ++it) {
      int idx = it * 256 + tid;
      int j = idx >> 4, k = idx & 15;
      Ws[j * 17 + k] = Wp[idx];
    }
    int n0 = bx * 16;
    { int nn = tid >> 4, k = tid & 15;
      xs[nn][k] = x[(size_t)(n0 + nn) * 16 + k]; }
    __syncthreads();
    int j = tid & 127, g = tid >> 7;
    float acc[8];
#pragma unroll
    for (int r = 0; r < 8; ++r) acc[r] = 0.f;
#pragma unroll
    for (int k = 0; k < 16; ++k) {
      float w = Ws[j * 17 + k];
#pragma unroll
      for (int r = 0; r < 8; ++r) acc[r] += xs[g * 8 + r][k] * w;
    }
#pragma unroll
    for (int r = 0; r < 8; ++r)
      feat[(size_t)(n0 + g * 8 + r) * 128 + j] = f2b(acc[r]);
  } else if (bid < 2 * AB + 128) {
    int cid = bid - 2 * AB;
    int y = cid >> 5, bx = cid & 31;
    const float* src = (y == 0) ? Wl : (y == 1) ? Wg0 : (y == 2) ? Wg1 : Wg2;
    u16* dst = (y == 0) ? Wl_bf : Wg_bf + (size_t)(y - 1) * 16384;
    int n = (y == 0) ? 32768 : 16384;
    int i = (bx * 256 + tid) * 4;
    if (i >= n) return;
    float4 v = *(const float4*)(src + i);
    ushort4 p; p.x = f2b(v.x); p.y = f2b(v.y); p.z = f2b(v.z); p.w = f2b(v.w);
    *(ushort4*)(dst + i) = p;
  } else if (bid < 2 * AB + 135) {
    int a = bid - (2 * AB + 128);
    if (tid >= 128) return;
    int j = tid;
    float s = 0.f;
    if (a < 6) {
      const float* W = (a < 2) ? Wg0 : (a < 4) ? Wg1 : Wg2;
      const float* v = (a == 0) ? al0 : (a == 1) ? ar0 : (a == 2) ? al1 : (a == 3) ? ar1 : (a == 4) ? al2 : ar2;
      for (int i = 0; i < 128; ++i) s += W[i * 128 + j] * v[i];
    } else {
      for (int i = 0; i < 128; ++i) s += Wl[(size_t)j * 256 + 128 + i] * bias[i];
    }
    vecs[a * 128 + j] = s;
  } else {
    int r = bid - (2 * AB + 135);
    for (int i = tid; i < NB; i += 256) bcnt[(size_t)r * NB + i] = 0;
  }
}

// logbh: logits (782) | bhist (441)
__global__ __launch_bounds__(256) void logbh_k(const u16* __restrict__ feat_net, const u16* __restrict__ feat_cell,
                                               const float* __restrict__ vecs, float* __restrict__ outs,
                                               const int* __restrict__ dst0, const int* __restrict__ dst1,
                                               const int* __restrict__ dst2, int* __restrict__ bcnt) {
  __shared__ int sm[NB];
  int bid = blockIdx.x, tid = threadIdx.x;
  if (bid < 782) {
    float* vs = (float*)sm;
#pragma unroll
    for (int it = 0; it < 3; ++it) vs[it * 256 + tid] = vecs[it * 256 + tid];
    __syncthreads();
    int y = bid >= 391;
    int bx = y ? bid - 391 : bid;
    const u16* f = y ? feat_cell : feat_net;
    int n = bx * 256 + tid;
    if (n >= NN) return;
    const u16* row = f + (size_t)n * 128;
    if (y == 0) {
      float s1 = 0.f, s2 = 0.f, s4 = 0.f, s5 = 0.f;
#pragma unroll
      for (int k = 0; k < 128; k += 8) {
        short8 u = *(const short8*)(row + k);
#pragma unroll
        for (int t = 0; t < 8; ++t) {
          float fv = b2f((u16)u[t]);
          s1 += fv * vs[1 * 128 + k + t]; s2 += fv * vs[2 * 128 + k + t];
          s4 += fv * vs[4 * 128 + k + t]; s5 += fv * vs[5 * 128 + k + t];
        }
      }
      outs[(size_t)1 * NN + n] = s1; outs[(size_t)2 * NN + n] = s2;
      outs[(size_t)4 * NN + n] = s4; outs[(size_t)5 * NN + n] = s5;
    } else {
      float s0 = 0.f, s3 = 0.f;
#pragma unroll
      for (int k = 0; k < 128; k += 8) {
        short8 u = *(const short8*)(row + k);
#pragma unroll
        for (int t = 0; t < 8; ++t) {
          float fv = b2f((u16)u[t]);
          s0 += fv * vs[0 * 128 + k + t]; s3 += fv * vs[3 * 128 + k + t];
        }
      }
      outs[(size_t)0 * NN + n] = s0; outs[(size_t)3 * NN + n] = s3;
    }
  } else {
    int e = bid - 782;
    int r = e / NCH, bx = e % NCH;
    const int* dst = (r == 0) ? dst0 : (r == 1) ? dst1 : dst2;
    for (int i = tid; i < NB; i += 256) sm[i] = 0;
    __syncthreads();
    int e0 = bx * CHUNK;
    int cnt = NE - e0; if (cnt > CHUNK) cnt = CHUNK;
    for (int i = tid; i < cnt; i += 256) atomicAdd(&sm[((u32)dst[e0 + i]) >> 7], 1);
    __syncthreads();
    for (int b = tid; b < NB; b += 256) {
      int c = sm[b];
      if (c) atomicAdd(&bcnt[(size_t)r * NB + b], c);
    }
  }
}

// exclusive scan of NB counters per relation
__global__ __launch_bounds__(1024) void bscan_k(const int* __restrict__ bcnt, int* __restrict__ bptr,
                                                int* __restrict__ bcur) {
  int r = blockIdx.x, t = threadIdx.x;
  const int* c = bcnt + (size_t)r * NB;
  int* p = bptr + (size_t)r * (NB + 1);
  int* cur = bcur + (size_t)r * NB;
  int v = (t < NB) ? c[t] : 0;
  __shared__ int ss[1024];
  ss[t] = v; __syncthreads();
  for (int off = 1; off < 1024; off <<= 1) {
    int u = (t >= off) ? ss[t - off] : 0;
    __syncthreads();
    ss[t] += u;
    __syncthreads();
  }
  if (t < NB) { int e = ss[t] - v; p[t] = e; cur[t] = e; }
  if (t == 1023) p[NB] = ss[1023];
}

// block-local radix partition (coalesced run-writes)
__global__ __launch_bounds__(256) void bscatter_k(const int* __restrict__ src0, const int* __restrict__ dst0,
                                                  const int* __restrict__ src1, const int* __restrict__ dst1,
                                                  const int* __restrict__ src2, const int* __restrict__ dst2,
                                                  int* __restrict__ bcur, u32* __restrict__ recs) {
  int r = blockIdx.y;
  const int* src = (r == 0) ? src0 : (r == 1) ? src1 : src2;
  const int* dst = (r == 0) ? dst0 : (r == 1) ? dst1 : dst2;
  __shared__ int hist[NB];
  __shared__ int lstart[NB];
  __shared__ int lcur[NB];
  __shared__ int badj[NB];
  __shared__ u32 rbuf[CHUNK];
  __shared__ u16 kbuf[CHUNK];
  __shared__ int ss[256];
  int tid = threadIdx.x;
  int e0 = blockIdx.x * CHUNK;
  int cnt = NE - e0; if (cnt > CHUNK) cnt = CHUNK;

  for (int i = tid; i < NB; i += 256) hist[i] = 0;
  __syncthreads();
  for (int i = tid; i < cnt; i += 256) atomicAdd(&hist[((u32)dst[e0 + i]) >> 7], 1);
  __syncthreads();
  int loc[4]; int s = 0;
  int base4 = tid * 4;
#pragma unroll
  for (int j = 0; j < 4; ++j) {
    int idx = base4 + j;
    int v = (idx < NB) ? hist[idx] : 0;
    loc[j] = s; s += v;
  }
  ss[tid] = s; __syncthreads();
  for (int off = 1; off < 256; off <<= 1) {
    int u = (tid >= off) ? ss[tid - off] : 0;
    __syncthreads();
    ss[tid] += u;
    __syncthreads();
  }
  int ex = ss[tid] - s;
#pragma unroll
  for (int j = 0; j < 4; ++j) {
    int idx = base4 + j;
    if (idx < NB) { int e = ex + loc[j]; lstart[idx] = e; lcur[idx] = e; }
  }
  __syncthreads();
  for (int b = tid; b < NB; b += 256) {
    int c = hist[b];
    int g = 0;
    if (c) g = atomicAdd(&bcur[(size_t)r * NB + b], c);
    badj[b] = g - lstart[b];
  }
  __syncthreads();
  for (int i = tid; i < cnt; i += 256) {
    int dN = dst[e0 + i], sN = src[e0 + i];
    int b = ((u32)dN) >> 7;
    int pos = atomicAdd(&lcur[b], 1);
    rbuf[pos] = ((u32)(dN & 127) << 17) | (u32)sN;
    kbuf[pos] = (u16)b;
  }
  __syncthreads();
  u32* out = recs + (size_t)r * NE;
  for (int i = tid; i < cnt; i += 256) {
    int b = kbuf[i];
    out[badj[b] + i] = rbuf[i];
  }
}

// sortgemm: GEMM blocks first (long blocks early), then sort blocks
__global__ __launch_bounds__(256) void sortgemm_k(u32* __restrict__ recs, const int* __restrict__ bptr,
                                                  int* __restrict__ rowptr,
                                                  const u16* __restrict__ feat_net, const u16* __restrict__ feat_cell,
                                                  const u16* __restrict__ Wl_bf, const u16* __restrict__ Wg_bf,
                                                  u16* __restrict__ P_net, u16* __restrict__ P_cell,
                                                  u16* __restrict__ h0, u16* __restrict__ h1, u16* __restrict__ h2) {
  __shared__ u32 smem[128 * SP / 2];   // 34816 B, shared by both paths
  int bid = blockIdx.x, tid = threadIdx.x;
  if (bid < 2 * GB) {
    int ntype = bid >= GB;
    int blk = ntype ? bid - GB : bid;
    u16* lds = (u16*)smem;
    const u16* A = ntype ? feat_cell : feat_net;
    const int row0 = blk * 64;
    const int lane = tid & 63, wv = tid >> 6;
    const int m16 = lane & 15, quad = lane >> 4;
    int arow = row0 + wv * 16 + m16;
    if (arow >= NN) arow = NN - 1;
    const u16* Ab = A + (size_t)arow * 128 + quad * 8;
    bf16x8 a[4];
#pragma unroll
    for (int kk = 0; kk < 4; ++kk) a[kk] = *(const bf16x8*)(Ab + kk * 32);
    if (!ntype) {
      gemm_w(Wl_bf,          256, P_net, lds, tid, row0, a, m16, quad, wv);
      __syncthreads();
      gemm_w(Wg_bf + 16384,  128, h1,    lds, tid, row0, a, m16, quad, wv);
      __syncthreads();
      gemm_w(Wg_bf + 32768,  128, h2,    lds, tid, row0, a, m16, quad, wv);
    } else {
      gemm_w(Wl_bf,          256, P_cell, lds, tid, row0, a, m16, quad, wv);
      __syncthreads();
      gemm_w(Wg_bf,          128, h0,     lds, tid, row0, a, m16, quad, wv);
    }
  } else {
    int sb = bid - 2 * GB;
    int r = sb / NB, b = sb % NB;
    const int* p = bptr + (size_t)r * (NB + 1);
    u32* rec = recs + (size_t)r * NE;
    int* rp = rowptr + (size_t)r * (NN + 1);
    int base = p[b], end = p[b + 1];
    int cnt = end - base; if (cnt > BCAP) cnt = BCAP;
    u32* rs = smem;
    int* hist = (int*)(smem + BCAP);
    int* excl = hist + 128;
    int* cur  = excl + 128;
    for (int i = tid; i < cnt; i += 256) rs[i] = rec[base + i];
    if (tid < 128) hist[tid] = 0;
    __syncthreads();
    for (int i = tid; i < cnt; i += 256) atomicAdd(&hist[rs[i] >> 17], 1);
    __syncthreads();
    if (tid < 128) cur[tid] = hist[tid];
    __syncthreads();
    for (int off = 1; off < 128; off <<= 1) {
      int v = 0;
      if (tid < 128 && tid >= off) v = cur[tid - off];
      __syncthreads();
      if (tid < 128) cur[tid] += v;
      __syncthreads();
    }
    if (tid < 128) {
      int e = cur[tid] - hist[tid];
      excl[tid] = e;
      int node = b * 128 + tid;
      if (node < NN) rp[node] = base + e;
    }
    if (b == NB - 1 && tid == 0) rp[NN] = p[NB];
    if (tid < 128) cur[tid] = excl[tid];
    __syncthreads();
    for (int i = tid; i < cnt; i += 256) {
      u32 v = rs[i];
      int pos = atomicAdd(&cur[v >> 17], 1);
      rec[base + pos] = v & 0x1FFFFu;
    }
  }
}

// tail: whole post-GEMM pipeline, one block per 16 nodes.
// net (bid<AB):  A=gat0 -> F -> F -> A+=gat2 -> F(final fp32)
// cell:          A=relu(P+c) -> A+=gat1 -> F -> F(final fp32)
__global__ __launch_bounds__(256) void tail_k(const u16* __restrict__ h0, const u16* __restrict__ h1,
                                              const u16* __restrict__ h2,
                                              const u32* __restrict__ recs, const int* __restrict__ rowptr,
                                              const float* __restrict__ logit,
                                              const u16* __restrict__ P_net, const u16* __restrict__ P_cell,
                                              const u16* __restrict__ W2, const float* __restrict__ cvec,
                                              float* __restrict__ out_net, float* __restrict__ out_cell) {
  __shared__ u16 Wlds[128 * SP];
  __shared__ u16 Alds[16 * SP];
  int bid = blockIdx.x, tid = threadIdx.x;
  stageW2(W2, Wlds, tid);
  if (bid < AB) {
    int nb = bid;  // net tile
    gat_phase<0>(nb, tid, h0, recs, rowptr, logit, logit + (size_t)NN, Alds);
    __syncthreads();                                   // covers W2 staging too
    F_phase<0>(nb, tid, P_net, cvec, Wlds, Alds, nullptr);   // buf_net0 -> Alds
    F_phase<0>(nb, tid, P_net, cvec, Wlds, Alds, nullptr);   // buf_net1 -> Alds
    gat_phase<1>(nb, tid, h2, recs + (size_t)2 * NE, rowptr + 2 * (NN + 1),
                 logit + (size_t)4 * NN, logit + (size_t)5 * NN, Alds);
    __syncthreads();
    F_phase<1>(nb, tid, P_net, cvec, Wlds, Alds, (void*)out_net);   // final
  } else {
    int nb = bid - AB;  // cell tile
    {  // elem init: relu(P_cell + cvec) -> Alds (same-thread slot as gat)
      int sub = tid & 15, g = tid >> 4;
      int n = nb * 16 + g;
      short8 pv = *(const short8*)(P_cell + (size_t)n * 128 + sub * 8);
      short8 rb;
#pragma unroll
      for (int t = 0; t < 8; ++t)
        rb[t] = (short)f2b(fmaxf(b2f((u16)pv[t]) + cvec[sub * 8 + t], 0.f));
      *(short8*)(&Alds[g * SP + sub * 8]) = rb;
    }
    // no barrier needed: gat_phase<1> reads the slot this same thread just wrote
    gat_phase<1>(nb, tid, h1, recs + (size_t)NE, rowptr + (NN + 1),
                 logit + (size_t)2 * NN, logit + (size_t)3 * NN, Alds);
    __syncthreads();                                   // covers W2 staging too
    F_phase<0>(nb, tid, P_cell, cvec, Wlds, Alds, nullptr);  // buf_cell1 -> Alds
    F_phase<1>(nb, tid, P_cell, cvec, Wlds, Alds, (void*)out_cell);  // final
  }
}

extern "C" void kernel_launch(void* const* d_in, const int* in_sizes, int n_in,
                              void* d_out, int out_size, void* d_ws, size_t ws_size,
                              hipStream_t stream) {
  const float* x_net   = (const float*)d_in[0];
  const float* x_cell  = (const float*)d_in[1];
  const float* Wp_net  = (const float*)d_in[2];
  const float* Wp_cell = (const float*)d_in[3];
  const float* Wg[3] = {(const float*)d_in[4], (const float*)d_in[7], (const float*)d_in[10]};
  const float* al[3] = {(const float*)d_in[5], (const float*)d_in[8], (const float*)d_in[11]};
  const float* ar[3] = {(const float*)d_in[6], (const float*)d_in[9], (const float*)d_in[12]};
  const float* Wl    = (const float*)d_in[13];
  const float* bias  = (const float*)d_in[14];
  const int* src[3] = {(const int*)d_in[15], (const int*)d_in[17], (const int*)d_in[19]};
  const int* dst[3] = {(const int*)d_in[16], (const int*)d_in[18], (const int*)d_in[20]};

  char* ws = (char*)d_ws;
  size_t off = 0;
  auto alloc = [&](size_t b) { void* p = ws + off; off = (off + b + 255) & ~(size_t)255; return p; };
  u16*  feat_net  = (u16*)alloc((size_t)NN * 128 * 2);
  u16*  feat_cell = (u16*)alloc((size_t)NN * 128 * 2);
  u16*  hbuf0     = (u16*)alloc((size_t)NN * 128 * 2);
  u16*  hbuf1     = (u16*)alloc((size_t)NN * 128 * 2);
  u16*  hbuf2     = (u16*)alloc((size_t)NN * 128 * 2);
  u16*  P_net     = (u16*)alloc((size_t)NN * 128 * 2);
  u16*  P_cell    = (u16*)alloc((size_t)NN * 128 * 2);
  float* vecs     = (float*)alloc(7 * 128 * 4);
  float* logit    = (float*)alloc((size_t)6 * NN * 4);
  u16*   Wl_bf    = (u16*)alloc((size_t)128 * 256 * 2);
  u16*   Wg_bf    = (u16*)alloc((size_t)3 * 128 * 128 * 2);
  int*   bcnt     = (int*)alloc((size_t)3 * NB * 4);
  int*   bcur     = (int*)alloc((size_t)3 * NB * 4);
  int*   bptr     = (int*)alloc((size_t)3 * (NB + 1) * 4);
  int*   rowptr   = (int*)alloc((size_t)3 * (NN + 1) * 4);
  u32*   recs     = (u32*)alloc((size_t)3 * NE * 4);

  float* out_f = (float*)d_out;  // [2,N,D] fp32: net then cell
  const u16* W2 = Wl_bf + 128;   // Wl cols 128..255 (ldw 256)
  const float* cvec = vecs + 6 * 128;

  // 1. prep: proj | conv | vec | zero bcnt
  prep_k<<<2 * AB + 138, 256, 0, stream>>>(x_net, x_cell, Wp_net, Wp_cell, feat_net, feat_cell,
                                           Wl, Wg[0], Wg[1], Wg[2], Wl_bf, Wg_bf,
                                           al[0], ar[0], al[1], ar[1], al[2], ar[2], bias, vecs, bcnt);
  // 2. logits | bhist
  logbh_k<<<782 + 3 * NCH, 256, 0, stream>>>(feat_net, feat_cell, vecs, logit,
                                             dst[0], dst[1], dst[2], bcnt);
  // 3. scan
  bscan_k<<<3, 1024, 0, stream>>>(bcnt, bptr, bcur);
  // 4. scatter
  bscatter_k<<<dim3(NCH, 3), 256, 0, stream>>>(src[0], dst[0], src[1], dst[1], src[2], dst[2],
                                               bcur, recs);
  // 5. GEMMs | sort
  sortgemm_k<<<2 * GB + 3 * NB, 256, 0, stream>>>(recs, bptr, rowptr, feat_net, feat_cell,
                                                  Wl_bf, Wg_bf, P_net, P_cell, hbuf0, hbuf1, hbuf2);
  // 6. tail: full node-local pipeline
  tail_k<<<2 * AB, 256, 0, stream>>>(hbuf0, hbuf1, hbuf2, recs, rowptr, logit,
                                     P_net, P_cell, W2, cvec,
                                     out_f, out_f + (size_t)NN * 128);
}

// Round 10
// 427.371 us; speedup vs baseline: 2.0572x; 1.0042x over previous
//
#include <hip/hip_runtime.h>
#include <hip/hip_bf16.h>
#include <stdint.h>

// ParaGraph: 2 node types (net/cell, N=100000), 3 relations (E=600000 each), D=128.
// I/O FP32. All intermediates bf16. W pre-converted bf16. 6 dispatches:
// prep | logbh | bscan | bscatter | sortgemm | tail.
// tail_k: whole post-GEMM pipeline node-local; 512 threads / 32 nodes per block
// (W2 LDS stage amortized 2x -> 24 waves/CU for the latency-bound gather).
#define NN 100000
#define NE 600000
#define SP 136        // LDS row stride (ushorts): 128 + 8 pad
#define NB 782        // ceil(NN/128) dst buckets of 128 nodes
#define BCAP 1600     // LDS rec capacity per bucket (mean 767, sd ~28)
#define CHUNK 4096    // edges per partition block
#define NCH 147       // ceil(NE/CHUNK)
#define GB 1563       // ceil(NN/64) GEMM row-blocks
#define AB 6250       // NN/16 (prep proj blocks)
#define ABT 3125      // NN/32 tail node-tile blocks per ntype (exact)

typedef unsigned short u16;
typedef unsigned int u32;
typedef __attribute__((ext_vector_type(8))) short short8;
typedef __attribute__((ext_vector_type(8))) __bf16 bf16x8;
typedef __attribute__((ext_vector_type(4))) float floatx4;

__device__ __forceinline__ float b2f(u16 u) {
  union { float f; u32 i; } c; c.i = ((u32)u) << 16; return c.f;
}
__device__ __forceinline__ u16 f2b(float f) {
  union { float f; u32 i; } c; c.f = f;
  u32 r = c.i + 0x7FFFu + ((c.i >> 16) & 1u);  // RNE
  return (u16)(r >> 16);
}

// ================= device bodies =================

// one W-tile pass (64-row GEMM): stage W -> sync -> MFMA -> store C
__device__ __forceinline__ void gemm_w(const u16* __restrict__ W, int ldw, u16* __restrict__ C,
                                       u16* lds, int tid, int row0, const bf16x8* a,
                                       int m16, int quad, int wv) {
#pragma unroll
  for (int it = 0; it < 8; ++it) {
    int idx = it * 256 + tid;
    int r = idx >> 4, c = (idx & 15) << 3;
    *(short8*)(&lds[r * SP + c]) = *(const short8*)(W + (size_t)r * ldw + c);
  }
  __syncthreads();
  const u16* brow = &lds[m16 * SP + quad * 8];
  floatx4 acc[8];
#pragma unroll
  for (int c = 0; c < 8; ++c) acc[c] = floatx4{0.f, 0.f, 0.f, 0.f};
#pragma unroll
  for (int kk = 0; kk < 4; ++kk) {
#pragma unroll
    for (int c = 0; c < 8; ++c) {
      bf16x8 bfr = *(const bf16x8*)(brow + c * 16 * SP + kk * 32);
      acc[c] = __builtin_amdgcn_mfma_f32_16x16x32_bf16(a[kk], bfr, acc[c], 0, 0, 0);
    }
  }
#pragma unroll
  for (int c = 0; c < 8; ++c) {
    int col = c * 16 + m16;
#pragma unroll
    for (int r = 0; r < 4; ++r) {
      int grow = row0 + wv * 16 + quad * 4 + r;
      if (grow < NN) C[(size_t)grow * 128 + col] = f2b(acc[c][r]);
    }
  }
}

// stage W2 (Wl cols 128..255, ldw 256) into LDS -- 512 threads, plain 16B copies
__device__ __forceinline__ void stageW2(const u16* __restrict__ W2, u16* Wlds, int tid) {
#pragma unroll
  for (int it = 0; it < 4; ++it) {
    int idx = it * 512 + tid;
    int r = idx >> 4, c = (idx & 15) << 3;
    *(short8*)(&Wlds[r * SP + c]) = *(const short8*)(W2 + (size_t)r * 256 + c);
  }
}

// gather phase: group g (16 lanes, g=tid>>4 in 0..31) softmax-aggregates node n's
// edges into Alds row g. Batched 8-deep h-row prefetch. INIT=1: start from Alds row.
template<int INIT>
__device__ __forceinline__ void gat_phase(int nb, int tid, const u16* __restrict__ h,
                                          const u32* __restrict__ srecs, const int* __restrict__ rp,
                                          const float* __restrict__ el, const float* __restrict__ er,
                                          u16* Alds) {
  int sub = tid & 15, g = tid >> 4;
  int n = nb * 32 + g;                    // NN = 3125*32, no tail
  int start = rp[n], end = rp[n + 1];
  float row[8];
  if (INIT) {
    short8 pv = *(const short8*)(&Alds[g * SP + sub * 8]);
#pragma unroll
    for (int t = 0; t < 8; ++t) row[t] = b2f((u16)pv[t]);
  } else {
#pragma unroll
    for (int t = 0; t < 8; ++t) row[t] = 0.f;
  }
  if (start < end) {
    float ern = er[n];
    float acc[8];
#pragma unroll
    for (int t = 0; t < 8; ++t) acc[t] = 0.f;
    float sl = 0.f;
    const u16* hsub = h + sub * 8;
    for (int base = start; base < end; base += 16) {
      int m = end - base; if (m > 16) m = 16;
      int srci = 0;
      if (sub < m) srci = (int)srecs[base + sub];
      short8 hv[8];
      int mm1 = (m > 8) ? 8 : m;
#pragma unroll
      for (int j = 0; j < 8; ++j) {
        if (j < mm1) {
          int sv = __shfl(srci, j, 16);
          hv[j] = *(const short8*)(hsub + (size_t)sv * 128);
        }
      }
      float w = 0.f;
      if (sub < m) {
        float l = el[srci] + ern;
        l = (l >= 0.f) ? l : 0.2f * l;
        w = __expf(l);
      }
      sl += w;
#pragma unroll
      for (int j = 0; j < 8; ++j) {
        if (j < mm1) {
          float x = __shfl(w, j, 16);
#pragma unroll
          for (int t = 0; t < 8; ++t) acc[t] += x * b2f((u16)hv[j][t]);
        }
      }
      if (m > 8) {
        short8 hv2[8];
        int mm2 = m - 8;
#pragma unroll
        for (int j = 0; j < 8; ++j) {
          if (j < mm2) {
            int sv = __shfl(srci, 8 + j, 16);
            hv2[j] = *(const short8*)(hsub + (size_t)sv * 128);
          }
        }
#pragma unroll
        for (int j = 0; j < 8; ++j) {
          if (j < mm2) {
            float x = __shfl(w, 8 + j, 16);
#pragma unroll
            for (int t = 0; t < 8; ++t) acc[t] += x * b2f((u16)hv2[j][t]);
          }
        }
      }
    }
    float s = sl;
#pragma unroll
    for (int off = 8; off > 0; off >>= 1) s += __shfl_xor(s, off, 16);
    float inv = 1.f / s;
#pragma unroll
    for (int t = 0; t < 8; ++t) row[t] += acc[t] * inv;
  }
  short8 rb;
#pragma unroll
  for (int t = 0; t < 8; ++t) rb[t] = (short)f2b(row[t]);
  *(short8*)(&Alds[g * SP + sub * 8]) = rb;
}

// F phase (512 threads, 32 rows): waves 0-3 rows 0-15, waves 4-7 rows 16-31.
// tile = relu(P + Alds @ W2.T + c). TO_GLOBAL: fp32 out; else bf16 -> Alds.
template<int TO_GLOBAL>
__device__ __forceinline__ void F_phase(int nb, int tid, const u16* __restrict__ P,
                                        const float* __restrict__ cvec,
                                        const u16* Wlds, u16* Alds, void* __restrict__ out) {
  const int half = tid >> 8;
  const int ltid = tid & 255;
  const int lane = ltid & 63, wv = ltid >> 6;
  const int m16 = lane & 15, quad = lane >> 4;
  const u16* arow = &Alds[(half * 16 + m16) * SP + quad * 8];
  bf16x8 a[4];
#pragma unroll
  for (int kk = 0; kk < 4; ++kk) a[kk] = *(const bf16x8*)(arow + kk * 32);
  if (!TO_GLOBAL) __syncthreads();      // all A reads landed before overwrite
  const u16* brow = &Wlds[m16 * SP + quad * 8];
  floatx4 acc2[2];
#pragma unroll
  for (int cc = 0; cc < 2; ++cc) acc2[cc] = floatx4{0.f, 0.f, 0.f, 0.f};
#pragma unroll
  for (int kk = 0; kk < 4; ++kk) {
#pragma unroll
    for (int cc = 0; cc < 2; ++cc) {
      int ct = wv * 2 + cc;
      bf16x8 bfr = *(const bf16x8*)(brow + ct * 16 * SP + kk * 32);
      acc2[cc] = __builtin_amdgcn_mfma_f32_16x16x32_bf16(a[kk], bfr, acc2[cc], 0, 0, 0);
    }
  }
#pragma unroll
  for (int cc = 0; cc < 2; ++cc) {
    int ct = wv * 2 + cc;
    int col = ct * 16 + m16;
    float cv = cvec[col];
#pragma unroll
    for (int r = 0; r < 4; ++r) {
      int nrow = half * 16 + quad * 4 + r;
      int node = nb * 32 + nrow;
      float v = acc2[cc][r] + b2f(P[(size_t)node * 128 + col]) + cv;
      v = fmaxf(v, 0.f);
      if (TO_GLOBAL) ((float*)out)[(size_t)node * 128 + col] = v;
      else           Alds[nrow * SP + col] = f2b(v);
    }
  }
  if (!TO_GLOBAL) __syncthreads();      // tile complete before next phase reads
}

// ================= kernels =================

// prep: proj (12500) | conv (128) | vec (7) | zero bcnt (3)
__global__ __launch_bounds__(256) void prep_k(const float* __restrict__ x_net, const float* __restrict__ x_cell,
                                              const float* __restrict__ Wp_net, const float* __restrict__ Wp_cell,
                                              u16* __restrict__ feat_net, u16* __restrict__ feat_cell,
                                              const float* __restrict__ Wl, const float* __restrict__ Wg0,
                                              const float* __restrict__ Wg1, const float* __restrict__ Wg2,
                                              u16* __restrict__ Wl_bf, u16* __restrict__ Wg_bf,
                                              const float* al0, const float* ar0, const float* al1,
                                              const float* ar1, const float* al2, const float* ar2,
                                              const float* bias, float* __restrict__ vecs,
                                              int* __restrict__ bcnt) {
  int bid = blockIdx.x, tid = threadIdx.x;
  if (bid < 2 * AB) {
    int y = bid >= AB;
    int bx = y ? bid - AB : bid;
    const float* x  = y ? x_cell : x_net;
    const float* Wp = y ? Wp_cell : Wp_net;
    u16* feat       = y ? feat_cell : feat_net;
    __shared__ float Ws[128 * 17];
    __shared__ float xs[16][17];
#pragma unroll
    for (int it = 0; it < 8; ++it) {
      int idx = it * 256 + tid;
      int j = idx >> 4, k = idx & 15;
      Ws[j * 17 + k] = Wp[idx];
    }
    int n0 = bx * 16;
    { int nn = tid >> 4, k = tid & 15;
      xs[nn][k] = x[(size_t)(n0 + nn) * 16 + k]; }
    __syncthreads();
    int j = tid & 127, g = tid >> 7;
    float acc[8];
#pragma unroll
    for (int r = 0; r < 8; ++r) acc[r] = 0.f;
#pragma unroll
    for (int k = 0; k < 16; ++k) {
      float w = Ws[j * 17 + k];
#pragma unroll
      for (int r = 0; r < 8; ++r) acc[r] += xs[g * 8 + r][k] * w;
    }
#pragma unroll
    for (int r = 0; r < 8; ++r)
      feat[(size_t)(n0 + g * 8 + r) * 128 + j] = f2b(acc[r]);
  } else if (bid < 2 * AB + 128) {
    int cid = bid - 2 * AB;
    int y = cid >> 5, bx = cid & 31;
    const float* src = (y == 0) ? Wl : (y == 1) ? Wg0 : (y == 2) ? Wg1 : Wg2;
    u16* dst = (y == 0) ? Wl_bf : Wg_bf + (size_t)(y - 1) * 16384;
    int n = (y == 0) ? 32768 : 16384;
    int i = (bx * 256 + tid) * 4;
    if (i >= n) return;
    float4 v = *(const float4*)(src + i);
    ushort4 p; p.x = f2b(v.x); p.y = f2b(v.y); p.z = f2b(v.z); p.w = f2b(v.w);
    *(ushort4*)(dst + i) = p;
  } else if (bid < 2 * AB + 135) {
    int a = bid - (2 * AB + 128);
    if (tid >= 128) return;
    int j = tid;
    float s = 0.f;
    if (a < 6) {
      const float* W = (a < 2) ? Wg0 : (a < 4) ? Wg1 : Wg2;
      const float* v = (a == 0) ? al0 : (a == 1) ? ar0 : (a == 2) ? al1 : (a == 3) ? ar1 : (a == 4) ? al2 : ar2;
      for (int i = 0; i < 128; ++i) s += W[i * 128 + j] * v[i];
    } else {
      for (int i = 0; i < 128; ++i) s += Wl[(size_t)j * 256 + 128 + i] * bias[i];
    }
    vecs[a * 128 + j] = s;
  } else {
    int r = bid - (2 * AB + 135);
    for (int i = tid; i < NB; i += 256) bcnt[(size_t)r * NB + i] = 0;
  }
}

// logbh: logits (782) | bhist (441)
__global__ __launch_bounds__(256) void logbh_k(const u16* __restrict__ feat_net, const u16* __restrict__ feat_cell,
                                               const float* __restrict__ vecs, float* __restrict__ outs,
                                               const int* __restrict__ dst0, const int* __restrict__ dst1,
                                               const int* __restrict__ dst2, int* __restrict__ bcnt) {
  __shared__ int sm[NB];
  int bid = blockIdx.x, tid = threadIdx.x;
  if (bid < 782) {
    float* vs = (float*)sm;
#pragma unroll
    for (int it = 0; it < 3; ++it) vs[it * 256 + tid] = vecs[it * 256 + tid];
    __syncthreads();
    int y = bid >= 391;
    int bx = y ? bid - 391 : bid;
    const u16* f = y ? feat_cell : feat_net;
    int n = bx * 256 + tid;
    if (n >= NN) return;
    const u16* row = f + (size_t)n * 128;
    if (y == 0) {
      float s1 = 0.f, s2 = 0.f, s4 = 0.f, s5 = 0.f;
#pragma unroll
      for (int k = 0; k < 128; k += 8) {
        short8 u = *(const short8*)(row + k);
#pragma unroll
        for (int t = 0; t < 8; ++t) {
          float fv = b2f((u16)u[t]);
          s1 += fv * vs[1 * 128 + k + t]; s2 += fv * vs[2 * 128 + k + t];
          s4 += fv * vs[4 * 128 + k + t]; s5 += fv * vs[5 * 128 + k + t];
        }
      }
      outs[(size_t)1 * NN + n] = s1; outs[(size_t)2 * NN + n] = s2;
      outs[(size_t)4 * NN + n] = s4; outs[(size_t)5 * NN + n] = s5;
    } else {
      float s0 = 0.f, s3 = 0.f;
#pragma unroll
      for (int k = 0; k < 128; k += 8) {
        short8 u = *(const short8*)(row + k);
#pragma unroll
        for (int t = 0; t < 8; ++t) {
          float fv = b2f((u16)u[t]);
          s0 += fv * vs[0 * 128 + k + t]; s3 += fv * vs[3 * 128 + k + t];
        }
      }
      outs[(size_t)0 * NN + n] = s0; outs[(size_t)3 * NN + n] = s3;
    }
  } else {
    int e = bid - 782;
    int r = e / NCH, bx = e % NCH;
    const int* dst = (r == 0) ? dst0 : (r == 1) ? dst1 : dst2;
    for (int i = tid; i < NB; i += 256) sm[i] = 0;
    __syncthreads();
    int e0 = bx * CHUNK;
    int cnt = NE - e0; if (cnt > CHUNK) cnt = CHUNK;
    for (int i = tid; i < cnt; i += 256) atomicAdd(&sm[((u32)dst[e0 + i]) >> 7], 1);
    __syncthreads();
    for (int b = tid; b < NB; b += 256) {
      int c = sm[b];
      if (c) atomicAdd(&bcnt[(size_t)r * NB + b], c);
    }
  }
}

// exclusive scan of NB counters per relation
__global__ __launch_bounds__(1024) void bscan_k(const int* __restrict__ bcnt, int* __restrict__ bptr,
                                                int* __restrict__ bcur) {
  int r = blockIdx.x, t = threadIdx.x;
  const int* c = bcnt + (size_t)r * NB;
  int* p = bptr + (size_t)r * (NB + 1);
  int* cur = bcur + (size_t)r * NB;
  int v = (t < NB) ? c[t] : 0;
  __shared__ int ss[1024];
  ss[t] = v; __syncthreads();
  for (int off = 1; off < 1024; off <<= 1) {
    int u = (t >= off) ? ss[t - off] : 0;
    __syncthreads();
    ss[t] += u;
    __syncthreads();
  }
  if (t < NB) { int e = ss[t] - v; p[t] = e; cur[t] = e; }
  if (t == 1023) p[NB] = ss[1023];
}

// block-local radix partition (coalesced run-writes)
__global__ __launch_bounds__(256) void bscatter_k(const int* __restrict__ src0, const int* __restrict__ dst0,
                                                  const int* __restrict__ src1, const int* __restrict__ dst1,
                                                  const int* __restrict__ src2, const int* __restrict__ dst2,
                                                  int* __restrict__ bcur, u32* __restrict__ recs) {
  int r = blockIdx.y;
  const int* src = (r == 0) ? src0 : (r == 1) ? src1 : src2;
  const int* dst = (r == 0) ? dst0 : (r == 1) ? dst1 : dst2;
  __shared__ int hist[NB];
  __shared__ int lstart[NB];
  __shared__ int lcur[NB];
  __shared__ int badj[NB];
  __shared__ u32 rbuf[CHUNK];
  __shared__ u16 kbuf[CHUNK];
  __shared__ int ss[256];
  int tid = threadIdx.x;
  int e0 = blockIdx.x * CHUNK;
  int cnt = NE - e0; if (cnt > CHUNK) cnt = CHUNK;

  for (int i = tid; i < NB; i += 256) hist[i] = 0;
  __syncthreads();
  for (int i = tid; i < cnt; i += 256) atomicAdd(&hist[((u32)dst[e0 + i]) >> 7], 1);
  __syncthreads();
  int loc[4]; int s = 0;
  int base4 = tid * 4;
#pragma unroll
  for (int j = 0; j < 4; ++j) {
    int idx = base4 + j;
    int v = (idx < NB) ? hist[idx] : 0;
    loc[j] = s; s += v;
  }
  ss[tid] = s; __syncthreads();
  for (int off = 1; off < 256; off <<= 1) {
    int u = (tid >= off) ? ss[tid - off] : 0;
    __syncthreads();
    ss[tid] += u;
    __syncthreads();
  }
  int ex = ss[tid] - s;
#pragma unroll
  for (int j = 0; j < 4; ++j) {
    int idx = base4 + j;
    if (idx < NB) { int e = ex + loc[j]; lstart[idx] = e; lcur[idx] = e; }
  }
  __syncthreads();
  for (int b = tid; b < NB; b += 256) {
    int c = hist[b];
    int g = 0;
    if (c) g = atomicAdd(&bcur[(size_t)r * NB + b], c);
    badj[b] = g - lstart[b];
  }
  __syncthreads();
  for (int i = tid; i < cnt; i += 256) {
    int dN = dst[e0 + i], sN = src[e0 + i];
    int b = ((u32)dN) >> 7;
    int pos = atomicAdd(&lcur[b], 1);
    rbuf[pos] = ((u32)(dN & 127) << 17) | (u32)sN;
    kbuf[pos] = (u16)b;
  }
  __syncthreads();
  u32* out = recs + (size_t)r * NE;
  for (int i = tid; i < cnt; i += 256) {
    int b = kbuf[i];
    out[badj[b] + i] = rbuf[i];
  }
}

// sortgemm: GEMM blocks first (long blocks early), then sort blocks
__global__ __launch_bounds__(256) void sortgemm_k(u32* __restrict__ recs, const int* __restrict__ bptr,
                                                  int* __restrict__ rowptr,
                                                  const u16* __restrict__ feat_net, const u16* __restrict__ feat_cell,
                                                  const u16* __restrict__ Wl_bf, const u16* __restrict__ Wg_bf,
                                                  u16* __restrict__ P_net, u16* __restrict__ P_cell,
                                                  u16* __restrict__ h0, u16* __restrict__ h1, u16* __restrict__ h2) {
  __shared__ u32 smem[128 * SP / 2];   // 34816 B, shared by both paths
  int bid = blockIdx.x, tid = threadIdx.x;
  if (bid < 2 * GB) {
    int ntype = bid >= GB;
    int blk = ntype ? bid - GB : bid;
    u16* lds = (u16*)smem;
    const u16* A = ntype ? feat_cell : feat_net;
    const int row0 = blk * 64;
    const int lane = tid & 63, wv = tid >> 6;
    const int m16 = lane & 15, quad = lane >> 4;
    int arow = row0 + wv * 16 + m16;
    if (arow >= NN) arow = NN - 1;
    const u16* Ab = A + (size_t)arow * 128 + quad * 8;
    bf16x8 a[4];
#pragma unroll
    for (int kk = 0; kk < 4; ++kk) a[kk] = *(const bf16x8*)(Ab + kk * 32);
    if (!ntype) {
      gemm_w(Wl_bf,          256, P_net, lds, tid, row0, a, m16, quad, wv);
      __syncthreads();
      gemm_w(Wg_bf + 16384,  128, h1,    lds, tid, row0, a, m16, quad, wv);
      __syncthreads();
      gemm_w(Wg_bf + 32768,  128, h2,    lds, tid, row0, a, m16, quad, wv);
    } else {
      gemm_w(Wl_bf,          256, P_cell, lds, tid, row0, a, m16, quad, wv);
      __syncthreads();
      gemm_w(Wg_bf,          128, h0,     lds, tid, row0, a, m16, quad, wv);
    }
  } else {
    int sb = bid - 2 * GB;
    int r = sb / NB, b = sb % NB;
    const int* p = bptr + (size_t)r * (NB + 1);
    u32* rec = recs + (size_t)r * NE;
    int* rp = rowptr + (size_t)r * (NN + 1);
    int base = p[b], end = p[b + 1];
    int cnt = end - base; if (cnt > BCAP) cnt = BCAP;
    u32* rs = smem;
    int* hist = (int*)(smem + BCAP);
    int* excl = hist + 128;
    int* cur  = excl + 128;
    for (int i = tid; i < cnt; i += 256) rs[i] = rec[base + i];
    if (tid < 128) hist[tid] = 0;
    __syncthreads();
    for (int i = tid; i < cnt; i += 256) atomicAdd(&hist[rs[i] >> 17], 1);
    __syncthreads();
    if (tid < 128) cur[tid] = hist[tid];
    __syncthreads();
    for (int off = 1; off < 128; off <<= 1) {
      int v = 0;
      if (tid < 128 && tid >= off) v = cur[tid - off];
      __syncthreads();
      if (tid < 128) cur[tid] += v;
      __syncthreads();
    }
    if (tid < 128) {
      int e = cur[tid] - hist[tid];
      excl[tid] = e;
      int node = b * 128 + tid;
      if (node < NN) rp[node] = base + e;
    }
    if (b == NB - 1 && tid == 0) rp[NN] = p[NB];
    if (tid < 128) cur[tid] = excl[tid];
    __syncthreads();
    for (int i = tid; i < cnt; i += 256) {
      u32 v = rs[i];
      int pos = atomicAdd(&cur[v >> 17], 1);
      rec[base + pos] = v & 0x1FFFFu;
    }
  }
}

// tail: whole post-GEMM pipeline, one 512-thread block per 32 nodes.
// net (bid<ABT): A=gat0 -> F -> F -> A+=gat2 -> F(final fp32)
// cell:          A=relu(P+c) -> A+=gat1 -> F -> F(final fp32)
__global__ __launch_bounds__(512) void tail_k(const u16* __restrict__ h0, const u16* __restrict__ h1,
                                              const u16* __restrict__ h2,
                                              const u32* __restrict__ recs, const int* __restrict__ rowptr,
                                              const float* __restrict__ logit,
                                              const u16* __restrict__ P_net, const u16* __restrict__ P_cell,
                                              const u16* __restrict__ W2, const float* __restrict__ cvec,
                                              float* __restrict__ out_net, float* __restrict__ out_cell) {
  __shared__ u16 Wlds[128 * SP];
  __shared__ u16 Alds[32 * SP];
  int bid = blockIdx.x, tid = threadIdx.x;
  stageW2(W2, Wlds, tid);
  if (bid < ABT) {
    int nb = bid;  // net tile
    gat_phase<0>(nb, tid, h0, recs, rowptr, logit, logit + (size_t)NN, Alds);
    __syncthreads();                                   // covers W2 staging too
    F_phase<0>(nb, tid, P_net, cvec, Wlds, Alds, nullptr);   // buf_net0 -> Alds
    F_phase<0>(nb, tid, P_net, cvec, Wlds, Alds, nullptr);   // buf_net1 -> Alds
    gat_phase<1>(nb, tid, h2, recs + (size_t)2 * NE, rowptr + 2 * (NN + 1),
                 logit + (size_t)4 * NN, logit + (size_t)5 * NN, Alds);
    __syncthreads();
    F_phase<1>(nb, tid, P_net, cvec, Wlds, Alds, (void*)out_net);   // final
  } else {
    int nb = bid - ABT;  // cell tile
    {  // elem init: relu(P_cell + cvec) -> Alds (same-thread slot as gat)
      int sub = tid & 15, g = tid >> 4;
      int n = nb * 32 + g;
      short8 pv = *(const short8*)(P_cell + (size_t)n * 128 + sub * 8);
      short8 rb;
#pragma unroll
      for (int t = 0; t < 8; ++t)
        rb[t] = (short)f2b(fmaxf(b2f((u16)pv[t]) + cvec[sub * 8 + t], 0.f));
      *(short8*)(&Alds[g * SP + sub * 8]) = rb;
    }
    // no barrier needed: gat_phase<1> reads the slot this same thread just wrote
    gat_phase<1>(nb, tid, h1, recs + (size_t)NE, rowptr + (NN + 1),
                 logit + (size_t)2 * NN, logit + (size_t)3 * NN, Alds);
    __syncthreads();                                   // covers W2 staging too
    F_phase<0>(nb, tid, P_cell, cvec, Wlds, Alds, nullptr);  // buf_cell1 -> Alds
    F_phase<1>(nb, tid, P_cell, cvec, Wlds, Alds, (void*)out_cell);  // final
  }
}

extern "C" void kernel_launch(void* const* d_in, const int* in_sizes, int n_in,
                              void* d_out, int out_size, void* d_ws, size_t ws_size,
                              hipStream_t stream) {
  const float* x_net   = (const float*)d_in[0];
  const float* x_cell  = (const float*)d_in[1];
  const float* Wp_net  = (const float*)d_in[2];
  const float* Wp_cell = (const float*)d_in[3];
  const float* Wg[3] = {(const float*)d_in[4], (const float*)d_in[7], (const float*)d_in[10]};
  const float* al[3] = {(const float*)d_in[5], (const float*)d_in[8], (const float*)d_in[11]};
  const float* ar[3] = {(const float*)d_in[6], (const float*)d_in[9], (const float*)d_in[12]};
  const float* Wl    = (const float*)d_in[13];
  const float* bias  = (const float*)d_in[14];
  const int* src[3] = {(const int*)d_in[15], (const int*)d_in[17], (const int*)d_in[19]};
  const int* dst[3] = {(const int*)d_in[16], (const int*)d_in[18], (const int*)d_in[20]};

  char* ws = (char*)d_ws;
  size_t off = 0;
  auto alloc = [&](size_t b) { void* p = ws + off; off = (off + b + 255) & ~(size_t)255; return p; };
  u16*  feat_net  = (u16*)alloc((size_t)NN * 128 * 2);
  u16*  feat_cell = (u16*)alloc((size_t)NN * 128 * 2);
  u16*  hbuf0     = (u16*)alloc((size_t)NN * 128 * 2);
  u16*  hbuf1     = (u16*)alloc((size_t)NN * 128 * 2);
  u16*  hbuf2     = (u16*)alloc((size_t)NN * 128 * 2);
  u16*  P_net     = (u16*)alloc((size_t)NN * 128 * 2);
  u16*  P_cell    = (u16*)alloc((size_t)NN * 128 * 2);
  float* vecs     = (float*)alloc(7 * 128 * 4);
  float* logit    = (float*)alloc((size_t)6 * NN * 4);
  u16*   Wl_bf    = (u16*)alloc((size_t)128 * 256 * 2);
  u16*   Wg_bf    = (u16*)alloc((size_t)3 * 128 * 128 * 2);
  int*   bcnt     = (int*)alloc((size_t)3 * NB * 4);
  int*   bcur     = (int*)alloc((size_t)3 * NB * 4);
  int*   bptr     = (int*)alloc((size_t)3 * (NB + 1) * 4);
  int*   rowptr   = (int*)alloc((size_t)3 * (NN + 1) * 4);
  u32*   recs     = (u32*)alloc((size_t)3 * NE * 4);

  float* out_f = (float*)d_out;  // [2,N,D] fp32: net then cell
  const u16* W2 = Wl_bf + 128;   // Wl cols 128..255 (ldw 256)
  const float* cvec = vecs + 6 * 128;

  // 1. prep: proj | conv | vec | zero bcnt
  prep_k<<<2 * AB + 138, 256, 0, stream>>>(x_net, x_cell, Wp_net, Wp_cell, feat_net, feat_cell,
                                           Wl, Wg[0], Wg[1], Wg[2], Wl_bf, Wg_bf,
                                           al[0], ar[0], al[1], ar[1], al[2], ar[2], bias, vecs, bcnt);
  // 2. logits | bhist
  logbh_k<<<782 + 3 * NCH, 256, 0, stream>>>(feat_net, feat_cell, vecs, logit,
                                             dst[0], dst[1], dst[2], bcnt);
  // 3. scan
  bscan_k<<<3, 1024, 0, stream>>>(bcnt, bptr, bcur);
  // 4. scatter
  bscatter_k<<<dim3(NCH, 3), 256, 0, stream>>>(src[0], dst[0], src[1], dst[1], src[2], dst[2],
                                               bcur, recs);
  // 5. GEMMs | sort
  sortgemm_k<<<2 * GB + 3 * NB, 256, 0, stream>>>(recs, bptr, rowptr, feat_net, feat_cell,
                                                  Wl_bf, Wg_bf, P_net, P_cell, hbuf0, hbuf1, hbuf2);
  // 6. tail: full node-local pipeline (512 threads / 32 nodes per block)
  tail_k<<<2 * ABT, 512, 0, stream>>>(hbuf0, hbuf1, hbuf2, recs, rowptr, logit,
                                      P_net, P_cell, W2, cvec,
                                      out_f, out_f + (size_t)NN * 128);
}

// Round 11
// 423.912 us; speedup vs baseline: 2.0740x; 1.0082x over previous
//
#include <hip/hip_runtime.h>
#include <hip/hip_bf16.h>
#include <stdint.h>

// ParaGraph: 2 node types (net/cell, N=100000), 3 relations (E=600000 each), D=128.
// I/O FP32. All intermediates bf16. W pre-converted bf16. 6 dispatches:
// prep | logbh | bscan | bscatter | sortgemm | tail.
// sortgemm's sort path also PRECOMPUTES normalized softmax edge weights (walpha):
// el-gather + exp + per-node denominator in LDS, overlapped with GEMM blocks.
// tail_k gather is then pure loads+fma: no shuffles, no exp, no reduction.
#define NN 100000
#define NE 600000
#define SP 136        // LDS row stride (ushorts): 128 + 8 pad
#define NB 782        // ceil(NN/128) dst buckets of 128 nodes
#define BCAP 1600     // LDS rec capacity per bucket (mean 767, sd ~28)
#define CHUNK 4096    // edges per partition block
#define NCH 147       // ceil(NE/CHUNK)
#define GB 1563       // ceil(NN/64) GEMM row-blocks
#define AB 6250       // NN/16 node-tile blocks (exact)

typedef unsigned short u16;
typedef unsigned int u32;
typedef __attribute__((ext_vector_type(8))) short short8;
typedef __attribute__((ext_vector_type(8))) __bf16 bf16x8;
typedef __attribute__((ext_vector_type(4))) float floatx4;

__device__ __forceinline__ float b2f(u16 u) {
  union { float f; u32 i; } c; c.i = ((u32)u) << 16; return c.f;
}
__device__ __forceinline__ u16 f2b(float f) {
  union { float f; u32 i; } c; c.f = f;
  u32 r = c.i + 0x7FFFu + ((c.i >> 16) & 1u);  // RNE
  return (u16)(r >> 16);
}

// ================= device bodies =================

// one W-tile pass (64-row GEMM): stage W -> sync -> MFMA -> store C
__device__ __forceinline__ void gemm_w(const u16* __restrict__ W, int ldw, u16* __restrict__ C,
                                       u16* lds, int tid, int row0, const bf16x8* a,
                                       int m16, int quad, int wv) {
#pragma unroll
  for (int it = 0; it < 8; ++it) {
    int idx = it * 256 + tid;
    int r = idx >> 4, c = (idx & 15) << 3;
    *(short8*)(&lds[r * SP + c]) = *(const short8*)(W + (size_t)r * ldw + c);
  }
  __syncthreads();
  const u16* brow = &lds[m16 * SP + quad * 8];
  floatx4 acc[8];
#pragma unroll
  for (int c = 0; c < 8; ++c) acc[c] = floatx4{0.f, 0.f, 0.f, 0.f};
#pragma unroll
  for (int kk = 0; kk < 4; ++kk) {
#pragma unroll
    for (int c = 0; c < 8; ++c) {
      bf16x8 bfr = *(const bf16x8*)(brow + c * 16 * SP + kk * 32);
      acc[c] = __builtin_amdgcn_mfma_f32_16x16x32_bf16(a[kk], bfr, acc[c], 0, 0, 0);
    }
  }
#pragma unroll
  for (int c = 0; c < 8; ++c) {
    int col = c * 16 + m16;
#pragma unroll
    for (int r = 0; r < 4; ++r) {
      int grow = row0 + wv * 16 + quad * 4 + r;
      if (grow < NN) C[(size_t)grow * 128 + col] = f2b(acc[c][r]);
    }
  }
}

// stage W2 (Wl cols 128..255, ldw 256) into LDS -- plain 16B copies (256 threads)
__device__ __forceinline__ void stageW2(const u16* __restrict__ W2, u16* Wlds, int tid) {
#pragma unroll
  for (int it = 0; it < 8; ++it) {
    int idx = it * 256 + tid;
    int r = idx >> 4, c = (idx & 15) << 3;
    *(short8*)(&Wlds[r * SP + c]) = *(const short8*)(W2 + (size_t)r * 256 + c);
  }
}

// gather phase: group g (16 lanes) accumulates node n's pre-normalized edges into
// Alds row g. Per edge: 2 uniform 4B loads + one 16B h-row load + fma. No shuffles.
template<int INIT>
__device__ __forceinline__ void gat_phase(int nb, int tid, const u16* __restrict__ h,
                                          const u32* __restrict__ srecs,
                                          const float* __restrict__ walpha,
                                          const int* __restrict__ rp, u16* Alds) {
  int sub = tid & 15, g = tid >> 4;
  int n = nb * 16 + g;                    // NN = 6250*16, no tail
  int start = rp[n], end = rp[n + 1];
  float row[8];
  if (INIT) {
    short8 pv = *(const short8*)(&Alds[g * SP + sub * 8]);
#pragma unroll
    for (int t = 0; t < 8; ++t) row[t] = b2f((u16)pv[t]);
  } else {
#pragma unroll
    for (int t = 0; t < 8; ++t) row[t] = 0.f;
  }
  if (start < end) {
    float acc[8];
#pragma unroll
    for (int t = 0; t < 8; ++t) acc[t] = 0.f;
    const u16* hsub = h + sub * 8;
    int e = start;
    for (; e + 4 <= end; e += 4) {
      int s0 = (int)srecs[e],     s1 = (int)srecs[e + 1];
      int s2 = (int)srecs[e + 2], s3 = (int)srecs[e + 3];
      float x0 = walpha[e],     x1 = walpha[e + 1];
      float x2 = walpha[e + 2], x3 = walpha[e + 3];
      short8 h0 = *(const short8*)(hsub + (size_t)s0 * 128);
      short8 h1 = *(const short8*)(hsub + (size_t)s1 * 128);
      short8 h2 = *(const short8*)(hsub + (size_t)s2 * 128);
      short8 h3 = *(const short8*)(hsub + (size_t)s3 * 128);
#pragma unroll
      for (int t = 0; t < 8; ++t) {
        acc[t] += x0 * b2f((u16)h0[t]) + x1 * b2f((u16)h1[t])
                + x2 * b2f((u16)h2[t]) + x3 * b2f((u16)h3[t]);
      }
    }
    for (; e < end; ++e) {
      int sv = (int)srecs[e];
      float x = walpha[e];
      short8 hv = *(const short8*)(hsub + (size_t)sv * 128);
#pragma unroll
      for (int t = 0; t < 8; ++t) acc[t] += x * b2f((u16)hv[t]);
    }
#pragma unroll
    for (int t = 0; t < 8; ++t) row[t] += acc[t];
  }
  short8 rb;
#pragma unroll
  for (int t = 0; t < 8; ++t) rb[t] = (short)f2b(row[t]);
  *(short8*)(&Alds[g * SP + sub * 8]) = rb;
}

// F phase (256 threads, 16 rows): tile = relu(P + Alds @ W2.T + c).
// TO_GLOBAL: fp32 out; else bf16 -> Alds.
template<int TO_GLOBAL>
__device__ __forceinline__ void F_phase(int nb, int tid, const u16* __restrict__ P,
                                        const float* __restrict__ cvec,
                                        const u16* Wlds, u16* Alds, void* __restrict__ out) {
  const int lane = tid & 63, wv = tid >> 6;
  const int m16 = lane & 15, quad = lane >> 4;
  const u16* arow = &Alds[m16 * SP + quad * 8];
  bf16x8 a[4];
#pragma unroll
  for (int kk = 0; kk < 4; ++kk) a[kk] = *(const bf16x8*)(arow + kk * 32);
  if (!TO_GLOBAL) __syncthreads();      // all A reads landed before overwrite
  const u16* brow = &Wlds[m16 * SP + quad * 8];
  floatx4 acc2[2];
#pragma unroll
  for (int cc = 0; cc < 2; ++cc) acc2[cc] = floatx4{0.f, 0.f, 0.f, 0.f};
#pragma unroll
  for (int kk = 0; kk < 4; ++kk) {
#pragma unroll
    for (int cc = 0; cc < 2; ++cc) {
      int ct = wv * 2 + cc;
      bf16x8 bfr = *(const bf16x8*)(brow + ct * 16 * SP + kk * 32);
      acc2[cc] = __builtin_amdgcn_mfma_f32_16x16x32_bf16(a[kk], bfr, acc2[cc], 0, 0, 0);
    }
  }
#pragma unroll
  for (int cc = 0; cc < 2; ++cc) {
    int ct = wv * 2 + cc;
    int col = ct * 16 + m16;
    float cv = cvec[col];
#pragma unroll
    for (int r = 0; r < 4; ++r) {
      int nrow = quad * 4 + r;
      int node = nb * 16 + nrow;
      float v = acc2[cc][r] + b2f(P[(size_t)node * 128 + col]) + cv;
      v = fmaxf(v, 0.f);
      if (TO_GLOBAL) ((float*)out)[(size_t)node * 128 + col] = v;
      else           Alds[nrow * SP + col] = f2b(v);
    }
  }
  if (!TO_GLOBAL) __syncthreads();      // tile complete before next phase reads
}

// ================= kernels =================

// prep: proj (12500) | conv (128) | vec (7) | zero bcnt (3)
__global__ __launch_bounds__(256) void prep_k(const float* __restrict__ x_net, const float* __restrict__ x_cell,
                                              const float* __restrict__ Wp_net, const float* __restrict__ Wp_cell,
                                              u16* __restrict__ feat_net, u16* __restrict__ feat_cell,
                                              const float* __restrict__ Wl, const float* __restrict__ Wg0,
                                              const float* __restrict__ Wg1, const float* __restrict__ Wg2,
                                              u16* __restrict__ Wl_bf, u16* __restrict__ Wg_bf,
                                              const float* al0, const float* ar0, const float* al1,
                                              const float* ar1, const float* al2, const float* ar2,
                                              const float* bias, float* __restrict__ vecs,
                                              int* __restrict__ bcnt) {
  int bid = blockIdx.x, tid = threadIdx.x;
  if (bid < 2 * AB) {
    int y = bid >= AB;
    int bx = y ? bid - AB : bid;
    const float* x  = y ? x_cell : x_net;
    const float* Wp = y ? Wp_cell : Wp_net;
    u16* feat       = y ? feat_cell : feat_net;
    __shared__ float Ws[128 * 17];
    __shared__ float xs[16][17];
#pragma unroll
    for (int it = 0; it < 8; ++it) {
      int idx = it * 256 + tid;
      int j = idx >> 4, k = idx & 15;
      Ws[j * 17 + k] = Wp[idx];
    }
    int n0 = bx * 16;
    { int nn = tid >> 4, k = tid & 15;
      xs[nn][k] = x[(size_t)(n0 + nn) * 16 + k]; }
    __syncthreads();
    int j = tid & 127, g = tid >> 7;
    float acc[8];
#pragma unroll
    for (int r = 0; r < 8; ++r) acc[r] = 0.f;
#pragma unroll
    for (int k = 0; k < 16; ++k) {
      float w = Ws[j * 17 + k];
#pragma unroll
      for (int r = 0; r < 8; ++r) acc[r] += xs[g * 8 + r][k] * w;
    }
#pragma unroll
    for (int r = 0; r < 8; ++r)
      feat[(size_t)(n0 + g * 8 + r) * 128 + j] = f2b(acc[r]);
  } else if (bid < 2 * AB + 128) {
    int cid = bid - 2 * AB;
    int y = cid >> 5, bx = cid & 31;
    const float* src = (y == 0) ? Wl : (y == 1) ? Wg0 : (y == 2) ? Wg1 : Wg2;
    u16* dst = (y == 0) ? Wl_bf : Wg_bf + (size_t)(y - 1) * 16384;
    int n = (y == 0) ? 32768 : 16384;
    int i = (bx * 256 + tid) * 4;
    if (i >= n) return;
    float4 v = *(const float4*)(src + i);
    ushort4 p; p.x = f2b(v.x); p.y = f2b(v.y); p.z = f2b(v.z); p.w = f2b(v.w);
    *(ushort4*)(dst + i) = p;
  } else if (bid < 2 * AB + 135) {
    int a = bid - (2 * AB + 128);
    if (tid >= 128) return;
    int j = tid;
    float s = 0.f;
    if (a < 6) {
      const float* W = (a < 2) ? Wg0 : (a < 4) ? Wg1 : Wg2;
      const float* v = (a == 0) ? al0 : (a == 1) ? ar0 : (a == 2) ? al1 : (a == 3) ? ar1 : (a == 4) ? al2 : ar2;
      for (int i = 0; i < 128; ++i) s += W[i * 128 + j] * v[i];
    } else {
      for (int i = 0; i < 128; ++i) s += Wl[(size_t)j * 256 + 128 + i] * bias[i];
    }
    vecs[a * 128 + j] = s;
  } else {
    int r = bid - (2 * AB + 135);
    for (int i = tid; i < NB; i += 256) bcnt[(size_t)r * NB + i] = 0;
  }
}

// logbh: logits (782) | bhist (441)
__global__ __launch_bounds__(256) void logbh_k(const u16* __restrict__ feat_net, const u16* __restrict__ feat_cell,
                                               const float* __restrict__ vecs, float* __restrict__ outs,
                                               const int* __restrict__ dst0, const int* __restrict__ dst1,
                                               const int* __restrict__ dst2, int* __restrict__ bcnt) {
  __shared__ int sm[NB];
  int bid = blockIdx.x, tid = threadIdx.x;
  if (bid < 782) {
    float* vs = (float*)sm;
#pragma unroll
    for (int it = 0; it < 3; ++it) vs[it * 256 + tid] = vecs[it * 256 + tid];
    __syncthreads();
    int y = bid >= 391;
    int bx = y ? bid - 391 : bid;
    const u16* f = y ? feat_cell : feat_net;
    int n = bx * 256 + tid;
    if (n >= NN) return;
    const u16* row = f + (size_t)n * 128;
    if (y == 0) {
      float s1 = 0.f, s2 = 0.f, s4 = 0.f, s5 = 0.f;
#pragma unroll
      for (int k = 0; k < 128; k += 8) {
        short8 u = *(const short8*)(row + k);
#pragma unroll
        for (int t = 0; t < 8; ++t) {
          float fv = b2f((u16)u[t]);
          s1 += fv * vs[1 * 128 + k + t]; s2 += fv * vs[2 * 128 + k + t];
          s4 += fv * vs[4 * 128 + k + t]; s5 += fv * vs[5 * 128 + k + t];
        }
      }
      outs[(size_t)1 * NN + n] = s1; outs[(size_t)2 * NN + n] = s2;
      outs[(size_t)4 * NN + n] = s4; outs[(size_t)5 * NN + n] = s5;
    } else {
      float s0 = 0.f, s3 = 0.f;
#pragma unroll
      for (int k = 0; k < 128; k += 8) {
        short8 u = *(const short8*)(row + k);
#pragma unroll
        for (int t = 0; t < 8; ++t) {
          float fv = b2f((u16)u[t]);
          s0 += fv * vs[0 * 128 + k + t]; s3 += fv * vs[3 * 128 + k + t];
        }
      }
      outs[(size_t)0 * NN + n] = s0; outs[(size_t)3 * NN + n] = s3;
    }
  } else {
    int e = bid - 782;
    int r = e / NCH, bx = e % NCH;
    const int* dst = (r == 0) ? dst0 : (r == 1) ? dst1 : dst2;
    for (int i = tid; i < NB; i += 256) sm[i] = 0;
    __syncthreads();
    int e0 = bx * CHUNK;
    int cnt = NE - e0; if (cnt > CHUNK) cnt = CHUNK;
    for (int i = tid; i < cnt; i += 256) atomicAdd(&sm[((u32)dst[e0 + i]) >> 7], 1);
    __syncthreads();
    for (int b = tid; b < NB; b += 256) {
      int c = sm[b];
      if (c) atomicAdd(&bcnt[(size_t)r * NB + b], c);
    }
  }
}

// exclusive scan of NB counters per relation
__global__ __launch_bounds__(1024) void bscan_k(const int* __restrict__ bcnt, int* __restrict__ bptr,
                                                int* __restrict__ bcur) {
  int r = blockIdx.x, t = threadIdx.x;
  const int* c = bcnt + (size_t)r * NB;
  int* p = bptr + (size_t)r * (NB + 1);
  int* cur = bcur + (size_t)r * NB;
  int v = (t < NB) ? c[t] : 0;
  __shared__ int ss[1024];
  ss[t] = v; __syncthreads();
  for (int off = 1; off < 1024; off <<= 1) {
    int u = (t >= off) ? ss[t - off] : 0;
    __syncthreads();
    ss[t] += u;
    __syncthreads();
  }
  if (t < NB) { int e = ss[t] - v; p[t] = e; cur[t] = e; }
  if (t == 1023) p[NB] = ss[1023];
}

// block-local radix partition (coalesced run-writes)
__global__ __launch_bounds__(256) void bscatter_k(const int* __restrict__ src0, const int* __restrict__ dst0,
                                                  const int* __restrict__ src1, const int* __restrict__ dst1,
                                                  const int* __restrict__ src2, const int* __restrict__ dst2,
                                                  int* __restrict__ bcur, u32* __restrict__ recs) {
  int r = blockIdx.y;
  const int* src = (r == 0) ? src0 : (r == 1) ? src1 : src2;
  const int* dst = (r == 0) ? dst0 : (r == 1) ? dst1 : dst2;
  __shared__ int hist[NB];
  __shared__ int lstart[NB];
  __shared__ int lcur[NB];
  __shared__ int badj[NB];
  __shared__ u32 rbuf[CHUNK];
  __shared__ u16 kbuf[CHUNK];
  __shared__ int ss[256];
  int tid = threadIdx.x;
  int e0 = blockIdx.x * CHUNK;
  int cnt = NE - e0; if (cnt > CHUNK) cnt = CHUNK;

  for (int i = tid; i < NB; i += 256) hist[i] = 0;
  __syncthreads();
  for (int i = tid; i < cnt; i += 256) atomicAdd(&hist[((u32)dst[e0 + i]) >> 7], 1);
  __syncthreads();
  int loc[4]; int s = 0;
  int base4 = tid * 4;
#pragma unroll
  for (int j = 0; j < 4; ++j) {
    int idx = base4 + j;
    int v = (idx < NB) ? hist[idx] : 0;
    loc[j] = s; s += v;
  }
  ss[tid] = s; __syncthreads();
  for (int off = 1; off < 256; off <<= 1) {
    int u = (tid >= off) ? ss[tid - off] : 0;
    __syncthreads();
    ss[tid] += u;
    __syncthreads();
  }
  int ex = ss[tid] - s;
#pragma unroll
  for (int j = 0; j < 4; ++j) {
    int idx = base4 + j;
    if (idx < NB) { int e = ex + loc[j]; lstart[idx] = e; lcur[idx] = e; }
  }
  __syncthreads();
  for (int b = tid; b < NB; b += 256) {
    int c = hist[b];
    int g = 0;
    if (c) g = atomicAdd(&bcur[(size_t)r * NB + b], c);
    badj[b] = g - lstart[b];
  }
  __syncthreads();
  for (int i = tid; i < cnt; i += 256) {
    int dN = dst[e0 + i], sN = src[e0 + i];
    int b = ((u32)dN) >> 7;
    int pos = atomicAdd(&lcur[b], 1);
    rbuf[pos] = ((u32)(dN & 127) << 17) | (u32)sN;
    kbuf[pos] = (u16)b;
  }
  __syncthreads();
  u32* out = recs + (size_t)r * NE;
  for (int i = tid; i < cnt; i += 256) {
    int b = kbuf[i];
    out[badj[b] + i] = rbuf[i];
  }
}

// sortgemm: GEMM blocks first (long blocks early), then sort blocks.
// Sort path additionally computes normalized softmax edge weights walpha[e]
// (el gather + exp + per-node LDS-atomic denominator), aligned with sorted recs.
__global__ __launch_bounds__(256) void sortgemm_k(u32* __restrict__ recs, const int* __restrict__ bptr,
                                                  int* __restrict__ rowptr,
                                                  const u16* __restrict__ feat_net, const u16* __restrict__ feat_cell,
                                                  const u16* __restrict__ Wl_bf, const u16* __restrict__ Wg_bf,
                                                  u16* __restrict__ P_net, u16* __restrict__ P_cell,
                                                  u16* __restrict__ h0, u16* __restrict__ h1, u16* __restrict__ h2,
                                                  const float* __restrict__ logit, float* __restrict__ walpha) {
  __shared__ u32 smem[128 * SP / 2];   // 34816 B, shared by both paths
  int bid = blockIdx.x, tid = threadIdx.x;
  if (bid < 2 * GB) {
    int ntype = bid >= GB;
    int blk = ntype ? bid - GB : bid;
    u16* lds = (u16*)smem;
    const u16* A = ntype ? feat_cell : feat_net;
    const int row0 = blk * 64;
    const int lane = tid & 63, wv = tid >> 6;
    const int m16 = lane & 15, quad = lane >> 4;
    int arow = row0 + wv * 16 + m16;
    if (arow >= NN) arow = NN - 1;
    const u16* Ab = A + (size_t)arow * 128 + quad * 8;
    bf16x8 a[4];
#pragma unroll
    for (int kk = 0; kk < 4; ++kk) a[kk] = *(const bf16x8*)(Ab + kk * 32);
    if (!ntype) {
      gemm_w(Wl_bf,          256, P_net, lds, tid, row0, a, m16, quad, wv);
      __syncthreads();
      gemm_w(Wg_bf + 16384,  128, h1,    lds, tid, row0, a, m16, quad, wv);
      __syncthreads();
      gemm_w(Wg_bf + 32768,  128, h2,    lds, tid, row0, a, m16, quad, wv);
    } else {
      gemm_w(Wl_bf,          256, P_cell, lds, tid, row0, a, m16, quad, wv);
      __syncthreads();
      gemm_w(Wg_bf,          128, h0,     lds, tid, row0, a, m16, quad, wv);
    }
  } else {
    int sb = bid - 2 * GB;
    int r = sb / NB, b = sb % NB;
    const int* p = bptr + (size_t)r * (NB + 1);
    u32* rec = recs + (size_t)r * NE;
    float* wal = walpha + (size_t)r * NE;
    int* rp = rowptr + (size_t)r * (NN + 1);
    const float* el = logit + (size_t)(2 * r) * NN;
    const float* er = logit + (size_t)(2 * r + 1) * NN;
    int base = p[b], end = p[b + 1];
    int cnt = end - base; if (cnt > BCAP) cnt = BCAP;
    u32* rs = smem;                              // [BCAP] u32
    float* xs = (float*)(smem + BCAP);           // [BCAP] f32
    int* hist = (int*)(smem + 2 * BCAP);         // [128]
    int* excl = hist + 128;                      // [128]
    int* cur  = excl + 128;                      // [128]
    float* den = (float*)(cur + 128);            // [128] sum -> inverse
    float* ers = den + 128;                      // [128] er cache
    for (int i = tid; i < cnt; i += 256) rs[i] = rec[base + i];
    if (tid < 128) {
      hist[tid] = 0;
      den[tid] = 0.f;
      int node = b * 128 + tid;
      ers[tid] = (node < NN) ? er[node] : 0.f;
    }
    __syncthreads();
    // count + edge-weight + denominator
    for (int i = tid; i < cnt; i += 256) {
      u32 v = rs[i];
      int d = v >> 17;
      float l = el[v & 0x1FFFFu] + ers[d];
      l = (l >= 0.f) ? l : 0.2f * l;
      float x = __expf(l);
      xs[i] = x;
      atomicAdd(&den[d], x);
      atomicAdd(&hist[d], 1);
    }
    __syncthreads();
    if (tid < 128) cur[tid] = hist[tid];
    __syncthreads();
    for (int off = 1; off < 128; off <<= 1) {
      int v = 0;
      if (tid < 128 && tid >= off) v = cur[tid - off];
      __syncthreads();
      if (tid < 128) cur[tid] += v;
      __syncthreads();
    }
    if (tid < 128) {
      int e = cur[tid] - hist[tid];
      excl[tid] = e;
      int node = b * 128 + tid;
      if (node < NN) rp[node] = base + e;
      float dd = den[tid];
      den[tid] = (dd > 0.f) ? 1.f / dd : 0.f;    // -> inverse
    }
    if (b == NB - 1 && tid == 0) rp[NN] = p[NB];
    if (tid < 128) cur[tid] = excl[tid];
    __syncthreads();
    for (int i = tid; i < cnt; i += 256) {
      u32 v = rs[i];
      int d = v >> 17;
      int pos = atomicAdd(&cur[d], 1);
      rec[base + pos] = v & 0x1FFFFu;            // src only, node-sorted
      wal[base + pos] = xs[i] * den[d];          // normalized alpha
    }
  }
}

// tail: whole post-GEMM pipeline, one 256-thread block per 16 nodes.
// net (bid<AB):  A=gat0 -> F -> F -> A+=gat2 -> F(final fp32)
// cell:          A=relu(P+c) -> A+=gat1 -> F -> F(final fp32)
__global__ __launch_bounds__(256) void tail_k(const u16* __restrict__ h0, const u16* __restrict__ h1,
                                              const u16* __restrict__ h2,
                                              const u32* __restrict__ recs, const float* __restrict__ walpha,
                                              const int* __restrict__ rowptr,
                                              const u16* __restrict__ P_net, const u16* __restrict__ P_cell,
                                              const u16* __restrict__ W2, const float* __restrict__ cvec,
                                              float* __restrict__ out_net, float* __restrict__ out_cell) {
  __shared__ u16 Wlds[128 * SP];
  __shared__ u16 Alds[16 * SP];
  int bid = blockIdx.x, tid = threadIdx.x;
  stageW2(W2, Wlds, tid);
  if (bid < AB) {
    int nb = bid;  // net tile
    gat_phase<0>(nb, tid, h0, recs, walpha, rowptr, Alds);
    __syncthreads();                                   // covers W2 staging too
    F_phase<0>(nb, tid, P_net, cvec, Wlds, Alds, nullptr);   // buf_net0 -> Alds
    F_phase<0>(nb, tid, P_net, cvec, Wlds, Alds, nullptr);   // buf_net1 -> Alds
    gat_phase<1>(nb, tid, h2, recs + (size_t)2 * NE, walpha + (size_t)2 * NE,
                 rowptr + 2 * (NN + 1), Alds);
    __syncthreads();
    F_phase<1>(nb, tid, P_net, cvec, Wlds, Alds, (void*)out_net);   // final
  } else {
    int nb = bid - AB;  // cell tile
    {  // elem init: relu(P_cell + cvec) -> Alds (same-thread slot as gat)
      int sub = tid & 15, g = tid >> 4;
      int n = nb * 16 + g;
      short8 pv = *(const short8*)(P_cell + (size_t)n * 128 + sub * 8);
      short8 rb;
#pragma unroll
      for (int t = 0; t < 8; ++t)
        rb[t] = (short)f2b(fmaxf(b2f((u16)pv[t]) + cvec[sub * 8 + t], 0.f));
      *(short8*)(&Alds[g * SP + sub * 8]) = rb;
    }
    // no barrier needed: gat_phase<1> reads the slot this same thread just wrote
    gat_phase<1>(nb, tid, h1, recs + (size_t)NE, walpha + (size_t)NE,
                 rowptr + (NN + 1), Alds);
    __syncthreads();                                   // covers W2 staging too
    F_phase<0>(nb, tid, P_cell, cvec, Wlds, Alds, nullptr);  // buf_cell1 -> Alds
    F_phase<1>(nb, tid, P_cell, cvec, Wlds, Alds, (void*)out_cell);  // final
  }
}

extern "C" void kernel_launch(void* const* d_in, const int* in_sizes, int n_in,
                              void* d_out, int out_size, void* d_ws, size_t ws_size,
                              hipStream_t stream) {
  const float* x_net   = (const float*)d_in[0];
  const float* x_cell  = (const float*)d_in[1];
  const float* Wp_net  = (const float*)d_in[2];
  const float* Wp_cell = (const float*)d_in[3];
  const float* Wg[3] = {(const float*)d_in[4], (const float*)d_in[7], (const float*)d_in[10]};
  const float* al[3] = {(const float*)d_in[5], (const float*)d_in[8], (const float*)d_in[11]};
  const float* ar[3] = {(const float*)d_in[6], (const float*)d_in[9], (const float*)d_in[12]};
  const float* Wl    = (const float*)d_in[13];
  const float* bias  = (const float*)d_in[14];
  const int* src[3] = {(const int*)d_in[15], (const int*)d_in[17], (const int*)d_in[19]};
  const int* dst[3] = {(const int*)d_in[16], (const int*)d_in[18], (const int*)d_in[20]};

  char* ws = (char*)d_ws;
  size_t off = 0;
  auto alloc = [&](size_t b) { void* p = ws + off; off = (off + b + 255) & ~(size_t)255; return p; };
  u16*  feat_net  = (u16*)alloc((size_t)NN * 128 * 2);
  u16*  feat_cell = (u16*)alloc((size_t)NN * 128 * 2);
  u16*  hbuf0     = (u16*)alloc((size_t)NN * 128 * 2);
  u16*  hbuf1     = (u16*)alloc((size_t)NN * 128 * 2);
  u16*  hbuf2     = (u16*)alloc((size_t)NN * 128 * 2);
  u16*  P_net     = (u16*)alloc((size_t)NN * 128 * 2);
  u16*  P_cell    = (u16*)alloc((size_t)NN * 128 * 2);
  float* vecs     = (float*)alloc(7 * 128 * 4);
  float* logit    = (float*)alloc((size_t)6 * NN * 4);
  u16*   Wl_bf    = (u16*)alloc((size_t)128 * 256 * 2);
  u16*   Wg_bf    = (u16*)alloc((size_t)3 * 128 * 128 * 2);
  int*   bcnt     = (int*)alloc((size_t)3 * NB * 4);
  int*   bcur     = (int*)alloc((size_t)3 * NB * 4);
  int*   bptr     = (int*)alloc((size_t)3 * (NB + 1) * 4);
  int*   rowptr   = (int*)alloc((size_t)3 * (NN + 1) * 4);
  u32*   recs     = (u32*)alloc((size_t)3 * NE * 4);
  float* walpha   = (float*)alloc((size_t)3 * NE * 4);

  float* out_f = (float*)d_out;  // [2,N,D] fp32: net then cell
  const u16* W2 = Wl_bf + 128;   // Wl cols 128..255 (ldw 256)
  const float* cvec = vecs + 6 * 128;

  // 1. prep: proj | conv | vec | zero bcnt
  prep_k<<<2 * AB + 138, 256, 0, stream>>>(x_net, x_cell, Wp_net, Wp_cell, feat_net, feat_cell,
                                           Wl, Wg[0], Wg[1], Wg[2], Wl_bf, Wg_bf,
                                           al[0], ar[0], al[1], ar[1], al[2], ar[2], bias, vecs, bcnt);
  // 2. logits | bhist
  logbh_k<<<782 + 3 * NCH, 256, 0, stream>>>(feat_net, feat_cell, vecs, logit,
                                             dst[0], dst[1], dst[2], bcnt);
  // 3. scan
  bscan_k<<<3, 1024, 0, stream>>>(bcnt, bptr, bcur);
  // 4. scatter
  bscatter_k<<<dim3(NCH, 3), 256, 0, stream>>>(src[0], dst[0], src[1], dst[1], src[2], dst[2],
                                               bcur, recs);
  // 5. GEMMs | sort (+ edge-weight precompute)
  sortgemm_k<<<2 * GB + 3 * NB, 256, 0, stream>>>(recs, bptr, rowptr, feat_net, feat_cell,
                                                  Wl_bf, Wg_bf, P_net, P_cell, hbuf0, hbuf1, hbuf2,
                                                  logit, walpha);
  // 6. tail: full node-local pipeline (shuffle-free gather)
  tail_k<<<2 * AB, 256, 0, stream>>>(hbuf0, hbuf1, hbuf2, recs, walpha, rowptr,
                                     P_net, P_cell, W2, cvec,
                                     out_f, out_f + (size_t)NN * 128);
}